// Round 6
// baseline (2148.600 us; speedup 1.0000x reference)
//
#include <hip/hip_runtime.h>
#include <hip/hip_bf16.h>

#define H 128
#define RBF 64

typedef __attribute__((ext_vector_type(8))) short bf16x8;
typedef __attribute__((ext_vector_type(4))) float f32x4;

__device__ inline short f2bf(float f) {
  union { float f; unsigned u; } v; v.f = f;
  const unsigned r = (v.u + 0x7FFFu + ((v.u >> 16) & 1u)) >> 16;
  return (short)r;
}

// ---------------------------------------------------------------- utilities
__global__ __launch_bounds__(128) void ln_rows(const float* __restrict__ X,
                                               const float* __restrict__ g,
                                               const float* __restrict__ bb,
                                               float* __restrict__ Y, int N) {
  __shared__ float sh[4];
  const int row = blockIdx.x;
  const int j = threadIdx.x;
  float x = X[(size_t)row * H + j];
  float s = x, q = x * x;
#pragma unroll
  for (int m = 32; m; m >>= 1) {
    s += __shfl_xor(s, m, 64);
    q += __shfl_xor(q, m, 64);
  }
  if ((j & 63) == 0) { sh[(j >> 6) * 2] = s; sh[(j >> 6) * 2 + 1] = q; }
  __syncthreads();
  s = sh[0] + sh[2];
  q = sh[1] + sh[3];
  const float mu = s * 0.0078125f;
  const float var = q * 0.0078125f - mu * mu;
  const float rs = rsqrtf(var + 1e-5f);
  Y[(size_t)row * H + j] = (x - mu) * rs * g[j] + bb[j];
}

// conv_k (o,i,dx,dy,dz) -> Kt[tap][i][o]
__global__ void transpose_k(const float* __restrict__ K, float* __restrict__ Kt) {
  const int idx = blockIdx.x * 256 + threadIdx.x;
  const int total = H * H * 27;
  if (idx >= total) return;
  const int tap = idx % 27;
  const int rem = idx / 27;
  const int i = rem % H;
  const int o = rem / H;
  Kt[((size_t)tap * H + i) * H + o] = K[idx];
}

// We[64][128] f32 -> frag-layout bf16: Web[((h*8+c)*64+lane)*8+j]
__global__ __launch_bounds__(256) void pack_we(const float* __restrict__ We,
                                               short* __restrict__ Web) {
  const int id = blockIdx.x * 256 + threadIdx.x;
  if (id >= 1024) return;
  const int f = id >> 6, l = id & 63;
  const int h = f >> 3, c = f & 7;
  const int col = (c << 4) + (l & 15);
  const int k0 = h * 32 + (l >> 4) * 8;
  short* o = Web + (size_t)id * 8;
#pragma unroll
  for (int j = 0; j < 8; ++j) o[j] = f2bf(We[(k0 + j) * H + col]);
}

// ----------------------------------------------- counting-sort (CSR builder)
__global__ __launch_bounds__(256) void k_hist(const int* __restrict__ dst, int E,
                                              int* __restrict__ cnt) {
  int e = blockIdx.x * 256 + threadIdx.x;
  const int stride = gridDim.x * 256;
  for (; e < E; e += stride) atomicAdd(&cnt[dst[e]], 1);
}

__global__ __launch_bounds__(256) void k_blocksum(const int* __restrict__ cnt,
                                                  int* __restrict__ bsum) {
  __shared__ int sh[256];
  const int t = threadIdx.x;
  sh[t] = cnt[blockIdx.x * 256 + t];
  __syncthreads();
#pragma unroll
  for (int o = 128; o; o >>= 1) {
    if (t < o) sh[t] += sh[t + o];
    __syncthreads();
  }
  if (!t) bsum[blockIdx.x] = sh[0];
}

__global__ __launch_bounds__(256) void k_scan_bsum(const int* __restrict__ bsum,
                                                   int* __restrict__ bpre, int NB) {
  __shared__ int sh[256];
  const int t = threadIdx.x;
  const int v = (t < NB) ? bsum[t] : 0;
  sh[t] = v;
  __syncthreads();
  for (int o = 1; o < 256; o <<= 1) {
    const int u = (t >= o) ? sh[t - o] : 0;
    __syncthreads();
    sh[t] += u;
    __syncthreads();
  }
  if (t < NB) bpre[t] = sh[t] - v;
}

__global__ __launch_bounds__(256) void k_apply(const int* __restrict__ cnt,
                                               const int* __restrict__ bpre,
                                               int* __restrict__ rowptr,
                                               int* __restrict__ cursor, int N) {
  __shared__ int sh[256];
  const int t = threadIdx.x;
  const int i = blockIdx.x * 256 + t;
  const int v = cnt[i];
  sh[t] = v;
  __syncthreads();
  for (int o = 1; o < 256; o <<= 1) {
    const int u = (t >= o) ? sh[t - o] : 0;
    __syncthreads();
    sh[t] += u;
    __syncthreads();
  }
  const int excl = sh[t] - v + bpre[blockIdx.x];
  if (i <= N) {
    rowptr[i] = excl;
    if (i < N) cursor[i] = excl;
  }
}

// also pre-permute src and ew to kill double indirection in the gather
__global__ __launch_bounds__(256) void k_perm(const int* __restrict__ dst,
                                              const int* __restrict__ src,
                                              const float* __restrict__ ew, int E,
                                              int* __restrict__ cursor,
                                              int* __restrict__ perm,
                                              int* __restrict__ srcp,
                                              float* __restrict__ ewp) {
  int e = blockIdx.x * 256 + threadIdx.x;
  const int stride = gridDim.x * 256;
  for (; e < E; e += stride) {
    const int p = atomicAdd(&cursor[dst[e]], 1);
    perm[p] = e;
    srcp[p] = src[e];
    ewp[p] = ew[e];
  }
}

// ------------------------------------------- node projection: Y = [LN](X) @ W
template <bool DO_LN>
__global__ __launch_bounds__(256) void proj_kernel(const float* __restrict__ X,
                                                   const float* __restrict__ W,
                                                   const float* __restrict__ g,
                                                   const float* __restrict__ bb,
                                                   float* __restrict__ Y, int N) {
  __shared__ float At[128 * 68];
  const int row0 = blockIdx.x * 64;
  const int t = threadIdx.x;
  const int lk = (t & 31) * 4;
  const int lr = t >> 5;
  float4 g4 = {0, 0, 0, 0}, b4 = {0, 0, 0, 0};
  if (DO_LN) {
    g4 = *(const float4*)(g + lk);
    b4 = *(const float4*)(bb + lk);
  }
#pragma unroll
  for (int p = 0; p < 8; ++p) {
    const int r = lr + p * 8;
    const int row = row0 + r;
    float4 xv = make_float4(0.f, 0.f, 0.f, 0.f);
    if (row < N) xv = *(const float4*)(X + (size_t)row * H + lk);
    if (DO_LN) {
      float s = xv.x + xv.y + xv.z + xv.w;
      float q = xv.x * xv.x + xv.y * xv.y + xv.z * xv.z + xv.w * xv.w;
#pragma unroll
      for (int m = 16; m; m >>= 1) {
        s += __shfl_xor(s, m, 64);
        q += __shfl_xor(q, m, 64);
      }
      const float mu = s * 0.0078125f;
      const float var = q * 0.0078125f - mu * mu;
      const float rs = rsqrtf(var + 1e-5f);
      xv.x = (xv.x - mu) * rs * g4.x + b4.x;
      xv.y = (xv.y - mu) * rs * g4.y + b4.y;
      xv.z = (xv.z - mu) * rs * g4.z + b4.z;
      xv.w = (xv.w - mu) * rs * g4.w + b4.w;
    }
    At[(lk + 0) * 68 + r] = xv.x;
    At[(lk + 1) * 68 + r] = xv.y;
    At[(lk + 2) * 68 + r] = xv.z;
    At[(lk + 3) * 68 + r] = xv.w;
  }
  __syncthreads();
  const int tc = t & 15;
  const int tr = t >> 4;
  float acc[4][8];
#pragma unroll
  for (int i = 0; i < 4; ++i)
#pragma unroll
    for (int c = 0; c < 8; ++c) acc[i][c] = 0.f;
  const float* wbase = W + tc * 8;
#pragma unroll 4
  for (int k = 0; k < 128; ++k) {
    const float4 a4 = *(const float4*)(At + k * 68 + tr * 4);
    const float4 w0 = *(const float4*)(wbase + k * H);
    const float4 w1 = *(const float4*)(wbase + k * H + 4);
    const float av[4] = {a4.x, a4.y, a4.z, a4.w};
#pragma unroll
    for (int i = 0; i < 4; ++i) {
      acc[i][0] += av[i] * w0.x; acc[i][1] += av[i] * w0.y;
      acc[i][2] += av[i] * w0.z; acc[i][3] += av[i] * w0.w;
      acc[i][4] += av[i] * w1.x; acc[i][5] += av[i] * w1.y;
      acc[i][6] += av[i] * w1.z; acc[i][7] += av[i] * w1.w;
    }
  }
#pragma unroll
  for (int i = 0; i < 4; ++i) {
    const int row = row0 + tr * 4 + i;
    if (row < N) {
      float4 o0 = {acc[i][0], acc[i][1], acc[i][2], acc[i][3]};
      float4 o1 = {acc[i][4], acc[i][5], acc[i][6], acc[i][7]};
      float* yp = Y + (size_t)row * H + tc * 8;
      *(float4*)yp = o0;
      *(float4*)(yp + 4) = o1;
    }
  }
}

// ----------------------------------------- tiled MFMA edge gather (CSR)
// Block owns 32 dst nodes. Each of the 4 waves owns 32 output columns and
// scans ALL the block's 16-edge tiles privately: NO barrier in the loop
// (hipcc's pre-barrier vmcnt(0) drain was killing every prefetch — R3/R5).
// 2-level static-register pipeline: idx loads 2 tiles ahead, data 1 ahead.
// Tail tiles are computed unguarded: their ew is forced to 0 so they add 0.
template <bool FUSE_LN>
__global__ __launch_bounds__(256, 2) void gather_mfma(
    const float* __restrict__ P, const short* __restrict__ Web,
    const float* __restrict__ ea, const int* __restrict__ perm,
    const int* __restrict__ srcp, const float* __restrict__ ewp,
    const int* __restrict__ rowptr, int E, int N,
    const float* __restrict__ base, const float* __restrict__ skip,
    const float* __restrict__ g, const float* __restrict__ bb,
    float* __restrict__ out) {
  __shared__ float acc[32 * 132];
  __shared__ int rp_s[33];
  const int t = threadIdx.x;
  const int w = t >> 6, lane = t & 63;
  const int n0 = blockIdx.x * 32;
  if (t < 33) rp_s[t] = rowptr[min(n0 + t, N)];
  for (int u = t; u < 32 * 132; u += 256) acc[u] = 0.f;
  __syncthreads();
  const int beg = rp_s[0], end = rp_s[32];
  const int ntiles = (end - beg + 15) >> 4;
  const int Em1 = E - 1;

  // B fragments for this wave's two 16-col blocks (16 VGPRs, loop-resident)
  const int c0 = 2 * w;
  const bf16x8 bw0 = *(const bf16x8*)(Web + ((size_t)((0 + c0) * 64 + lane)) * 8);
  const bf16x8 bw1 = *(const bf16x8*)(Web + ((size_t)((8 + c0) * 64 + lane)) * 8);
  const bf16x8 bw2 = *(const bf16x8*)(Web + ((size_t)((1 + c0) * 64 + lane)) * 8);
  const bf16x8 bw3 = *(const bf16x8*)(Web + ((size_t)((9 + c0) * 64 + lane)) * 8);

  const int l15 = lane & 15, lg = lane >> 4, rbase = lg * 4;
  const int col0 = c0 * 16 + l15;

  // idx stage: perm for A rows, srcp/ewp (+dl binsearch) for C rows
  auto IDX = [&](int q, int& pe, int* sp, float* wq, int* dl) {
    const int j0 = beg + (q << 4);
    pe = perm[min(j0 + l15, Em1)];
#pragma unroll
    for (int j = 0; j < 4; ++j) {
      const int jr = j0 + rbase + j;
      const int jc = min(jr, Em1);
      sp[j] = srcp[jc];
      wq[j] = (jr < end) ? ewp[jc] : 0.f;  // masks tail AND clamped rows
      int lo = 0, hi = 32;
#pragma unroll
      for (int it = 0; it < 5; ++it) {
        const int mid = (lo + hi) >> 1;
        if (rp_s[mid] <= jr) lo = mid; else hi = mid;
      }
      dl[j] = lo;
    }
  };
  // data stage: ea raw (A-tile) + P values for this wave's columns
  auto DATA = [&](int pe, const int* sp, float4& e0, float4& e1, float4& e2,
                  float4& e3, float* pv) {
    const float* er = ea + (size_t)pe * RBF + lg * 8;
    e0 = *(const float4*)(er);
    e1 = *(const float4*)(er + 4);
    e2 = *(const float4*)(er + 32);
    e3 = *(const float4*)(er + 36);
#pragma unroll
    for (int j = 0; j < 4; ++j) {
      const float* pr = P + (size_t)sp[j] * H + col0;
      pv[j] = pr[0];
      pv[4 + j] = pr[16];
    }
  };
  auto COMPUTE = [&](const float4& e0, const float4& e1, const float4& e2,
                     const float4& e3, const float* pv, const float* wq,
                     const int* dl) {
    bf16x8 af0, af1;
    af0[0] = f2bf(e0.x); af0[1] = f2bf(e0.y); af0[2] = f2bf(e0.z); af0[3] = f2bf(e0.w);
    af0[4] = f2bf(e1.x); af0[5] = f2bf(e1.y); af0[6] = f2bf(e1.z); af0[7] = f2bf(e1.w);
    af1[0] = f2bf(e2.x); af1[1] = f2bf(e2.y); af1[2] = f2bf(e2.z); af1[3] = f2bf(e2.w);
    af1[4] = f2bf(e3.x); af1[5] = f2bf(e3.y); af1[6] = f2bf(e3.z); af1[7] = f2bf(e3.w);
    f32x4 C0 = {0.f, 0.f, 0.f, 0.f};
    C0 = __builtin_amdgcn_mfma_f32_16x16x32_bf16(af0, bw0, C0, 0, 0, 0);
    C0 = __builtin_amdgcn_mfma_f32_16x16x32_bf16(af1, bw1, C0, 0, 0, 0);
    f32x4 C1 = {0.f, 0.f, 0.f, 0.f};
    C1 = __builtin_amdgcn_mfma_f32_16x16x32_bf16(af0, bw2, C1, 0, 0, 0);
    C1 = __builtin_amdgcn_mfma_f32_16x16x32_bf16(af1, bw3, C1, 0, 0, 0);
#pragma unroll
    for (int j = 0; j < 4; ++j) {
      unsafeAtomicAdd(&acc[dl[j] * 132 + col0], C0[j] * wq[j] * pv[j]);
      unsafeAtomicAdd(&acc[dl[j] * 132 + col0 + 16], C1[j] * wq[j] * pv[4 + j]);
    }
  };

  if (ntiles > 0) {
    const int qmax = ntiles - 1;
    // named register sets (static — no runtime-indexed arrays, rule #20)
    int peX, spX[4], dlX[4];  float wqX[4];
    int peY, spY[4], dlY[4];  float wqY[4];
    float4 a0A, a1A, a2A, a3A;  float pvA[8];
    int dlA[4];  float wqA[4];
    float4 a0B, a1B, a2B, a3B;  float pvB[8];
    int dlB[4];  float wqB[4];

    // prologue: idx(0)->X, data(0)->A, idx(1)->Y
    IDX(0, peX, spX, wqX, dlX);
    DATA(peX, spX, a0A, a1A, a2A, a3A, pvA);
#pragma unroll
    for (int j = 0; j < 4; ++j) { dlA[j] = dlX[j]; wqA[j] = wqX[j]; }
    IDX(min(1, qmax), peY, spY, wqY, dlY);

    for (int tt = 0; tt < ntiles; tt += 2) {
      // data(tt+1): Y -> B ; idx(tt+2) -> X ; compute A (tile tt)
      DATA(peY, spY, a0B, a1B, a2B, a3B, pvB);
#pragma unroll
      for (int j = 0; j < 4; ++j) { dlB[j] = dlY[j]; wqB[j] = wqY[j]; }
      IDX(min(tt + 2, qmax), peX, spX, wqX, dlX);
      COMPUTE(a0A, a1A, a2A, a3A, pvA, wqA, dlA);
      // data(tt+2): X -> A ; idx(tt+3) -> Y ; compute B (tile tt+1)
      DATA(peX, spX, a0A, a1A, a2A, a3A, pvA);
#pragma unroll
      for (int j = 0; j < 4; ++j) { dlA[j] = dlX[j]; wqA[j] = wqX[j]; }
      IDX(min(tt + 3, qmax), peY, spY, wqY, dlY);
      if (tt + 1 < ntiles) COMPUTE(a0B, a1B, a2B, a3B, pvB, wqB, dlB);
    }
  }
  __syncthreads();

  // ---- epilogue: one write per node, optional fused LN + base + skip
  for (int n = w; n < 32; n += 4) {
    const int node = n0 + n;
    if (node >= N) break;
    const float v0 = acc[n * 132 + lane];
    const float v1 = acc[n * 132 + 64 + lane];
    const size_t i0 = (size_t)node * H + lane;
    if (FUSE_LN) {
      float s = v0 + v1, q = v0 * v0 + v1 * v1;
#pragma unroll
      for (int m = 32; m; m >>= 1) {
        s += __shfl_xor(s, m, 64);
        q += __shfl_xor(q, m, 64);
      }
      const float mu = s * 0.0078125f;
      const float var = q * 0.0078125f - mu * mu;
      const float rs = rsqrtf(var + 1e-5f);
      out[i0] = base[i0] + (v0 - mu) * rs * g[lane] + bb[lane] + skip[i0];
      out[i0 + 64] =
          base[i0 + 64] + (v1 - mu) * rs * g[lane + 64] + bb[lane + 64] + skip[i0 + 64];
    } else {
      out[i0] = v0;
      out[i0 + 64] = v1;
    }
  }
}

// ----------------------------------------------------------------- conv3d
__global__ __launch_bounds__(256) void conv3d(const float* __restrict__ Min,
                                              const float* __restrict__ Kt,
                                              const float* __restrict__ bias,
                                              float* __restrict__ Mout) {
  __shared__ float in_s[193 * 68];
  const int b = blockIdx.x >> 3;
  const int x = blockIdx.x & 7;
  const int t = threadIdx.x;
  const int tc = t & 15;
  const int tr = t >> 4;
  float acc[4][8];
  {
    const float4 bs0 = *(const float4*)(bias + tc * 8);
    const float4 bs1 = *(const float4*)(bias + tc * 8 + 4);
#pragma unroll
    for (int vi = 0; vi < 4; ++vi) {
      acc[vi][0] = bs0.x; acc[vi][1] = bs0.y; acc[vi][2] = bs0.z; acc[vi][3] = bs0.w;
      acc[vi][4] = bs1.x; acc[vi][5] = bs1.y; acc[vi][6] = bs1.z; acc[vi][7] = bs1.w;
    }
  }
  for (int u = t; u < 68; u += 256) in_s[192 * 68 + u] = 0.f;

  for (int pass = 0; pass < 2; ++pass) {
    __syncthreads();
#pragma unroll
    for (int it = 0; it < 12; ++it) {
      const int r = (t >> 4) + it * 16;
      const int c4 = (t & 15) * 4;
      const int xs = r >> 6;
      const int yz = r & 63;
      const int gx = x + xs - 1;
      float4 val = make_float4(0.f, 0.f, 0.f, 0.f);
      if (gx >= 0 && gx < 8) {
        const int row = (b * 8 + gx) * 64 + yz;
        val = *(const float4*)(Min + (size_t)row * H + pass * 64 + c4);
      }
      *(float4*)(in_s + r * 68 + c4) = val;
    }
    __syncthreads();

    for (int tap = 0; tap < 27; ++tap) {
      const int dx = tap / 9, dy = (tap / 3) % 3, dz = tap % 3;
      int rp[4];
#pragma unroll
      for (int vi = 0; vi < 4; ++vi) {
        const int v = tr * 4 + vi;
        const int y = v >> 3, z = v & 7;
        const int ny = y + dy - 1, nz = z + dz - 1;
        const bool ok = (ny >= 0 && ny < 8 && nz >= 0 && nz < 8);
        rp[vi] = ok ? (dx * 64 + ny * 8 + nz) * 68 : 192 * 68;
      }
      const float* wbase = Kt + ((size_t)tap * H + pass * 64) * H + tc * 8;
#pragma unroll 4
      for (int kk = 0; kk < 64; ++kk) {
        const float4 w0 = *(const float4*)(wbase + (size_t)kk * H);
        const float4 w1 = *(const float4*)(wbase + (size_t)kk * H + 4);
        float iv[4];
#pragma unroll
        for (int vi = 0; vi < 4; ++vi) iv[vi] = in_s[rp[vi] + kk];
#pragma unroll
        for (int vi = 0; vi < 4; ++vi) {
          acc[vi][0] += iv[vi] * w0.x; acc[vi][1] += iv[vi] * w0.y;
          acc[vi][2] += iv[vi] * w0.z; acc[vi][3] += iv[vi] * w0.w;
          acc[vi][4] += iv[vi] * w1.x; acc[vi][5] += iv[vi] * w1.y;
          acc[vi][6] += iv[vi] * w1.z; acc[vi][7] += iv[vi] * w1.w;
        }
      }
    }
  }
#pragma unroll
  for (int vi = 0; vi < 4; ++vi) {
    const int v = tr * 4 + vi;
    float* op = Mout + ((size_t)((b * 8 + x) * 64 + v)) * H + tc * 8;
    float4 o0 = {acc[vi][0], acc[vi][1], acc[vi][2], acc[vi][3]};
    float4 o1 = {acc[vi][4], acc[vi][5], acc[vi][6], acc[vi][7]};
    *(float4*)op = o0;
    *(float4*)(op + 4) = o1;
  }
}

// ------------------------------------------------------------------ driver
static inline void build_csr(const int* dst, const int* src, const float* ew,
                             int E, int N, int* cnt, int* bsum, int* bpre,
                             int* rowptr, int* cursor, int* perm, int* srcp,
                             float* ewp, hipStream_t stream) {
  const int NB = (N + 256) / 256;
  hipMemsetAsync(cnt, 0, (size_t)NB * 256 * sizeof(int), stream);
  k_hist<<<1024, 256, 0, stream>>>(dst, E, cnt);
  k_blocksum<<<NB, 256, 0, stream>>>(cnt, bsum);
  k_scan_bsum<<<1, 256, 0, stream>>>(bsum, bpre, NB);
  k_apply<<<NB, 256, 0, stream>>>(cnt, bpre, rowptr, cursor, N);
  k_perm<<<1024, 256, 0, stream>>>(dst, src, ew, E, cursor, perm, srcp, ewp);
}

extern "C" void kernel_launch(void* const* d_in, const int* in_sizes, int n_in,
                              void* d_out, int out_size, void* d_ws, size_t ws_size,
                              hipStream_t stream) {
  const float* a_x = (const float*)d_in[0];
  const float* m_x = (const float*)d_in[1];
  const int* aa_idx = (const int*)d_in[2];
  const int* a2m_src = (const int*)d_in[3];
  const int* a2m_dst = (const int*)d_in[4];
  const int* m2a_src = (const int*)d_in[5];
  const int* m2a_dst = (const int*)d_in[6];
  const float* aa_w = (const float*)d_in[7];
  const float* a2m_w = (const float*)d_in[8];
  const float* m2a_w = (const float*)d_in[9];
  const float* aa_ea = (const float*)d_in[10];
  const float* a2m_ea = (const float*)d_in[11];
  const float* m2a_ea = (const float*)d_in[12];
  const float* W_short = (const float*)d_in[13];
  const float* We_short = (const float*)d_in[14];
  const float* W_a2m = (const float*)d_in[15];
  const float* We_a2m = (const float*)d_in[16];
  const float* W_m2a = (const float*)d_in[17];
  const float* We_m2a = (const float*)d_in[18];
  const float* conv_k = (const float*)d_in[19];
  const float* conv_b = (const float*)d_in[20];
  const float* g_short = (const float*)d_in[21];
  const float* b_short = (const float*)d_in[22];
  const float* g_long = (const float*)d_in[23];
  const float* b_long = (const float*)d_in[24];
  const float* g_a2m = (const float*)d_in[25];
  const float* b_a2m = (const float*)d_in[26];
  const float* g_m2a = (const float*)d_in[27];
  const float* b_m2a = (const float*)d_in[28];

  const int NA = in_sizes[0] / H;
  const int NM = in_sizes[1] / H;
  const int E_AA = in_sizes[2] / 2;
  const int E_AM = in_sizes[3];
  const int E_MA = in_sizes[5];
  const int* aa_src = aa_idx;
  const int* aa_dst = aa_idx + E_AA;

  float* ws = (float*)d_ws;
  float* p_buf = ws;                         // NA*H
  float* m1_buf = p_buf + (size_t)NA * H;    // NM*H
  float* m2_buf = m1_buf + (size_t)NM * H;   // NM*H
  float* a2_buf = m2_buf + (size_t)NM * H;   // NA*H
  float* kt = a2_buf + (size_t)NA * H;       // 27*H*H
  float* ewp_aa = kt + (size_t)27 * H * H;   // E_AA
  float* ewp_a2m = ewp_aa + E_AA;            // E_AM
  float* ewp_m2a = ewp_a2m + E_AM;           // E_MA
  short* web_aa = (short*)(ewp_m2a + E_MA);  // 8192 bf16 each
  short* web_a2m = web_aa + 8192;
  short* web_m2a = web_a2m + 8192;
  int* iws = (int*)(web_m2a + 8192);
  int* perm_aa = iws;   iws += E_AA;
  int* perm_a2m = iws;  iws += E_AM;
  int* perm_m2a = iws;  iws += E_MA;
  int* srcp_aa = iws;   iws += E_AA;
  int* srcp_a2m = iws;  iws += E_AM;
  int* srcp_m2a = iws;  iws += E_MA;
  int* rp_aa = iws;     iws += NA + 1;
  int* rp_a2m = iws;    iws += NM + 1;
  int* rp_m2a = iws;    iws += NA + 1;
  const int PADN = ((NA + 256) / 256) * 256;
  int* cnt = iws;       iws += PADN;
  int* cursor = iws;    iws += PADN;
  int* bsum = iws;      iws += 256;
  int* bpre = iws;      iws += 256;

  float* out_a = (float*)d_out;
  float* out_m = out_a + (size_t)NA * H;

  // CSR builds
  build_csr(aa_dst, aa_src, aa_w, E_AA, NA, cnt, bsum, bpre, rp_aa, cursor,
            perm_aa, srcp_aa, ewp_aa, stream);
  build_csr(a2m_dst, a2m_src, a2m_w, E_AM, NM, cnt, bsum, bpre, rp_a2m, cursor,
            perm_a2m, srcp_a2m, ewp_a2m, stream);
  build_csr(m2a_dst, m2a_src, m2a_w, E_MA, NA, cnt, bsum, bpre, rp_m2a, cursor,
            perm_m2a, srcp_m2a, ewp_m2a, stream);

  // weight prep
  pack_we<<<4, 256, 0, stream>>>(We_short, web_aa);
  pack_we<<<4, 256, 0, stream>>>(We_a2m, web_a2m);
  pack_we<<<4, 256, 0, stream>>>(We_m2a, web_m2a);
  transpose_k<<<(H * H * 27 + 255) / 256, 256, 0, stream>>>(conv_k, kt);

  ln_rows<<<NM, 128, 0, stream>>>(m_x, g_long, b_long, m1_buf, NM);

  // P_short = LN(a_x) @ W_short
  proj_kernel<true><<<(NA + 63) / 64, 256, 0, stream>>>(a_x, W_short, g_short,
                                                        b_short, p_buf, NA);
  // a = gather_aa(P_short) (raw)
  gather_mfma<false><<<(NA + 31) / 32, 256, 0, stream>>>(
      p_buf, web_aa, aa_ea, perm_aa, srcp_aa, ewp_aa, rp_aa, E_AA, NA, nullptr,
      nullptr, nullptr, nullptr, a2_buf);
  // m = conv3d(LN(m_x))
  conv3d<<<(NM / 64), 256, 0, stream>>>(m1_buf, kt, conv_b, m2_buf);

  // P_a2m = a @ W_a2m
  proj_kernel<false><<<(NA + 63) / 64, 256, 0, stream>>>(a2_buf, W_a2m, nullptr,
                                                         nullptr, p_buf, NA);
  // out_m = m + LN(gather_a2m(P_a2m)) + m_x
  gather_mfma<true><<<(NM + 31) / 32, 256, 0, stream>>>(
      p_buf, web_a2m, a2m_ea, perm_a2m, srcp_a2m, ewp_a2m, rp_a2m, E_AM, NM,
      m2_buf, m_x, g_a2m, b_a2m, out_m);
  // P_m2a = m @ W_m2a
  proj_kernel<false><<<(NM + 63) / 64, 256, 0, stream>>>(m2_buf, W_m2a, nullptr,
                                                         nullptr, m1_buf, NM);
  // out_a = a + LN(gather_m2a(P_m2a)) + a_x
  gather_mfma<true><<<(NA + 31) / 32, 256, 0, stream>>>(
      m1_buf, web_m2a, m2a_ea, perm_m2a, srcp_m2a, ewp_m2a, rp_m2a, E_MA, NA,
      a2_buf, a_x, g_m2a, b_m2a, out_a);
}

// Round 7
// 2095.877 us; speedup vs baseline: 1.0252x; 1.0252x over previous
//
#include <hip/hip_runtime.h>
#include <hip/hip_bf16.h>

#define H 128
#define RBF 64

typedef __attribute__((ext_vector_type(8))) short bf16x8;
typedef __attribute__((ext_vector_type(4))) float f32x4;

__device__ inline short f2bf(float f) {
  union { float f; unsigned u; } v; v.f = f;
  const unsigned r = (v.u + 0x7FFFu + ((v.u >> 16) & 1u)) >> 16;
  return (short)r;
}

// ---------------------------------------------------------------- utilities
__global__ __launch_bounds__(128) void ln_rows(const float* __restrict__ X,
                                               const float* __restrict__ g,
                                               const float* __restrict__ bb,
                                               float* __restrict__ Y, int N) {
  __shared__ float sh[4];
  const int row = blockIdx.x;
  const int j = threadIdx.x;
  float x = X[(size_t)row * H + j];
  float s = x, q = x * x;
#pragma unroll
  for (int m = 32; m; m >>= 1) {
    s += __shfl_xor(s, m, 64);
    q += __shfl_xor(q, m, 64);
  }
  if ((j & 63) == 0) { sh[(j >> 6) * 2] = s; sh[(j >> 6) * 2 + 1] = q; }
  __syncthreads();
  s = sh[0] + sh[2];
  q = sh[1] + sh[3];
  const float mu = s * 0.0078125f;
  const float var = q * 0.0078125f - mu * mu;
  const float rs = rsqrtf(var + 1e-5f);
  Y[(size_t)row * H + j] = (x - mu) * rs * g[j] + bb[j];
}

// conv_k (o,i,dx,dy,dz) -> Kt[tap][i][o]
__global__ void transpose_k(const float* __restrict__ K, float* __restrict__ Kt) {
  const int idx = blockIdx.x * 256 + threadIdx.x;
  const int total = H * H * 27;
  if (idx >= total) return;
  const int tap = idx % 27;
  const int rem = idx / 27;
  const int i = rem % H;
  const int o = rem / H;
  Kt[((size_t)tap * H + i) * H + o] = K[idx];
}

// We[64][128] f32 -> frag-layout bf16: Web[((h*8+c)*64+lane)*8+j]
__global__ __launch_bounds__(256) void pack_we(const float* __restrict__ We,
                                               short* __restrict__ Web) {
  const int id = blockIdx.x * 256 + threadIdx.x;
  if (id >= 1024) return;
  const int f = id >> 6, l = id & 63;
  const int h = f >> 3, c = f & 7;
  const int col = (c << 4) + (l & 15);
  const int k0 = h * 32 + (l >> 4) * 8;
  short* o = Web + (size_t)id * 8;
#pragma unroll
  for (int j = 0; j < 8; ++j) o[j] = f2bf(We[(k0 + j) * H + col]);
}

// ----------------------------------------------- counting-sort (CSR builder)
__global__ __launch_bounds__(256) void k_hist(const int* __restrict__ dst, int E,
                                              int* __restrict__ cnt) {
  int e = blockIdx.x * 256 + threadIdx.x;
  const int stride = gridDim.x * 256;
  for (; e < E; e += stride) atomicAdd(&cnt[dst[e]], 1);
}

__global__ __launch_bounds__(256) void k_blocksum(const int* __restrict__ cnt,
                                                  int* __restrict__ bsum) {
  __shared__ int sh[256];
  const int t = threadIdx.x;
  sh[t] = cnt[blockIdx.x * 256 + t];
  __syncthreads();
#pragma unroll
  for (int o = 128; o; o >>= 1) {
    if (t < o) sh[t] += sh[t + o];
    __syncthreads();
  }
  if (!t) bsum[blockIdx.x] = sh[0];
}

__global__ __launch_bounds__(256) void k_scan_bsum(const int* __restrict__ bsum,
                                                   int* __restrict__ bpre, int NB) {
  __shared__ int sh[256];
  const int t = threadIdx.x;
  const int v = (t < NB) ? bsum[t] : 0;
  sh[t] = v;
  __syncthreads();
  for (int o = 1; o < 256; o <<= 1) {
    const int u = (t >= o) ? sh[t - o] : 0;
    __syncthreads();
    sh[t] += u;
    __syncthreads();
  }
  if (t < NB) bpre[t] = sh[t] - v;
}

__global__ __launch_bounds__(256) void k_apply(const int* __restrict__ cnt,
                                               const int* __restrict__ bpre,
                                               int* __restrict__ rowptr,
                                               int* __restrict__ cursor, int N) {
  __shared__ int sh[256];
  const int t = threadIdx.x;
  const int i = blockIdx.x * 256 + t;
  const int v = cnt[i];
  sh[t] = v;
  __syncthreads();
  for (int o = 1; o < 256; o <<= 1) {
    const int u = (t >= o) ? sh[t - o] : 0;
    __syncthreads();
    sh[t] += u;
    __syncthreads();
  }
  const int excl = sh[t] - v + bpre[blockIdx.x];
  if (i <= N) {
    rowptr[i] = excl;
    if (i < N) cursor[i] = excl;
  }
}

// permute src/dst/ew into CSR order
__global__ __launch_bounds__(256) void k_perm(const int* __restrict__ dst,
                                              const int* __restrict__ src,
                                              const float* __restrict__ ew, int E,
                                              int* __restrict__ cursor,
                                              int* __restrict__ perm,
                                              int* __restrict__ srcp,
                                              int* __restrict__ dstp,
                                              float* __restrict__ ewp) {
  int e = blockIdx.x * 256 + threadIdx.x;
  const int stride = gridDim.x * 256;
  for (; e < E; e += stride) {
    const int d = dst[e];
    const int p = atomicAdd(&cursor[d], 1);
    perm[p] = e;
    srcp[p] = src[e];
    dstp[p] = d;
    ewp[p] = ew[e];
  }
}

// ------------- prep: eapf[tile][half][lane][8] = bf16(ea[perm[i]] * ew) -----
// MFMA A-fragment order: lane l holds row (l&15), k = half*32 + (l>>4)*8 + j.
// Pure-BW kernel, no dependent chains in the consumer's hot loop afterwards.
__global__ __launch_bounds__(256) void prep_eapf(const float* __restrict__ ea,
                                                 const int* __restrict__ perm,
                                                 const float* __restrict__ ewp,
                                                 short* __restrict__ eapf, int E) {
  const int ntiles = (E + 15) >> 4;
  const int tile = blockIdx.x * 4 + (threadIdx.x >> 6);
  if (tile >= ntiles) return;
  const int lane = threadIdx.x & 63;
  const int row = tile * 16 + (lane & 15);
  const int k0 = (lane >> 4) * 8;
  float w = 0.f;
  int pe = 0;
  if (row < E) { pe = perm[row]; w = ewp[row]; }
  const float* er = ea + (size_t)pe * RBF + k0;
  const float4 x0 = *(const float4*)(er);
  const float4 x1 = *(const float4*)(er + 4);
  const float4 x2 = *(const float4*)(er + 32);
  const float4 x3 = *(const float4*)(er + 36);
  bf16x8 o0, o1;
  o0[0] = f2bf(x0.x * w); o0[1] = f2bf(x0.y * w);
  o0[2] = f2bf(x0.z * w); o0[3] = f2bf(x0.w * w);
  o0[4] = f2bf(x1.x * w); o0[5] = f2bf(x1.y * w);
  o0[6] = f2bf(x1.z * w); o0[7] = f2bf(x1.w * w);
  o1[0] = f2bf(x2.x * w); o1[1] = f2bf(x2.y * w);
  o1[2] = f2bf(x2.z * w); o1[3] = f2bf(x2.w * w);
  o1[4] = f2bf(x3.x * w); o1[5] = f2bf(x3.y * w);
  o1[6] = f2bf(x3.z * w); o1[7] = f2bf(x3.w * w);
  short* ob = eapf + (size_t)tile * 1024;
  *(bf16x8*)(ob + lane * 8) = o0;
  *(bf16x8*)(ob + 512 + lane * 8) = o1;
}

// ------------------------------------------- node projection: Y = [LN](X) @ W
template <bool DO_LN>
__global__ __launch_bounds__(256) void proj_kernel(const float* __restrict__ X,
                                                   const float* __restrict__ W,
                                                   const float* __restrict__ g,
                                                   const float* __restrict__ bb,
                                                   float* __restrict__ Y, int N) {
  __shared__ float At[128 * 68];
  const int row0 = blockIdx.x * 64;
  const int t = threadIdx.x;
  const int lk = (t & 31) * 4;
  const int lr = t >> 5;
  float4 g4 = {0, 0, 0, 0}, b4 = {0, 0, 0, 0};
  if (DO_LN) {
    g4 = *(const float4*)(g + lk);
    b4 = *(const float4*)(bb + lk);
  }
#pragma unroll
  for (int p = 0; p < 8; ++p) {
    const int r = lr + p * 8;
    const int row = row0 + r;
    float4 xv = make_float4(0.f, 0.f, 0.f, 0.f);
    if (row < N) xv = *(const float4*)(X + (size_t)row * H + lk);
    if (DO_LN) {
      float s = xv.x + xv.y + xv.z + xv.w;
      float q = xv.x * xv.x + xv.y * xv.y + xv.z * xv.z + xv.w * xv.w;
#pragma unroll
      for (int m = 16; m; m >>= 1) {
        s += __shfl_xor(s, m, 64);
        q += __shfl_xor(q, m, 64);
      }
      const float mu = s * 0.0078125f;
      const float var = q * 0.0078125f - mu * mu;
      const float rs = rsqrtf(var + 1e-5f);
      xv.x = (xv.x - mu) * rs * g4.x + b4.x;
      xv.y = (xv.y - mu) * rs * g4.y + b4.y;
      xv.z = (xv.z - mu) * rs * g4.z + b4.z;
      xv.w = (xv.w - mu) * rs * g4.w + b4.w;
    }
    At[(lk + 0) * 68 + r] = xv.x;
    At[(lk + 1) * 68 + r] = xv.y;
    At[(lk + 2) * 68 + r] = xv.z;
    At[(lk + 3) * 68 + r] = xv.w;
  }
  __syncthreads();
  const int tc = t & 15;
  const int tr = t >> 4;
  float acc[4][8];
#pragma unroll
  for (int i = 0; i < 4; ++i)
#pragma unroll
    for (int c = 0; c < 8; ++c) acc[i][c] = 0.f;
  const float* wbase = W + tc * 8;
#pragma unroll 4
  for (int k = 0; k < 128; ++k) {
    const float4 a4 = *(const float4*)(At + k * 68 + tr * 4);
    const float4 w0 = *(const float4*)(wbase + k * H);
    const float4 w1 = *(const float4*)(wbase + k * H + 4);
    const float av[4] = {a4.x, a4.y, a4.z, a4.w};
#pragma unroll
    for (int i = 0; i < 4; ++i) {
      acc[i][0] += av[i] * w0.x; acc[i][1] += av[i] * w0.y;
      acc[i][2] += av[i] * w0.z; acc[i][3] += av[i] * w0.w;
      acc[i][4] += av[i] * w1.x; acc[i][5] += av[i] * w1.y;
      acc[i][6] += av[i] * w1.z; acc[i][7] += av[i] * w1.w;
    }
  }
#pragma unroll
  for (int i = 0; i < 4; ++i) {
    const int row = row0 + tr * 4 + i;
    if (row < N) {
      float4 o0 = {acc[i][0], acc[i][1], acc[i][2], acc[i][3]};
      float4 o1 = {acc[i][4], acc[i][5], acc[i][6], acc[i][7]};
      float* yp = Y + (size_t)row * H + tc * 8;
      *(float4*)yp = o0;
      *(float4*)(yp + 4) = o1;
    }
  }
}

// ----------------------------------------- tiled MFMA edge gather (CSR)
// Block owns NPB dst nodes. Tiles are aligned to ABSOLUTE edge index 16q, so
// the pre-permuted frag array eapf is block-independent; boundary-tile edges
// belonging to neighbor blocks are masked to a dump row (dl=NPB).
// Hot loop has NO indirection except the P gather (L3-resident): A-frags and
// index vectors are sequential loads. No barriers; 2-deep named pipeline.
template <int NPB, bool FUSE_LN>
__global__ __launch_bounds__(256, 4) void gather_mfma(
    const float* __restrict__ P, const short* __restrict__ Web,
    const short* __restrict__ eapf, const int* __restrict__ srcp,
    const int* __restrict__ dstp, const int* __restrict__ rowptr, int N,
    const float* __restrict__ base, const float* __restrict__ skip,
    const float* __restrict__ g, const float* __restrict__ bb,
    float* __restrict__ out) {
  __shared__ float acc[(NPB + 1) * 132];
  const int t = threadIdx.x;
  const int w = t >> 6, lane = t & 63;
  const int n0 = blockIdx.x * NPB;
  for (int u = t; u < (NPB + 1) * 132; u += 256) acc[u] = 0.f;
  const int rp0 = rowptr[n0];
  const int rp1 = rowptr[min(n0 + NPB, N)];
  __syncthreads();
  const int q0 = rp0 >> 4;
  const int q1 = (rp1 + 15) >> 4;

  // B fragments for this wave's two 16-col blocks (16 VGPRs, loop-resident)
  const int c0 = 2 * w;
  const bf16x8 bw0 = *(const bf16x8*)(Web + ((size_t)((0 + c0) * 64 + lane)) * 8);
  const bf16x8 bw1 = *(const bf16x8*)(Web + ((size_t)((8 + c0) * 64 + lane)) * 8);
  const bf16x8 bw2 = *(const bf16x8*)(Web + ((size_t)((1 + c0) * 64 + lane)) * 8);
  const bf16x8 bw3 = *(const bf16x8*)(Web + ((size_t)((9 + c0) * 64 + lane)) * 8);

  const int l15 = lane & 15, lg = lane >> 4, rbase = lg * 4;
  const int col0 = c0 * 16 + l15;

  auto LOADI = [&](int q, bf16x8& A0, bf16x8& A1, int4& sp, int4& dp) {
    const short* fb = eapf + (size_t)q * 1024;
    A0 = *(const bf16x8*)(fb + lane * 8);
    A1 = *(const bf16x8*)(fb + 512 + lane * 8);
    sp = *(const int4*)(srcp + q * 16 + rbase);
    dp = *(const int4*)(dstp + q * 16 + rbase);
  };
  auto PLOAD = [&](const int4& sp, float* pv) {
    const float* p0 = P + (size_t)sp.x * H + col0;
    const float* p1 = P + (size_t)sp.y * H + col0;
    const float* p2 = P + (size_t)sp.z * H + col0;
    const float* p3 = P + (size_t)sp.w * H + col0;
    pv[0] = p0[0]; pv[4] = p0[16];
    pv[1] = p1[0]; pv[5] = p1[16];
    pv[2] = p2[0]; pv[6] = p2[16];
    pv[3] = p3[0]; pv[7] = p3[16];
  };
  auto COMP = [&](const bf16x8& A0, const bf16x8& A1, const float* pv,
                  const int4& dp) {
    f32x4 C0 = {0.f, 0.f, 0.f, 0.f};
    C0 = __builtin_amdgcn_mfma_f32_16x16x32_bf16(A0, bw0, C0, 0, 0, 0);
    C0 = __builtin_amdgcn_mfma_f32_16x16x32_bf16(A1, bw1, C0, 0, 0, 0);
    f32x4 C1 = {0.f, 0.f, 0.f, 0.f};
    C1 = __builtin_amdgcn_mfma_f32_16x16x32_bf16(A0, bw2, C1, 0, 0, 0);
    C1 = __builtin_amdgcn_mfma_f32_16x16x32_bf16(A1, bw3, C1, 0, 0, 0);
    const int dls[4] = {dp.x - n0, dp.y - n0, dp.z - n0, dp.w - n0};
#pragma unroll
    for (int j = 0; j < 4; ++j) {
      const int dl = ((unsigned)dls[j] < (unsigned)NPB) ? dls[j] : NPB;
      unsafeAtomicAdd(&acc[dl * 132 + col0], C0[j] * pv[j]);
      unsafeAtomicAdd(&acc[dl * 132 + col0 + 16], C1[j] * pv[4 + j]);
    }
  };

  if (q1 > q0) {
    bf16x8 A0a, A1a, A0b, A1b;
    int4 spa, dpa, spb, dpb;
    float pva[8], pvb[8];
    LOADI(q0, A0a, A1a, spa, dpa);
    PLOAD(spa, pva);
    for (int q = q0; q < q1; q += 2) {
      if (q + 1 < q1) { LOADI(q + 1, A0b, A1b, spb, dpb); PLOAD(spb, pvb); }
      COMP(A0a, A1a, pva, dpa);
      if (q + 2 < q1) { LOADI(q + 2, A0a, A1a, spa, dpa); PLOAD(spa, pva); }
      if (q + 1 < q1) COMP(A0b, A1b, pvb, dpb);
    }
  }
  __syncthreads();

  // ---- epilogue: one write per node, optional fused LN + base + skip
  for (int n = w; n < NPB; n += 4) {
    const int node = n0 + n;
    if (node >= N) break;
    const float v0 = acc[n * 132 + lane];
    const float v1 = acc[n * 132 + 64 + lane];
    const size_t i0 = (size_t)node * H + lane;
    if (FUSE_LN) {
      float s = v0 + v1, q = v0 * v0 + v1 * v1;
#pragma unroll
      for (int m = 32; m; m >>= 1) {
        s += __shfl_xor(s, m, 64);
        q += __shfl_xor(q, m, 64);
      }
      const float mu = s * 0.0078125f;
      const float var = q * 0.0078125f - mu * mu;
      const float rs = rsqrtf(var + 1e-5f);
      out[i0] = base[i0] + (v0 - mu) * rs * g[lane] + bb[lane] + skip[i0];
      out[i0 + 64] =
          base[i0 + 64] + (v1 - mu) * rs * g[lane + 64] + bb[lane + 64] + skip[i0 + 64];
    } else {
      out[i0] = v0;
      out[i0 + 64] = v1;
    }
  }
}

// ----------------------------------------------------------------- conv3d
__global__ __launch_bounds__(256) void conv3d(const float* __restrict__ Min,
                                              const float* __restrict__ Kt,
                                              const float* __restrict__ bias,
                                              float* __restrict__ Mout) {
  __shared__ float in_s[193 * 68];
  const int b = blockIdx.x >> 3;
  const int x = blockIdx.x & 7;
  const int t = threadIdx.x;
  const int tc = t & 15;
  const int tr = t >> 4;
  float acc[4][8];
  {
    const float4 bs0 = *(const float4*)(bias + tc * 8);
    const float4 bs1 = *(const float4*)(bias + tc * 8 + 4);
#pragma unroll
    for (int vi = 0; vi < 4; ++vi) {
      acc[vi][0] = bs0.x; acc[vi][1] = bs0.y; acc[vi][2] = bs0.z; acc[vi][3] = bs0.w;
      acc[vi][4] = bs1.x; acc[vi][5] = bs1.y; acc[vi][6] = bs1.z; acc[vi][7] = bs1.w;
    }
  }
  for (int u = t; u < 68; u += 256) in_s[192 * 68 + u] = 0.f;

  for (int pass = 0; pass < 2; ++pass) {
    __syncthreads();
#pragma unroll
    for (int it = 0; it < 12; ++it) {
      const int r = (t >> 4) + it * 16;
      const int c4 = (t & 15) * 4;
      const int xs = r >> 6;
      const int yz = r & 63;
      const int gx = x + xs - 1;
      float4 val = make_float4(0.f, 0.f, 0.f, 0.f);
      if (gx >= 0 && gx < 8) {
        const int row = (b * 8 + gx) * 64 + yz;
        val = *(const float4*)(Min + (size_t)row * H + pass * 64 + c4);
      }
      *(float4*)(in_s + r * 68 + c4) = val;
    }
    __syncthreads();

    for (int tap = 0; tap < 27; ++tap) {
      const int dx = tap / 9, dy = (tap / 3) % 3, dz = tap % 3;
      int rp[4];
#pragma unroll
      for (int vi = 0; vi < 4; ++vi) {
        const int v = tr * 4 + vi;
        const int y = v >> 3, z = v & 7;
        const int ny = y + dy - 1, nz = z + dz - 1;
        const bool ok = (ny >= 0 && ny < 8 && nz >= 0 && nz < 8);
        rp[vi] = ok ? (dx * 64 + ny * 8 + nz) * 68 : 192 * 68;
      }
      const float* wbase = Kt + ((size_t)tap * H + pass * 64) * H + tc * 8;
#pragma unroll 4
      for (int kk = 0; kk < 64; ++kk) {
        const float4 w0 = *(const float4*)(wbase + (size_t)kk * H);
        const float4 w1 = *(const float4*)(wbase + (size_t)kk * H + 4);
        float iv[4];
#pragma unroll
        for (int vi = 0; vi < 4; ++vi) iv[vi] = in_s[rp[vi] + kk];
#pragma unroll
        for (int vi = 0; vi < 4; ++vi) {
          acc[vi][0] += iv[vi] * w0.x; acc[vi][1] += iv[vi] * w0.y;
          acc[vi][2] += iv[vi] * w0.z; acc[vi][3] += iv[vi] * w0.w;
          acc[vi][4] += iv[vi] * w1.x; acc[vi][5] += iv[vi] * w1.y;
          acc[vi][6] += iv[vi] * w1.z; acc[vi][7] += iv[vi] * w1.w;
        }
      }
    }
  }
#pragma unroll
  for (int vi = 0; vi < 4; ++vi) {
    const int v = tr * 4 + vi;
    float* op = Mout + ((size_t)((b * 8 + x) * 64 + v)) * H + tc * 8;
    float4 o0 = {acc[vi][0], acc[vi][1], acc[vi][2], acc[vi][3]};
    float4 o1 = {acc[vi][4], acc[vi][5], acc[vi][6], acc[vi][7]};
    *(float4*)op = o0;
    *(float4*)(op + 4) = o1;
  }
}

// ------------------------------------------------------------------ driver
static inline void build_csr(const int* dst, const int* src, const float* ew,
                             int E, int N, int* cnt, int* bsum, int* bpre,
                             int* rowptr, int* cursor, int* perm, int* srcp,
                             int* dstp, float* ewp, hipStream_t stream) {
  const int NB = (N + 256) / 256;
  hipMemsetAsync(cnt, 0, (size_t)NB * 256 * sizeof(int), stream);
  k_hist<<<1024, 256, 0, stream>>>(dst, E, cnt);
  k_blocksum<<<NB, 256, 0, stream>>>(cnt, bsum);
  k_scan_bsum<<<1, 256, 0, stream>>>(bsum, bpre, NB);
  k_apply<<<NB, 256, 0, stream>>>(cnt, bpre, rowptr, cursor, N);
  k_perm<<<1024, 256, 0, stream>>>(dst, src, ew, E, cursor, perm, srcp, dstp, ewp);
}

extern "C" void kernel_launch(void* const* d_in, const int* in_sizes, int n_in,
                              void* d_out, int out_size, void* d_ws, size_t ws_size,
                              hipStream_t stream) {
  const float* a_x = (const float*)d_in[0];
  const float* m_x = (const float*)d_in[1];
  const int* aa_idx = (const int*)d_in[2];
  const int* a2m_src = (const int*)d_in[3];
  const int* a2m_dst = (const int*)d_in[4];
  const int* m2a_src = (const int*)d_in[5];
  const int* m2a_dst = (const int*)d_in[6];
  const float* aa_w = (const float*)d_in[7];
  const float* a2m_w = (const float*)d_in[8];
  const float* m2a_w = (const float*)d_in[9];
  const float* aa_ea = (const float*)d_in[10];
  const float* a2m_ea = (const float*)d_in[11];
  const float* m2a_ea = (const float*)d_in[12];
  const float* W_short = (const float*)d_in[13];
  const float* We_short = (const float*)d_in[14];
  const float* W_a2m = (const float*)d_in[15];
  const float* We_a2m = (const float*)d_in[16];
  const float* W_m2a = (const float*)d_in[17];
  const float* We_m2a = (const float*)d_in[18];
  const float* conv_k = (const float*)d_in[19];
  const float* conv_b = (const float*)d_in[20];
  const float* g_short = (const float*)d_in[21];
  const float* b_short = (const float*)d_in[22];
  const float* g_long = (const float*)d_in[23];
  const float* b_long = (const float*)d_in[24];
  const float* g_a2m = (const float*)d_in[25];
  const float* b_a2m = (const float*)d_in[26];
  const float* g_m2a = (const float*)d_in[27];
  const float* b_m2a = (const float*)d_in[28];

  const int NA = in_sizes[0] / H;
  const int NM = in_sizes[1] / H;
  const int E_AA = in_sizes[2] / 2;
  const int E_AM = in_sizes[3];
  const int E_MA = in_sizes[5];
  const int* aa_src = aa_idx;
  const int* aa_dst = aa_idx + E_AA;

  float* ws = (float*)d_ws;
  float* p_buf = ws;                         // NA*H
  float* m1_buf = p_buf + (size_t)NA * H;    // NM*H
  float* m2_buf = m1_buf + (size_t)NM * H;   // NM*H
  float* a2_buf = m2_buf + (size_t)NM * H;   // NA*H
  float* kt = a2_buf + (size_t)NA * H;       // 27*H*H
  float* ewp_sh = kt + (size_t)27 * H * H;   // max E (shared across sets)
  short* web_aa = (short*)(ewp_sh + E_AA);
  short* web_a2m = web_aa + 8192;
  short* web_m2a = web_a2m + 8192;
  int* iws = (int*)(web_m2a + 8192);
  int* perm_sh = iws;   iws += E_AA;          // shared across sets
  int* srcp_aa = iws;   iws += E_AA;
  int* srcp_a2m = iws;  iws += E_AM;
  int* srcp_m2a = iws;  iws += E_MA;
  int* dstp_aa = iws;   iws += E_AA;
  int* dstp_a2m = iws;  iws += E_AM;
  int* dstp_m2a = iws;  iws += E_MA;
  int* rp_aa = iws;     iws += NA + 1;
  int* rp_a2m = iws;    iws += NM + 1;
  int* rp_m2a = iws;    iws += NA + 1;
  const int PADN = ((NA + 256) / 256) * 256;
  int* cnt = iws;       iws += PADN;
  int* cursor = iws;    iws += PADN;
  int* bsum = iws;      iws += 256;
  int* bpre = iws;      iws += 256;
  short* eapf = (short*)iws;  // shared: max tiles (E_AA/16) * 1024 shorts

  float* out_a = (float*)d_out;
  float* out_m = out_a + (size_t)NA * H;

  // ---- independent prep
  pack_we<<<4, 256, 0, stream>>>(We_short, web_aa);
  pack_we<<<4, 256, 0, stream>>>(We_a2m, web_a2m);
  pack_we<<<4, 256, 0, stream>>>(We_m2a, web_m2a);
  transpose_k<<<(H * H * 27 + 255) / 256, 256, 0, stream>>>(conv_k, kt);
  ln_rows<<<NM, 128, 0, stream>>>(m_x, g_long, b_long, m1_buf, NM);
  conv3d<<<(NM / 64), 256, 0, stream>>>(m1_buf, kt, conv_b, m2_buf);
  proj_kernel<true><<<(NA + 63) / 64, 256, 0, stream>>>(a_x, W_short, g_short,
                                                        b_short, p_buf, NA);

  // ---- AA: csr -> prep -> gather (eapf/perm/ewp shared, stream-ordered)
  build_csr(aa_dst, aa_src, aa_w, E_AA, NA, cnt, bsum, bpre, rp_aa, cursor,
            perm_sh, srcp_aa, dstp_aa, ewp_sh, stream);
  prep_eapf<<<(((E_AA + 15) / 16) + 3) / 4, 256, 0, stream>>>(aa_ea, perm_sh,
                                                              ewp_sh, eapf, E_AA);
  gather_mfma<32, false><<<(NA + 31) / 32, 256, 0, stream>>>(
      p_buf, web_aa, eapf, srcp_aa, dstp_aa, rp_aa, NA, nullptr, nullptr,
      nullptr, nullptr, a2_buf);

  // ---- a2m
  build_csr(a2m_dst, a2m_src, a2m_w, E_AM, NM, cnt, bsum, bpre, rp_a2m, cursor,
            perm_sh, srcp_a2m, dstp_a2m, ewp_sh, stream);
  prep_eapf<<<(((E_AM + 15) / 16) + 3) / 4, 256, 0, stream>>>(a2m_ea, perm_sh,
                                                              ewp_sh, eapf, E_AM);
  proj_kernel<false><<<(NA + 63) / 64, 256, 0, stream>>>(a2_buf, W_a2m, nullptr,
                                                         nullptr, p_buf, NA);
  gather_mfma<16, true><<<(NM + 15) / 16, 256, 0, stream>>>(
      p_buf, web_a2m, eapf, srcp_a2m, dstp_a2m, rp_a2m, NM, m2_buf, m_x,
      g_a2m, b_a2m, out_m);

  // ---- m2a
  build_csr(m2a_dst, m2a_src, m2a_w, E_MA, NA, cnt, bsum, bpre, rp_m2a, cursor,
            perm_sh, srcp_m2a, dstp_m2a, ewp_sh, stream);
  prep_eapf<<<(((E_MA + 15) / 16) + 3) / 4, 256, 0, stream>>>(m2a_ea, perm_sh,
                                                              ewp_sh, eapf, E_MA);
  proj_kernel<false><<<(NM + 63) / 64, 256, 0, stream>>>(m2_buf, W_m2a, nullptr,
                                                         nullptr, m1_buf, NM);
  gather_mfma<32, true><<<(NA + 31) / 32, 256, 0, stream>>>(
      m1_buf, web_m2a, eapf, srcp_m2a, dstp_m2a, rp_m2a, NA, a2_buf, a_x,
      g_m2a, b_m2a, out_a);
}

// Round 8
// 1058.103 us; speedup vs baseline: 2.0306x; 1.9808x over previous
//
#include <hip/hip_runtime.h>
#include <hip/hip_bf16.h>

#define H 128
#define RBF 64

typedef __attribute__((ext_vector_type(8))) short bf16x8;
typedef __attribute__((ext_vector_type(4))) float f32x4;

__device__ inline short f2bf(float f) {
  union { float f; unsigned u; } v; v.f = f;
  const unsigned r = (v.u + 0x7FFFu + ((v.u >> 16) & 1u)) >> 16;
  return (short)r;
}

// ---------------------------------------------------------------- utilities
__global__ __launch_bounds__(128) void ln_rows(const float* __restrict__ X,
                                               const float* __restrict__ g,
                                               const float* __restrict__ bb,
                                               float* __restrict__ Y, int N) {
  __shared__ float sh[4];
  const int row = blockIdx.x;
  const int j = threadIdx.x;
  float x = X[(size_t)row * H + j];
  float s = x, q = x * x;
#pragma unroll
  for (int m = 32; m; m >>= 1) {
    s += __shfl_xor(s, m, 64);
    q += __shfl_xor(q, m, 64);
  }
  if ((j & 63) == 0) { sh[(j >> 6) * 2] = s; sh[(j >> 6) * 2 + 1] = q; }
  __syncthreads();
  s = sh[0] + sh[2];
  q = sh[1] + sh[3];
  const float mu = s * 0.0078125f;
  const float var = q * 0.0078125f - mu * mu;
  const float rs = rsqrtf(var + 1e-5f);
  Y[(size_t)row * H + j] = (x - mu) * rs * g[j] + bb[j];
}

// conv_k (o,i,dx,dy,dz) -> Kt[tap][i][o]
__global__ void transpose_k(const float* __restrict__ K, float* __restrict__ Kt) {
  const int idx = blockIdx.x * 256 + threadIdx.x;
  const int total = H * H * 27;
  if (idx >= total) return;
  const int tap = idx % 27;
  const int rem = idx / 27;
  const int i = rem % H;
  const int o = rem / H;
  Kt[((size_t)tap * H + i) * H + o] = K[idx];
}

// We[64][128] f32 -> frag-layout bf16: Web[((h*8+c)*64+lane)*8+j]
__global__ __launch_bounds__(256) void pack_we(const float* __restrict__ We,
                                               short* __restrict__ Web) {
  const int id = blockIdx.x * 256 + threadIdx.x;
  if (id >= 1024) return;
  const int f = id >> 6, l = id & 63;
  const int h = f >> 3, c = f & 7;
  const int col = (c << 4) + (l & 15);
  const int k0 = h * 32 + (l >> 4) * 8;
  short* o = Web + (size_t)id * 8;
#pragma unroll
  for (int j = 0; j < 8; ++j) o[j] = f2bf(We[(k0 + j) * H + col]);
}

// ----------------------------------------------- counting-sort (CSR builder)
__global__ __launch_bounds__(256) void k_hist(const int* __restrict__ dst, int E,
                                              int* __restrict__ cnt) {
  int e = blockIdx.x * 256 + threadIdx.x;
  const int stride = gridDim.x * 256;
  for (; e < E; e += stride) atomicAdd(&cnt[dst[e]], 1);
}

__global__ __launch_bounds__(256) void k_blocksum(const int* __restrict__ cnt,
                                                  int* __restrict__ bsum) {
  __shared__ int sh[256];
  const int t = threadIdx.x;
  sh[t] = cnt[blockIdx.x * 256 + t];
  __syncthreads();
#pragma unroll
  for (int o = 128; o; o >>= 1) {
    if (t < o) sh[t] += sh[t + o];
    __syncthreads();
  }
  if (!t) bsum[blockIdx.x] = sh[0];
}

__global__ __launch_bounds__(256) void k_scan_bsum(const int* __restrict__ bsum,
                                                   int* __restrict__ bpre, int NB) {
  __shared__ int sh[256];
  const int t = threadIdx.x;
  const int v = (t < NB) ? bsum[t] : 0;
  sh[t] = v;
  __syncthreads();
  for (int o = 1; o < 256; o <<= 1) {
    const int u = (t >= o) ? sh[t - o] : 0;
    __syncthreads();
    sh[t] += u;
    __syncthreads();
  }
  if (t < NB) bpre[t] = sh[t] - v;
}

__global__ __launch_bounds__(256) void k_apply(const int* __restrict__ cnt,
                                               const int* __restrict__ bpre,
                                               int* __restrict__ rowptr,
                                               int* __restrict__ cursor, int N) {
  __shared__ int sh[256];
  const int t = threadIdx.x;
  const int i = blockIdx.x * 256 + t;
  const int v = cnt[i];
  sh[t] = v;
  __syncthreads();
  for (int o = 1; o < 256; o <<= 1) {
    const int u = (t >= o) ? sh[t - o] : 0;
    __syncthreads();
    sh[t] += u;
    __syncthreads();
  }
  const int excl = sh[t] - v + bpre[blockIdx.x];
  if (i <= N) {
    rowptr[i] = excl;
    if (i < N) cursor[i] = excl;
  }
}

// permute src/dst/ew into CSR order
__global__ __launch_bounds__(256) void k_perm(const int* __restrict__ dst,
                                              const int* __restrict__ src,
                                              const float* __restrict__ ew, int E,
                                              int* __restrict__ cursor,
                                              int* __restrict__ perm,
                                              int* __restrict__ srcp,
                                              int* __restrict__ dstp,
                                              float* __restrict__ ewp) {
  int e = blockIdx.x * 256 + threadIdx.x;
  const int stride = gridDim.x * 256;
  for (; e < E; e += stride) {
    const int d = dst[e];
    const int p = atomicAdd(&cursor[d], 1);
    perm[p] = e;
    srcp[p] = src[e];
    dstp[p] = d;
    ewp[p] = ew[e];
  }
}

// ------------- prep: eapf[tile][half][lane][8] = bf16(ea[perm[i]] * ew) -----
__global__ __launch_bounds__(256) void prep_eapf(const float* __restrict__ ea,
                                                 const int* __restrict__ perm,
                                                 const float* __restrict__ ewp,
                                                 short* __restrict__ eapf, int E) {
  const int ntiles = (E + 15) >> 4;
  const int tile = blockIdx.x * 4 + (threadIdx.x >> 6);
  if (tile >= ntiles) return;
  const int lane = threadIdx.x & 63;
  const int row = tile * 16 + (lane & 15);
  const int k0 = (lane >> 4) * 8;
  float w = 0.f;
  int pe = 0;
  if (row < E) { pe = perm[row]; w = ewp[row]; }
  const float* er = ea + (size_t)pe * RBF + k0;
  const float4 x0 = *(const float4*)(er);
  const float4 x1 = *(const float4*)(er + 4);
  const float4 x2 = *(const float4*)(er + 32);
  const float4 x3 = *(const float4*)(er + 36);
  bf16x8 o0, o1;
  o0[0] = f2bf(x0.x * w); o0[1] = f2bf(x0.y * w);
  o0[2] = f2bf(x0.z * w); o0[3] = f2bf(x0.w * w);
  o0[4] = f2bf(x1.x * w); o0[5] = f2bf(x1.y * w);
  o0[6] = f2bf(x1.z * w); o0[7] = f2bf(x1.w * w);
  o1[0] = f2bf(x2.x * w); o1[1] = f2bf(x2.y * w);
  o1[2] = f2bf(x2.z * w); o1[3] = f2bf(x2.w * w);
  o1[4] = f2bf(x3.x * w); o1[5] = f2bf(x3.y * w);
  o1[6] = f2bf(x3.z * w); o1[7] = f2bf(x3.w * w);
  short* ob = eapf + (size_t)tile * 1024;
  *(bf16x8*)(ob + lane * 8) = o0;
  *(bf16x8*)(ob + 512 + lane * 8) = o1;
}

// ------------------------------------------- node projection: Y = [LN](X) @ W
template <bool DO_LN>
__global__ __launch_bounds__(256) void proj_kernel(const float* __restrict__ X,
                                                   const float* __restrict__ W,
                                                   const float* __restrict__ g,
                                                   const float* __restrict__ bb,
                                                   float* __restrict__ Y, int N) {
  __shared__ float At[128 * 68];
  const int row0 = blockIdx.x * 64;
  const int t = threadIdx.x;
  const int lk = (t & 31) * 4;
  const int lr = t >> 5;
  float4 g4 = {0, 0, 0, 0}, b4 = {0, 0, 0, 0};
  if (DO_LN) {
    g4 = *(const float4*)(g + lk);
    b4 = *(const float4*)(bb + lk);
  }
#pragma unroll
  for (int p = 0; p < 8; ++p) {
    const int r = lr + p * 8;
    const int row = row0 + r;
    float4 xv = make_float4(0.f, 0.f, 0.f, 0.f);
    if (row < N) xv = *(const float4*)(X + (size_t)row * H + lk);
    if (DO_LN) {
      float s = xv.x + xv.y + xv.z + xv.w;
      float q = xv.x * xv.x + xv.y * xv.y + xv.z * xv.z + xv.w * xv.w;
#pragma unroll
      for (int m = 16; m; m >>= 1) {
        s += __shfl_xor(s, m, 64);
        q += __shfl_xor(q, m, 64);
      }
      const float mu = s * 0.0078125f;
      const float var = q * 0.0078125f - mu * mu;
      const float rs = rsqrtf(var + 1e-5f);
      xv.x = (xv.x - mu) * rs * g4.x + b4.x;
      xv.y = (xv.y - mu) * rs * g4.y + b4.y;
      xv.z = (xv.z - mu) * rs * g4.z + b4.z;
      xv.w = (xv.w - mu) * rs * g4.w + b4.w;
    }
    At[(lk + 0) * 68 + r] = xv.x;
    At[(lk + 1) * 68 + r] = xv.y;
    At[(lk + 2) * 68 + r] = xv.z;
    At[(lk + 3) * 68 + r] = xv.w;
  }
  __syncthreads();
  const int tc = t & 15;
  const int tr = t >> 4;
  float acc[4][8];
#pragma unroll
  for (int i = 0; i < 4; ++i)
#pragma unroll
    for (int c = 0; c < 8; ++c) acc[i][c] = 0.f;
  const float* wbase = W + tc * 8;
#pragma unroll 4
  for (int k = 0; k < 128; ++k) {
    const float4 a4 = *(const float4*)(At + k * 68 + tr * 4);
    const float4 w0 = *(const float4*)(wbase + k * H);
    const float4 w1 = *(const float4*)(wbase + k * H + 4);
    const float av[4] = {a4.x, a4.y, a4.z, a4.w};
#pragma unroll
    for (int i = 0; i < 4; ++i) {
      acc[i][0] += av[i] * w0.x; acc[i][1] += av[i] * w0.y;
      acc[i][2] += av[i] * w0.z; acc[i][3] += av[i] * w0.w;
      acc[i][4] += av[i] * w1.x; acc[i][5] += av[i] * w1.y;
      acc[i][6] += av[i] * w1.z; acc[i][7] += av[i] * w1.w;
    }
  }
#pragma unroll
  for (int i = 0; i < 4; ++i) {
    const int row = row0 + tr * 4 + i;
    if (row < N) {
      float4 o0 = {acc[i][0], acc[i][1], acc[i][2], acc[i][3]};
      float4 o1 = {acc[i][4], acc[i][5], acc[i][6], acc[i][7]};
      float* yp = Y + (size_t)row * H + tc * 8;
      *(float4*)yp = o0;
      *(float4*)(yp + 4) = o1;
    }
  }
}

// ----------------------------------------- tiled MFMA edge gather (CSR)
// R8 change: NO LDS ATOMICS. 4 lg-replicated accumulators (lane (lg,l15)
// writes only replica lg / its own columns -> no address ever shared by two
// lanes), plus in-lane merge of adjacent equal-dst rows before a plain
// ds_read+add+ds_write flush. Replica stride padded so the active lg groups
// cover disjoint bank halves (2 lanes/bank = free).
template <int NPB, bool FUSE_LN>
__global__ __launch_bounds__(256, 4) void gather_mfma(
    const float* __restrict__ P, const short* __restrict__ Web,
    const short* __restrict__ eapf, const int* __restrict__ srcp,
    const int* __restrict__ dstp, const int* __restrict__ rowptr, int N,
    const float* __restrict__ base, const float* __restrict__ skip,
    const float* __restrict__ g, const float* __restrict__ bb,
    float* __restrict__ out) {
  constexpr int RSTR = (NPB + 1) * 132;                       // dwords/replica
  constexpr int RPAD = RSTR + ((16 - (RSTR & 31)) & 31);      // ≡16 (mod 32)
  __shared__ float acc[4 * RPAD];
  const int t = threadIdx.x;
  const int w = t >> 6, lane = t & 63;
  const int n0 = blockIdx.x * NPB;
  for (int u = t; u < 4 * RPAD; u += 256) acc[u] = 0.f;
  const int rp0 = rowptr[n0];
  const int rp1 = rowptr[min(n0 + NPB, N)];
  __syncthreads();
  const int q0 = rp0 >> 4;
  const int q1 = (rp1 + 15) >> 4;

  // B fragments for this wave's two 16-col blocks (16 VGPRs, loop-resident)
  const int c0 = 2 * w;
  const bf16x8 bw0 = *(const bf16x8*)(Web + ((size_t)((0 + c0) * 64 + lane)) * 8);
  const bf16x8 bw1 = *(const bf16x8*)(Web + ((size_t)((8 + c0) * 64 + lane)) * 8);
  const bf16x8 bw2 = *(const bf16x8*)(Web + ((size_t)((1 + c0) * 64 + lane)) * 8);
  const bf16x8 bw3 = *(const bf16x8*)(Web + ((size_t)((9 + c0) * 64 + lane)) * 8);

  const int l15 = lane & 15, lg = lane >> 4, rbase = lg * 4;
  const int col0 = c0 * 16 + l15;
  float* const arep = acc + lg * RPAD;  // this lane's private replica

  auto LOADI = [&](int q, bf16x8& A0, bf16x8& A1, int4& sp, int4& dp) {
    const short* fb = eapf + (size_t)q * 1024;
    A0 = *(const bf16x8*)(fb + lane * 8);
    A1 = *(const bf16x8*)(fb + 512 + lane * 8);
    sp = *(const int4*)(srcp + q * 16 + rbase);
    dp = *(const int4*)(dstp + q * 16 + rbase);
  };
  auto PLOAD = [&](const int4& sp, float* pv) {
    const float* p0 = P + (size_t)sp.x * H + col0;
    const float* p1 = P + (size_t)sp.y * H + col0;
    const float* p2 = P + (size_t)sp.z * H + col0;
    const float* p3 = P + (size_t)sp.w * H + col0;
    pv[0] = p0[0]; pv[4] = p0[16];
    pv[1] = p1[0]; pv[5] = p1[16];
    pv[2] = p2[0]; pv[6] = p2[16];
    pv[3] = p3[0]; pv[7] = p3[16];
  };
  auto COMP = [&](const bf16x8& A0, const bf16x8& A1, const float* pv,
                  const int4& dp) {
    f32x4 C0 = {0.f, 0.f, 0.f, 0.f};
    C0 = __builtin_amdgcn_mfma_f32_16x16x32_bf16(A0, bw0, C0, 0, 0, 0);
    C0 = __builtin_amdgcn_mfma_f32_16x16x32_bf16(A1, bw1, C0, 0, 0, 0);
    f32x4 C1 = {0.f, 0.f, 0.f, 0.f};
    C1 = __builtin_amdgcn_mfma_f32_16x16x32_bf16(A0, bw2, C1, 0, 0, 0);
    C1 = __builtin_amdgcn_mfma_f32_16x16x32_bf16(A1, bw3, C1, 0, 0, 0);
    const int dls[4] = {dp.x - n0, dp.y - n0, dp.z - n0, dp.w - n0};
    int dl[5];
#pragma unroll
    for (int j = 0; j < 4; ++j)
      dl[j] = ((unsigned)dls[j] < (unsigned)NPB) ? dls[j] : NPB;
    dl[4] = -1;  // sentinel: forces flush at j=3
    float c0v = 0.f, c1v = 0.f;
#pragma unroll
    for (int j = 0; j < 4; ++j) {
      c0v += C0[j] * pv[j];
      c1v += C1[j] * pv[4 + j];
      if (dl[j + 1] != dl[j]) {  // adjacent-merge flush (race-free: see above)
        float* a0 = arep + dl[j] * 132 + col0;
        a0[0] += c0v;
        a0[16] += c1v;
        c0v = 0.f;
        c1v = 0.f;
      }
    }
  };

  if (q1 > q0) {
    bf16x8 A0a, A1a, A0b, A1b;
    int4 spa, dpa, spb, dpb;
    float pva[8], pvb[8];
    LOADI(q0, A0a, A1a, spa, dpa);
    PLOAD(spa, pva);
    for (int q = q0; q < q1; q += 2) {
      if (q + 1 < q1) { LOADI(q + 1, A0b, A1b, spb, dpb); PLOAD(spb, pvb); }
      COMP(A0a, A1a, pva, dpa);
      if (q + 2 < q1) { LOADI(q + 2, A0a, A1a, spa, dpa); PLOAD(spa, pva); }
      if (q + 1 < q1) COMP(A0b, A1b, pvb, dpb);
    }
  }
  __syncthreads();

  // ---- epilogue: sum the 4 replicas; one write per node; optional LN fuse
  for (int n = w; n < NPB; n += 4) {
    const int node = n0 + n;
    if (node >= N) break;
    const int rb = n * 132 + lane;
    const float v0 = acc[rb] + acc[RPAD + rb] + acc[2 * RPAD + rb] +
                     acc[3 * RPAD + rb];
    const float v1 = acc[rb + 64] + acc[RPAD + rb + 64] +
                     acc[2 * RPAD + rb + 64] + acc[3 * RPAD + rb + 64];
    const size_t i0 = (size_t)node * H + lane;
    if (FUSE_LN) {
      float s = v0 + v1, q = v0 * v0 + v1 * v1;
#pragma unroll
      for (int m = 32; m; m >>= 1) {
        s += __shfl_xor(s, m, 64);
        q += __shfl_xor(q, m, 64);
      }
      const float mu = s * 0.0078125f;
      const float var = q * 0.0078125f - mu * mu;
      const float rs = rsqrtf(var + 1e-5f);
      out[i0] = base[i0] + (v0 - mu) * rs * g[lane] + bb[lane] + skip[i0];
      out[i0 + 64] =
          base[i0 + 64] + (v1 - mu) * rs * g[lane + 64] + bb[lane + 64] + skip[i0 + 64];
    } else {
      out[i0] = v0;
      out[i0 + 64] = v1;
    }
  }
}

// ----------------------------------------------------------------- conv3d
__global__ __launch_bounds__(256) void conv3d(const float* __restrict__ Min,
                                              const float* __restrict__ Kt,
                                              const float* __restrict__ bias,
                                              float* __restrict__ Mout) {
  __shared__ float in_s[193 * 68];
  const int b = blockIdx.x >> 3;
  const int x = blockIdx.x & 7;
  const int t = threadIdx.x;
  const int tc = t & 15;
  const int tr = t >> 4;
  float acc[4][8];
  {
    const float4 bs0 = *(const float4*)(bias + tc * 8);
    const float4 bs1 = *(const float4*)(bias + tc * 8 + 4);
#pragma unroll
    for (int vi = 0; vi < 4; ++vi) {
      acc[vi][0] = bs0.x; acc[vi][1] = bs0.y; acc[vi][2] = bs0.z; acc[vi][3] = bs0.w;
      acc[vi][4] = bs1.x; acc[vi][5] = bs1.y; acc[vi][6] = bs1.z; acc[vi][7] = bs1.w;
    }
  }
  for (int u = t; u < 68; u += 256) in_s[192 * 68 + u] = 0.f;

  for (int pass = 0; pass < 2; ++pass) {
    __syncthreads();
#pragma unroll
    for (int it = 0; it < 12; ++it) {
      const int r = (t >> 4) + it * 16;
      const int c4 = (t & 15) * 4;
      const int xs = r >> 6;
      const int yz = r & 63;
      const int gx = x + xs - 1;
      float4 val = make_float4(0.f, 0.f, 0.f, 0.f);
      if (gx >= 0 && gx < 8) {
        const int row = (b * 8 + gx) * 64 + yz;
        val = *(const float4*)(Min + (size_t)row * H + pass * 64 + c4);
      }
      *(float4*)(in_s + r * 68 + c4) = val;
    }
    __syncthreads();

    for (int tap = 0; tap < 27; ++tap) {
      const int dx = tap / 9, dy = (tap / 3) % 3, dz = tap % 3;
      int rp[4];
#pragma unroll
      for (int vi = 0; vi < 4; ++vi) {
        const int v = tr * 4 + vi;
        const int y = v >> 3, z = v & 7;
        const int ny = y + dy - 1, nz = z + dz - 1;
        const bool ok = (ny >= 0 && ny < 8 && nz >= 0 && nz < 8);
        rp[vi] = ok ? (dx * 64 + ny * 8 + nz) * 68 : 192 * 68;
      }
      const float* wbase = Kt + ((size_t)tap * H + pass * 64) * H + tc * 8;
#pragma unroll 4
      for (int kk = 0; kk < 64; ++kk) {
        const float4 w0 = *(const float4*)(wbase + (size_t)kk * H);
        const float4 w1 = *(const float4*)(wbase + (size_t)kk * H + 4);
        float iv[4];
#pragma unroll
        for (int vi = 0; vi < 4; ++vi) iv[vi] = in_s[rp[vi] + kk];
#pragma unroll
        for (int vi = 0; vi < 4; ++vi) {
          acc[vi][0] += iv[vi] * w0.x; acc[vi][1] += iv[vi] * w0.y;
          acc[vi][2] += iv[vi] * w0.z; acc[vi][3] += iv[vi] * w0.w;
          acc[vi][4] += iv[vi] * w1.x; acc[vi][5] += iv[vi] * w1.y;
          acc[vi][6] += iv[vi] * w1.z; acc[vi][7] += iv[vi] * w1.w;
        }
      }
    }
  }
#pragma unroll
  for (int vi = 0; vi < 4; ++vi) {
    const int v = tr * 4 + vi;
    float* op = Mout + ((size_t)((b * 8 + x) * 64 + v)) * H + tc * 8;
    float4 o0 = {acc[vi][0], acc[vi][1], acc[vi][2], acc[vi][3]};
    float4 o1 = {acc[vi][4], acc[vi][5], acc[vi][6], acc[vi][7]};
    *(float4*)op = o0;
    *(float4*)(op + 4) = o1;
  }
}

// ------------------------------------------------------------------ driver
static inline void build_csr(const int* dst, const int* src, const float* ew,
                             int E, int N, int* cnt, int* bsum, int* bpre,
                             int* rowptr, int* cursor, int* perm, int* srcp,
                             int* dstp, float* ewp, hipStream_t stream) {
  const int NB = (N + 256) / 256;
  hipMemsetAsync(cnt, 0, (size_t)NB * 256 * sizeof(int), stream);
  k_hist<<<1024, 256, 0, stream>>>(dst, E, cnt);
  k_blocksum<<<NB, 256, 0, stream>>>(cnt, bsum);
  k_scan_bsum<<<1, 256, 0, stream>>>(bsum, bpre, NB);
  k_apply<<<NB, 256, 0, stream>>>(cnt, bpre, rowptr, cursor, N);
  k_perm<<<1024, 256, 0, stream>>>(dst, src, ew, E, cursor, perm, srcp, dstp, ewp);
  // pad tail-tile reads: dstp pad = -1 (maps to dump row), srcp pad = 0
  hipMemsetAsync(srcp + E, 0, 16 * sizeof(int), stream);
  hipMemsetAsync(dstp + E, 0xFF, 16 * sizeof(int), stream);
}

extern "C" void kernel_launch(void* const* d_in, const int* in_sizes, int n_in,
                              void* d_out, int out_size, void* d_ws, size_t ws_size,
                              hipStream_t stream) {
  const float* a_x = (const float*)d_in[0];
  const float* m_x = (const float*)d_in[1];
  const int* aa_idx = (const int*)d_in[2];
  const int* a2m_src = (const int*)d_in[3];
  const int* a2m_dst = (const int*)d_in[4];
  const int* m2a_src = (const int*)d_in[5];
  const int* m2a_dst = (const int*)d_in[6];
  const float* aa_w = (const float*)d_in[7];
  const float* a2m_w = (const float*)d_in[8];
  const float* m2a_w = (const float*)d_in[9];
  const float* aa_ea = (const float*)d_in[10];
  const float* a2m_ea = (const float*)d_in[11];
  const float* m2a_ea = (const float*)d_in[12];
  const float* W_short = (const float*)d_in[13];
  const float* We_short = (const float*)d_in[14];
  const float* W_a2m = (const float*)d_in[15];
  const float* We_a2m = (const float*)d_in[16];
  const float* W_m2a = (const float*)d_in[17];
  const float* We_m2a = (const float*)d_in[18];
  const float* conv_k = (const float*)d_in[19];
  const float* conv_b = (const float*)d_in[20];
  const float* g_short = (const float*)d_in[21];
  const float* b_short = (const float*)d_in[22];
  const float* g_long = (const float*)d_in[23];
  const float* b_long = (const float*)d_in[24];
  const float* g_a2m = (const float*)d_in[25];
  const float* b_a2m = (const float*)d_in[26];
  const float* g_m2a = (const float*)d_in[27];
  const float* b_m2a = (const float*)d_in[28];

  const int NA = in_sizes[0] / H;
  const int NM = in_sizes[1] / H;
  const int E_AA = in_sizes[2] / 2;
  const int E_AM = in_sizes[3];
  const int E_MA = in_sizes[5];
  const int* aa_src = aa_idx;
  const int* aa_dst = aa_idx + E_AA;

  float* ws = (float*)d_ws;
  float* p_buf = ws;                         // NA*H
  float* m1_buf = p_buf + (size_t)NA * H;    // NM*H
  float* m2_buf = m1_buf + (size_t)NM * H;   // NM*H
  float* a2_buf = m2_buf + (size_t)NM * H;   // NA*H
  float* kt = a2_buf + (size_t)NA * H;       // 27*H*H
  float* ewp_sh = kt + (size_t)27 * H * H;   // max E (shared across sets)
  short* web_aa = (short*)(ewp_sh + E_AA);
  short* web_a2m = web_aa + 8192;
  short* web_m2a = web_a2m + 8192;
  int* iws = (int*)(web_m2a + 8192);
  int* perm_sh = iws;   iws += E_AA;          // shared across sets
  int* srcp_aa = iws;   iws += E_AA + 16;     // +16 pad for tail tiles
  int* srcp_a2m = iws;  iws += E_AM + 16;
  int* srcp_m2a = iws;  iws += E_MA + 16;
  int* dstp_aa = iws;   iws += E_AA + 16;
  int* dstp_a2m = iws;  iws += E_AM + 16;
  int* dstp_m2a = iws;  iws += E_MA + 16;
  int* rp_aa = iws;     iws += NA + 1;
  int* rp_a2m = iws;    iws += NM + 1;
  int* rp_m2a = iws;    iws += NA + 1;
  const int PADN = ((NA + 256) / 256) * 256;
  int* cnt = iws;       iws += PADN;
  int* cursor = iws;    iws += PADN;
  int* bsum = iws;      iws += 256;
  int* bpre = iws;      iws += 256;
  short* eapf = (short*)iws;  // shared: max tiles (E_AA/16) * 1024 shorts

  float* out_a = (float*)d_out;
  float* out_m = out_a + (size_t)NA * H;

  // ---- independent prep
  pack_we<<<4, 256, 0, stream>>>(We_short, web_aa);
  pack_we<<<4, 256, 0, stream>>>(We_a2m, web_a2m);
  pack_we<<<4, 256, 0, stream>>>(We_m2a, web_m2a);
  transpose_k<<<(H * H * 27 + 255) / 256, 256, 0, stream>>>(conv_k, kt);
  ln_rows<<<NM, 128, 0, stream>>>(m_x, g_long, b_long, m1_buf, NM);
  conv3d<<<(NM / 64), 256, 0, stream>>>(m1_buf, kt, conv_b, m2_buf);
  proj_kernel<true><<<(NA + 63) / 64, 256, 0, stream>>>(a_x, W_short, g_short,
                                                        b_short, p_buf, NA);

  // ---- AA: csr -> prep -> gather
  build_csr(aa_dst, aa_src, aa_w, E_AA, NA, cnt, bsum, bpre, rp_aa, cursor,
            perm_sh, srcp_aa, dstp_aa, ewp_sh, stream);
  prep_eapf<<<(((E_AA + 15) / 16) + 3) / 4, 256, 0, stream>>>(aa_ea, perm_sh,
                                                              ewp_sh, eapf, E_AA);
  gather_mfma<16, false><<<(NA + 15) / 16, 256, 0, stream>>>(
      p_buf, web_aa, eapf, srcp_aa, dstp_aa, rp_aa, NA, nullptr, nullptr,
      nullptr, nullptr, a2_buf);

  // ---- a2m
  build_csr(a2m_dst, a2m_src, a2m_w, E_AM, NM, cnt, bsum, bpre, rp_a2m, cursor,
            perm_sh, srcp_a2m, dstp_a2m, ewp_sh, stream);
  prep_eapf<<<(((E_AM + 15) / 16) + 3) / 4, 256, 0, stream>>>(a2m_ea, perm_sh,
                                                              ewp_sh, eapf, E_AM);
  proj_kernel<false><<<(NA + 63) / 64, 256, 0, stream>>>(a2_buf, W_a2m, nullptr,
                                                         nullptr, p_buf, NA);
  gather_mfma<16, true><<<(NM + 15) / 16, 256, 0, stream>>>(
      p_buf, web_a2m, eapf, srcp_a2m, dstp_a2m, rp_a2m, NM, m2_buf, m_x,
      g_a2m, b_a2m, out_m);

  // ---- m2a
  build_csr(m2a_dst, m2a_src, m2a_w, E_MA, NA, cnt, bsum, bpre, rp_m2a, cursor,
            perm_sh, srcp_m2a, dstp_m2a, ewp_sh, stream);
  prep_eapf<<<(((E_MA + 15) / 16) + 3) / 4, 256, 0, stream>>>(m2a_ea, perm_sh,
                                                              ewp_sh, eapf, E_MA);
  proj_kernel<false><<<(NM + 63) / 64, 256, 0, stream>>>(m2_buf, W_m2a, nullptr,
                                                         nullptr, m1_buf, NM);
  gather_mfma<16, true><<<(NA + 15) / 16, 256, 0, stream>>>(
      m1_buf, web_m2a, eapf, srcp_m2a, dstp_m2a, rp_m2a, NA, a2_buf, a_x,
      g_m2a, b_m2a, out_a);
}

// Round 9
// 758.816 us; speedup vs baseline: 2.8315x; 1.3944x over previous
//
#include <hip/hip_runtime.h>
#include <hip/hip_bf16.h>

#define H 128
#define RBF 64

typedef __attribute__((ext_vector_type(8))) short bf16x8;
typedef __attribute__((ext_vector_type(4))) float f32x4;

__device__ inline short f2bf(float f) {
  union { float f; unsigned u; } v; v.f = f;
  const unsigned r = (v.u + 0x7FFFu + ((v.u >> 16) & 1u)) >> 16;
  return (short)r;
}

// ---------------------------------------------------------------- utilities
__global__ __launch_bounds__(128) void ln_rows(const float* __restrict__ X,
                                               const float* __restrict__ g,
                                               const float* __restrict__ bb,
                                               float* __restrict__ Y, int N) {
  __shared__ float sh[4];
  const int row = blockIdx.x;
  const int j = threadIdx.x;
  float x = X[(size_t)row * H + j];
  float s = x, q = x * x;
#pragma unroll
  for (int m = 32; m; m >>= 1) {
    s += __shfl_xor(s, m, 64);
    q += __shfl_xor(q, m, 64);
  }
  if ((j & 63) == 0) { sh[(j >> 6) * 2] = s; sh[(j >> 6) * 2 + 1] = q; }
  __syncthreads();
  s = sh[0] + sh[2];
  q = sh[1] + sh[3];
  const float mu = s * 0.0078125f;
  const float var = q * 0.0078125f - mu * mu;
  const float rs = rsqrtf(var + 1e-5f);
  Y[(size_t)row * H + j] = (x - mu) * rs * g[j] + bb[j];
}

// conv_k (o,i,dx,dy,dz) -> Kt[tap][i][o]
__global__ void transpose_k(const float* __restrict__ K, float* __restrict__ Kt) {
  const int idx = blockIdx.x * 256 + threadIdx.x;
  const int total = H * H * 27;
  if (idx >= total) return;
  const int tap = idx % 27;
  const int rem = idx / 27;
  const int i = rem % H;
  const int o = rem / H;
  Kt[((size_t)tap * H + i) * H + o] = K[idx];
}

// Kt[tap][i][o] f32 -> MFMA B-frag bf16:
// Ktb[(((tap*4+kb)*8+cb)*64+l)*8+j] = Kt[tap][kb*32+(l>>4)*8+j][cb*16+(l&15)]
__global__ __launch_bounds__(256) void pack_kt(const float* __restrict__ Kt,
                                               short* __restrict__ Ktb) {
  const int id = blockIdx.x * 256 + threadIdx.x;
  if (id >= 27 * 4 * 8 * 64) return;
  const int l = id & 63;
  int r = id >> 6;
  const int cb = r & 7; r >>= 3;
  const int kb = r & 3;
  const int tap = r >> 2;
  const int o = cb * 16 + (l & 15);
  const int i0 = kb * 32 + (l >> 4) * 8;
  short* out = Ktb + (size_t)id * 8;
#pragma unroll
  for (int j = 0; j < 8; ++j)
    out[j] = f2bf(Kt[((size_t)tap * H + i0 + j) * H + o]);
}

// We[64][128] f32 -> frag-layout bf16: Web[((h*8+c)*64+lane)*8+j]
__global__ __launch_bounds__(256) void pack_we(const float* __restrict__ We,
                                               short* __restrict__ Web) {
  const int id = blockIdx.x * 256 + threadIdx.x;
  if (id >= 1024) return;
  const int f = id >> 6, l = id & 63;
  const int h = f >> 3, c = f & 7;
  const int col = (c << 4) + (l & 15);
  const int k0 = h * 32 + (l >> 4) * 8;
  short* o = Web + (size_t)id * 8;
#pragma unroll
  for (int j = 0; j < 8; ++j) o[j] = f2bf(We[(k0 + j) * H + col]);
}

// ----------------------------------------------- counting-sort (CSR builder)
__global__ __launch_bounds__(256) void k_hist(const int* __restrict__ dst, int E,
                                              int* __restrict__ cnt) {
  int e = blockIdx.x * 256 + threadIdx.x;
  const int stride = gridDim.x * 256;
  for (; e < E; e += stride) atomicAdd(&cnt[dst[e]], 1);
}

__global__ __launch_bounds__(256) void k_blocksum(const int* __restrict__ cnt,
                                                  int* __restrict__ bsum) {
  __shared__ int sh[256];
  const int t = threadIdx.x;
  sh[t] = cnt[blockIdx.x * 256 + t];
  __syncthreads();
#pragma unroll
  for (int o = 128; o; o >>= 1) {
    if (t < o) sh[t] += sh[t + o];
    __syncthreads();
  }
  if (!t) bsum[blockIdx.x] = sh[0];
}

__global__ __launch_bounds__(256) void k_scan_bsum(const int* __restrict__ bsum,
                                                   int* __restrict__ bpre, int NB) {
  __shared__ int sh[256];
  const int t = threadIdx.x;
  const int v = (t < NB) ? bsum[t] : 0;
  sh[t] = v;
  __syncthreads();
  for (int o = 1; o < 256; o <<= 1) {
    const int u = (t >= o) ? sh[t - o] : 0;
    __syncthreads();
    sh[t] += u;
    __syncthreads();
  }
  if (t < NB) bpre[t] = sh[t] - v;
}

__global__ __launch_bounds__(256) void k_apply(const int* __restrict__ cnt,
                                               const int* __restrict__ bpre,
                                               int* __restrict__ rowptr,
                                               int* __restrict__ cursor, int N) {
  __shared__ int sh[256];
  const int t = threadIdx.x;
  const int i = blockIdx.x * 256 + t;
  const int v = cnt[i];
  sh[t] = v;
  __syncthreads();
  for (int o = 1; o < 256; o <<= 1) {
    const int u = (t >= o) ? sh[t - o] : 0;
    __syncthreads();
    sh[t] += u;
    __syncthreads();
  }
  const int excl = sh[t] - v + bpre[blockIdx.x];
  if (i <= N) {
    rowptr[i] = excl;
    if (i < N) cursor[i] = excl;
  }
}

// permute src/dst/ew into CSR order
__global__ __launch_bounds__(256) void k_perm(const int* __restrict__ dst,
                                              const int* __restrict__ src,
                                              const float* __restrict__ ew, int E,
                                              int* __restrict__ cursor,
                                              int* __restrict__ perm,
                                              int* __restrict__ srcp,
                                              int* __restrict__ dstp,
                                              float* __restrict__ ewp) {
  int e = blockIdx.x * 256 + threadIdx.x;
  const int stride = gridDim.x * 256;
  for (; e < E; e += stride) {
    const int d = dst[e];
    const int p = atomicAdd(&cursor[d], 1);
    perm[p] = e;
    srcp[p] = src[e];
    dstp[p] = d;
    ewp[p] = ew[e];
  }
}

// ------------- prep: eapf[tile][half][lane][8] = bf16(ea[perm[i]] * ew) -----
__global__ __launch_bounds__(256) void prep_eapf(const float* __restrict__ ea,
                                                 const int* __restrict__ perm,
                                                 const float* __restrict__ ewp,
                                                 short* __restrict__ eapf, int E) {
  const int ntiles = (E + 15) >> 4;
  const int tile = blockIdx.x * 4 + (threadIdx.x >> 6);
  if (tile >= ntiles) return;
  const int lane = threadIdx.x & 63;
  const int row = tile * 16 + (lane & 15);
  const int k0 = (lane >> 4) * 8;
  float w = 0.f;
  int pe = 0;
  if (row < E) { pe = perm[row]; w = ewp[row]; }
  const float* er = ea + (size_t)pe * RBF + k0;
  const float4 x0 = *(const float4*)(er);
  const float4 x1 = *(const float4*)(er + 4);
  const float4 x2 = *(const float4*)(er + 32);
  const float4 x3 = *(const float4*)(er + 36);
  bf16x8 o0, o1;
  o0[0] = f2bf(x0.x * w); o0[1] = f2bf(x0.y * w);
  o0[2] = f2bf(x0.z * w); o0[3] = f2bf(x0.w * w);
  o0[4] = f2bf(x1.x * w); o0[5] = f2bf(x1.y * w);
  o0[6] = f2bf(x1.z * w); o0[7] = f2bf(x1.w * w);
  o1[0] = f2bf(x2.x * w); o1[1] = f2bf(x2.y * w);
  o1[2] = f2bf(x2.z * w); o1[3] = f2bf(x2.w * w);
  o1[4] = f2bf(x3.x * w); o1[5] = f2bf(x3.y * w);
  o1[6] = f2bf(x3.z * w); o1[7] = f2bf(x3.w * w);
  short* ob = eapf + (size_t)tile * 1024;
  *(bf16x8*)(ob + lane * 8) = o0;
  *(bf16x8*)(ob + 512 + lane * 8) = o1;
}

// ------------------------------------------- node projection: Y = [LN](X) @ W
template <bool DO_LN>
__global__ __launch_bounds__(256) void proj_kernel(const float* __restrict__ X,
                                                   const float* __restrict__ W,
                                                   const float* __restrict__ g,
                                                   const float* __restrict__ bb,
                                                   float* __restrict__ Y, int N) {
  __shared__ float At[128 * 68];
  const int row0 = blockIdx.x * 64;
  const int t = threadIdx.x;
  const int lk = (t & 31) * 4;
  const int lr = t >> 5;
  float4 g4 = {0, 0, 0, 0}, b4 = {0, 0, 0, 0};
  if (DO_LN) {
    g4 = *(const float4*)(g + lk);
    b4 = *(const float4*)(bb + lk);
  }
#pragma unroll
  for (int p = 0; p < 8; ++p) {
    const int r = lr + p * 8;
    const int row = row0 + r;
    float4 xv = make_float4(0.f, 0.f, 0.f, 0.f);
    if (row < N) xv = *(const float4*)(X + (size_t)row * H + lk);
    if (DO_LN) {
      float s = xv.x + xv.y + xv.z + xv.w;
      float q = xv.x * xv.x + xv.y * xv.y + xv.z * xv.z + xv.w * xv.w;
#pragma unroll
      for (int m = 16; m; m >>= 1) {
        s += __shfl_xor(s, m, 64);
        q += __shfl_xor(q, m, 64);
      }
      const float mu = s * 0.0078125f;
      const float var = q * 0.0078125f - mu * mu;
      const float rs = rsqrtf(var + 1e-5f);
      xv.x = (xv.x - mu) * rs * g4.x + b4.x;
      xv.y = (xv.y - mu) * rs * g4.y + b4.y;
      xv.z = (xv.z - mu) * rs * g4.z + b4.z;
      xv.w = (xv.w - mu) * rs * g4.w + b4.w;
    }
    At[(lk + 0) * 68 + r] = xv.x;
    At[(lk + 1) * 68 + r] = xv.y;
    At[(lk + 2) * 68 + r] = xv.z;
    At[(lk + 3) * 68 + r] = xv.w;
  }
  __syncthreads();
  const int tc = t & 15;
  const int tr = t >> 4;
  float acc[4][8];
#pragma unroll
  for (int i = 0; i < 4; ++i)
#pragma unroll
    for (int c = 0; c < 8; ++c) acc[i][c] = 0.f;
  const float* wbase = W + tc * 8;
#pragma unroll 4
  for (int k = 0; k < 128; ++k) {
    const float4 a4 = *(const float4*)(At + k * 68 + tr * 4);
    const float4 w0 = *(const float4*)(wbase + k * H);
    const float4 w1 = *(const float4*)(wbase + k * H + 4);
    const float av[4] = {a4.x, a4.y, a4.z, a4.w};
#pragma unroll
    for (int i = 0; i < 4; ++i) {
      acc[i][0] += av[i] * w0.x; acc[i][1] += av[i] * w0.y;
      acc[i][2] += av[i] * w0.z; acc[i][3] += av[i] * w0.w;
      acc[i][4] += av[i] * w1.x; acc[i][5] += av[i] * w1.y;
      acc[i][6] += av[i] * w1.z; acc[i][7] += av[i] * w1.w;
    }
  }
#pragma unroll
  for (int i = 0; i < 4; ++i) {
    const int row = row0 + tr * 4 + i;
    if (row < N) {
      float4 o0 = {acc[i][0], acc[i][1], acc[i][2], acc[i][3]};
      float4 o1 = {acc[i][4], acc[i][5], acc[i][6], acc[i][7]};
      float* yp = Y + (size_t)row * H + tc * 8;
      *(float4*)yp = o0;
      *(float4*)(yp + 4) = o1;
    }
  }
}

// ----------------------------------------- tiled MFMA edge gather (CSR)
// NO LDS ATOMICS: 4 lg-replicated accumulators + in-lane adjacent merge.
template <int NPB, bool FUSE_LN>
__global__ __launch_bounds__(256, 4) void gather_mfma(
    const float* __restrict__ P, const short* __restrict__ Web,
    const short* __restrict__ eapf, const int* __restrict__ srcp,
    const int* __restrict__ dstp, const int* __restrict__ rowptr, int N,
    const float* __restrict__ base, const float* __restrict__ skip,
    const float* __restrict__ g, const float* __restrict__ bb,
    float* __restrict__ out) {
  constexpr int RSTR = (NPB + 1) * 132;                       // dwords/replica
  constexpr int RPAD = RSTR + ((16 - (RSTR & 31)) & 31);      // ≡16 (mod 32)
  __shared__ float acc[4 * RPAD];
  const int t = threadIdx.x;
  const int w = t >> 6, lane = t & 63;
  const int n0 = blockIdx.x * NPB;
  for (int u = t; u < 4 * RPAD; u += 256) acc[u] = 0.f;
  const int rp0 = rowptr[n0];
  const int rp1 = rowptr[min(n0 + NPB, N)];
  __syncthreads();
  const int q0 = rp0 >> 4;
  const int q1 = (rp1 + 15) >> 4;

  const int c0 = 2 * w;
  const bf16x8 bw0 = *(const bf16x8*)(Web + ((size_t)((0 + c0) * 64 + lane)) * 8);
  const bf16x8 bw1 = *(const bf16x8*)(Web + ((size_t)((8 + c0) * 64 + lane)) * 8);
  const bf16x8 bw2 = *(const bf16x8*)(Web + ((size_t)((1 + c0) * 64 + lane)) * 8);
  const bf16x8 bw3 = *(const bf16x8*)(Web + ((size_t)((9 + c0) * 64 + lane)) * 8);

  const int l15 = lane & 15, lg = lane >> 4, rbase = lg * 4;
  const int col0 = c0 * 16 + l15;
  float* const arep = acc + lg * RPAD;  // this lane's private replica

  auto LOADI = [&](int q, bf16x8& A0, bf16x8& A1, int4& sp, int4& dp) {
    const short* fb = eapf + (size_t)q * 1024;
    A0 = *(const bf16x8*)(fb + lane * 8);
    A1 = *(const bf16x8*)(fb + 512 + lane * 8);
    sp = *(const int4*)(srcp + q * 16 + rbase);
    dp = *(const int4*)(dstp + q * 16 + rbase);
  };
  auto PLOAD = [&](const int4& sp, float* pv) {
    const float* p0 = P + (size_t)sp.x * H + col0;
    const float* p1 = P + (size_t)sp.y * H + col0;
    const float* p2 = P + (size_t)sp.z * H + col0;
    const float* p3 = P + (size_t)sp.w * H + col0;
    pv[0] = p0[0]; pv[4] = p0[16];
    pv[1] = p1[0]; pv[5] = p1[16];
    pv[2] = p2[0]; pv[6] = p2[16];
    pv[3] = p3[0]; pv[7] = p3[16];
  };
  auto COMP = [&](const bf16x8& A0, const bf16x8& A1, const float* pv,
                  const int4& dp) {
    f32x4 C0 = {0.f, 0.f, 0.f, 0.f};
    C0 = __builtin_amdgcn_mfma_f32_16x16x32_bf16(A0, bw0, C0, 0, 0, 0);
    C0 = __builtin_amdgcn_mfma_f32_16x16x32_bf16(A1, bw1, C0, 0, 0, 0);
    f32x4 C1 = {0.f, 0.f, 0.f, 0.f};
    C1 = __builtin_amdgcn_mfma_f32_16x16x32_bf16(A0, bw2, C1, 0, 0, 0);
    C1 = __builtin_amdgcn_mfma_f32_16x16x32_bf16(A1, bw3, C1, 0, 0, 0);
    const int dls[4] = {dp.x - n0, dp.y - n0, dp.z - n0, dp.w - n0};
    int dl[5];
#pragma unroll
    for (int j = 0; j < 4; ++j)
      dl[j] = ((unsigned)dls[j] < (unsigned)NPB) ? dls[j] : NPB;
    dl[4] = -1;  // sentinel: forces flush at j=3
    float c0v = 0.f, c1v = 0.f;
#pragma unroll
    for (int j = 0; j < 4; ++j) {
      c0v += C0[j] * pv[j];
      c1v += C1[j] * pv[4 + j];
      if (dl[j + 1] != dl[j]) {
        float* a0 = arep + dl[j] * 132 + col0;
        a0[0] += c0v;
        a0[16] += c1v;
        c0v = 0.f;
        c1v = 0.f;
      }
    }
  };

  if (q1 > q0) {
    bf16x8 A0a, A1a, A0b, A1b;
    int4 spa, dpa, spb, dpb;
    float pva[8], pvb[8];
    LOADI(q0, A0a, A1a, spa, dpa);
    PLOAD(spa, pva);
    for (int q = q0; q < q1; q += 2) {
      if (q + 1 < q1) { LOADI(q + 1, A0b, A1b, spb, dpb); PLOAD(spb, pvb); }
      COMP(A0a, A1a, pva, dpa);
      if (q + 2 < q1) { LOADI(q + 2, A0a, A1a, spa, dpa); PLOAD(spa, pva); }
      if (q + 1 < q1) COMP(A0b, A1b, pvb, dpb);
    }
  }
  __syncthreads();

  // ---- epilogue
  for (int n = w; n < NPB; n += 4) {
    const int node = n0 + n;
    if (node >= N) break;
    const int rb = n * 132 + lane;
    const float v0 = acc[rb] + acc[RPAD + rb] + acc[2 * RPAD + rb] +
                     acc[3 * RPAD + rb];
    const float v1 = acc[rb + 64] + acc[RPAD + rb + 64] +
                     acc[2 * RPAD + rb + 64] + acc[3 * RPAD + rb + 64];
    const size_t i0 = (size_t)node * H + lane;
    if (FUSE_LN) {
      float s = v0 + v1, q = v0 * v0 + v1 * v1;
#pragma unroll
      for (int m = 32; m; m >>= 1) {
        s += __shfl_xor(s, m, 64);
        q += __shfl_xor(q, m, 64);
      }
      const float mu = s * 0.0078125f;
      const float var = q * 0.0078125f - mu * mu;
      const float rs = rsqrtf(var + 1e-5f);
      out[i0] = base[i0] + (v0 - mu) * rs * g[lane] + bb[lane] + skip[i0];
      out[i0 + 64] =
          base[i0 + 64] + (v1 - mu) * rs * g[lane + 64] + bb[lane + 64] + skip[i0 + 64];
    } else {
      out[i0] = v0;
      out[i0 + 64] = v1;
    }
  }
}

// -------------------------------------------------------- conv3d via MFMA
// Block = (batch, x-slab): 64 voxels x 128 out-ch. GEMM M=64 N=128 K=128*27.
// Input staged once as bf16 in LDS (192 rows x 128 ch) with XOR swizzle
// (row stride 256B would be a 16-way bank conflict on ds_read_b128 — G4).
// Wave owns 2 col-blocks; C[4 M-tiles][2] f32x4 in regs; B prefetch dbuf.
__global__ __launch_bounds__(256, 2) void conv3d_mfma(
    const float* __restrict__ Min, const short* __restrict__ Ktb,
    const float* __restrict__ bias, float* __restrict__ Mout) {
  __shared__ short in_s[193 * 128];  // bf16; row 192 = zeros
  const int b = blockIdx.x >> 3;
  const int x = blockIdx.x & 7;
  const int t = threadIdx.x;
  const int w = t >> 6, lane = t & 63;
  const int l15 = lane & 15, lg = lane >> 4;

  if (t < 128) in_s[192 * 128 + t] = 0;
  // stage 192 rows x 128 ch -> bf16, swizzled
#pragma unroll
  for (int it = 0; it < 12; ++it) {
    const int gidx = it * 256 + t;  // 0..3071 (16B chunks)
    const int r = gidx >> 4;        // row 0..191
    const int ch = (gidx & 15) * 8;
    const int gx = x + (r >> 6) - 1;
    const int yz = r & 63;
    float4 v0 = make_float4(0.f, 0.f, 0.f, 0.f), v1 = v0;
    if (gx >= 0 && gx < 8) {
      const float* src = Min + ((size_t)((b * 8 + gx) * 64 + yz)) * H + ch;
      v0 = *(const float4*)(src);
      v1 = *(const float4*)(src + 4);
    }
    bf16x8 pk;
    pk[0] = f2bf(v0.x); pk[1] = f2bf(v0.y); pk[2] = f2bf(v0.z); pk[3] = f2bf(v0.w);
    pk[4] = f2bf(v1.x); pk[5] = f2bf(v1.y); pk[6] = f2bf(v1.z); pk[7] = f2bf(v1.w);
    const int byte0 = (r * 256 + ch * 2) ^ ((r & 7) << 4);
    *(bf16x8*)((char*)in_s + byte0) = pk;
  }
  __syncthreads();

  const int cb0 = 2 * w;
  f32x4 C[4][2];
#pragma unroll
  for (int mt = 0; mt < 4; ++mt) {
    C[mt][0] = (f32x4){0.f, 0.f, 0.f, 0.f};
    C[mt][1] = (f32x4){0.f, 0.f, 0.f, 0.f};
  }

  auto BP = [&](int u, int cbi) -> const bf16x8* {
    return (const bf16x8*)(Ktb + (((size_t)u * 8) + cb0 + cbi) * 64 * 8 +
                           (size_t)lane * 8);
  };
  bf16x8 Ba0 = *BP(0, 0), Ba1 = *BP(0, 1);
  for (int u = 0; u < 108; ++u) {
    const int un = min(u + 1, 107);
    const bf16x8 Bn0 = *BP(un, 0);
    const bf16x8 Bn1 = *BP(un, 1);
    const int tap = u >> 2, kb = u & 3;
    const int dx = tap / 9, dy = (tap / 3) % 3, dz = tap % 3;
#pragma unroll
    for (int mt = 0; mt < 4; ++mt) {
      const int v = mt * 16 + l15;
      const int y = v >> 3, z = v & 7;
      const int ny = y + dy - 1, nz = z + dz - 1;
      const bool ok = (ny >= 0 && ny < 8 && nz >= 0 && nz < 8);
      const int vrow = ok ? dx * 64 + ny * 8 + nz : 192;
      const int byte0 = ((vrow * 256 + kb * 64 + lg * 16) ^ ((vrow & 7) << 4));
      const bf16x8 A = *(const bf16x8*)((const char*)in_s + byte0);
      C[mt][0] = __builtin_amdgcn_mfma_f32_16x16x32_bf16(A, Ba0, C[mt][0], 0, 0, 0);
      C[mt][1] = __builtin_amdgcn_mfma_f32_16x16x32_bf16(A, Ba1, C[mt][1], 0, 0, 0);
    }
    Ba0 = Bn0;
    Ba1 = Bn1;
  }

  // epilogue: C row = lg*4 + j, col = l15 (m89 layout); + bias
  const float b0 = bias[cb0 * 16 + l15];
  const float b1 = bias[cb0 * 16 + 16 + l15];
  float* obase = Mout + ((size_t)((b * 8 + x) * 64)) * H;
#pragma unroll
  for (int mt = 0; mt < 4; ++mt)
#pragma unroll
    for (int j = 0; j < 4; ++j) {
      const int vox = mt * 16 + lg * 4 + j;
      float* op = obase + (size_t)vox * H + cb0 * 16 + l15;
      op[0] = C[mt][0][j] + b0;
      op[16] = C[mt][1][j] + b1;
    }
}

// ------------------------------------------------------------------ driver
static inline void build_csr(const int* dst, const int* src, const float* ew,
                             int E, int N, int* cnt, int* bsum, int* bpre,
                             int* rowptr, int* cursor, int* perm, int* srcp,
                             int* dstp, float* ewp, hipStream_t stream) {
  const int NB = (N + 256) / 256;
  hipMemsetAsync(cnt, 0, (size_t)NB * 256 * sizeof(int), stream);
  k_hist<<<1024, 256, 0, stream>>>(dst, E, cnt);
  k_blocksum<<<NB, 256, 0, stream>>>(cnt, bsum);
  k_scan_bsum<<<1, 256, 0, stream>>>(bsum, bpre, NB);
  k_apply<<<NB, 256, 0, stream>>>(cnt, bpre, rowptr, cursor, N);
  k_perm<<<1024, 256, 0, stream>>>(dst, src, ew, E, cursor, perm, srcp, dstp, ewp);
  hipMemsetAsync(srcp + E, 0, 16 * sizeof(int), stream);
  hipMemsetAsync(dstp + E, 0xFF, 16 * sizeof(int), stream);
}

extern "C" void kernel_launch(void* const* d_in, const int* in_sizes, int n_in,
                              void* d_out, int out_size, void* d_ws, size_t ws_size,
                              hipStream_t stream) {
  const float* a_x = (const float*)d_in[0];
  const float* m_x = (const float*)d_in[1];
  const int* aa_idx = (const int*)d_in[2];
  const int* a2m_src = (const int*)d_in[3];
  const int* a2m_dst = (const int*)d_in[4];
  const int* m2a_src = (const int*)d_in[5];
  const int* m2a_dst = (const int*)d_in[6];
  const float* aa_w = (const float*)d_in[7];
  const float* a2m_w = (const float*)d_in[8];
  const float* m2a_w = (const float*)d_in[9];
  const float* aa_ea = (const float*)d_in[10];
  const float* a2m_ea = (const float*)d_in[11];
  const float* m2a_ea = (const float*)d_in[12];
  const float* W_short = (const float*)d_in[13];
  const float* We_short = (const float*)d_in[14];
  const float* W_a2m = (const float*)d_in[15];
  const float* We_a2m = (const float*)d_in[16];
  const float* W_m2a = (const float*)d_in[17];
  const float* We_m2a = (const float*)d_in[18];
  const float* conv_k = (const float*)d_in[19];
  const float* conv_b = (const float*)d_in[20];
  const float* g_short = (const float*)d_in[21];
  const float* b_short = (const float*)d_in[22];
  const float* g_long = (const float*)d_in[23];
  const float* b_long = (const float*)d_in[24];
  const float* g_a2m = (const float*)d_in[25];
  const float* b_a2m = (const float*)d_in[26];
  const float* g_m2a = (const float*)d_in[27];
  const float* b_m2a = (const float*)d_in[28];

  const int NA = in_sizes[0] / H;
  const int NM = in_sizes[1] / H;
  const int E_AA = in_sizes[2] / 2;
  const int E_AM = in_sizes[3];
  const int E_MA = in_sizes[5];
  const int* aa_src = aa_idx;
  const int* aa_dst = aa_idx + E_AA;

  float* ws = (float*)d_ws;
  float* p_buf = ws;                         // NA*H
  float* m1_buf = p_buf + (size_t)NA * H;    // NM*H
  float* m2_buf = m1_buf + (size_t)NM * H;   // NM*H
  float* a2_buf = m2_buf + (size_t)NM * H;   // NA*H
  float* kt = a2_buf + (size_t)NA * H;       // 27*H*H
  float* ewp_sh = kt + (size_t)27 * H * H;   // max E (shared across sets)
  short* web_aa = (short*)(ewp_sh + E_AA);
  short* web_a2m = web_aa + 8192;
  short* web_m2a = web_a2m + 8192;
  short* ktb = web_m2a + 8192;               // 27*4*8*64*8 = 442368 shorts
  int* iws = (int*)(ktb + 442368);
  int* perm_sh = iws;   iws += E_AA;
  int* srcp_aa = iws;   iws += E_AA + 16;
  int* srcp_a2m = iws;  iws += E_AM + 16;
  int* srcp_m2a = iws;  iws += E_MA + 16;
  int* dstp_aa = iws;   iws += E_AA + 16;
  int* dstp_a2m = iws;  iws += E_AM + 16;
  int* dstp_m2a = iws;  iws += E_MA + 16;
  int* rp_aa = iws;     iws += NA + 1;
  int* rp_a2m = iws;    iws += NM + 1;
  int* rp_m2a = iws;    iws += NA + 1;
  const int PADN = ((NA + 256) / 256) * 256;
  int* cnt = iws;       iws += PADN;
  int* cursor = iws;    iws += PADN;
  int* bsum = iws;      iws += 256;
  int* bpre = iws;      iws += 256;
  short* eapf = (short*)iws;  // shared: max tiles (E_AA/16) * 1024 shorts

  float* out_a = (float*)d_out;
  float* out_m = out_a + (size_t)NA * H;

  // ---- independent prep
  pack_we<<<4, 256, 0, stream>>>(We_short, web_aa);
  pack_we<<<4, 256, 0, stream>>>(We_a2m, web_a2m);
  pack_we<<<4, 256, 0, stream>>>(We_m2a, web_m2a);
  transpose_k<<<(H * H * 27 + 255) / 256, 256, 0, stream>>>(conv_k, kt);
  pack_kt<<<(27 * 4 * 8 * 64 + 255) / 256, 256, 0, stream>>>(kt, ktb);
  ln_rows<<<NM, 128, 0, stream>>>(m_x, g_long, b_long, m1_buf, NM);
  conv3d_mfma<<<(NM / 64), 256, 0, stream>>>(m1_buf, ktb, conv_b, m2_buf);
  proj_kernel<true><<<(NA + 63) / 64, 256, 0, stream>>>(a_x, W_short, g_short,
                                                        b_short, p_buf, NA);

  // ---- AA: csr -> prep -> gather
  build_csr(aa_dst, aa_src, aa_w, E_AA, NA, cnt, bsum, bpre, rp_aa, cursor,
            perm_sh, srcp_aa, dstp_aa, ewp_sh, stream);
  prep_eapf<<<(((E_AA + 15) / 16) + 3) / 4, 256, 0, stream>>>(aa_ea, perm_sh,
                                                              ewp_sh, eapf, E_AA);
  gather_mfma<16, false><<<(NA + 15) / 16, 256, 0, stream>>>(
      p_buf, web_aa, eapf, srcp_aa, dstp_aa, rp_aa, NA, nullptr, nullptr,
      nullptr, nullptr, a2_buf);

  // ---- a2m
  build_csr(a2m_dst, a2m_src, a2m_w, E_AM, NM, cnt, bsum, bpre, rp_a2m, cursor,
            perm_sh, srcp_a2m, dstp_a2m, ewp_sh, stream);
  prep_eapf<<<(((E_AM + 15) / 16) + 3) / 4, 256, 0, stream>>>(a2m_ea, perm_sh,
                                                              ewp_sh, eapf, E_AM);
  proj_kernel<false><<<(NA + 63) / 64, 256, 0, stream>>>(a2_buf, W_a2m, nullptr,
                                                         nullptr, p_buf, NA);
  gather_mfma<16, true><<<(NM + 15) / 16, 256, 0, stream>>>(
      p_buf, web_a2m, eapf, srcp_a2m, dstp_a2m, rp_a2m, NM, m2_buf, m_x,
      g_a2m, b_a2m, out_m);

  // ---- m2a
  build_csr(m2a_dst, m2a_src, m2a_w, E_MA, NA, cnt, bsum, bpre, rp_m2a, cursor,
            perm_sh, srcp_m2a, dstp_m2a, ewp_sh, stream);
  prep_eapf<<<(((E_MA + 15) / 16) + 3) / 4, 256, 0, stream>>>(m2a_ea, perm_sh,
                                                              ewp_sh, eapf, E_MA);
  proj_kernel<false><<<(NM + 63) / 64, 256, 0, stream>>>(m2_buf, W_m2a, nullptr,
                                                         nullptr, m1_buf, NM);
  gather_mfma<16, true><<<(NA + 15) / 16, 256, 0, stream>>>(
      m1_buf, web_m2a, eapf, srcp_m2a, dstp_m2a, rp_m2a, NA, a2_buf, a_x,
      g_m2a, b_m2a, out_a);
}

// Round 10
// 755.456 us; speedup vs baseline: 2.8441x; 1.0044x over previous
//
#include <hip/hip_runtime.h>
#include <hip/hip_bf16.h>

#define H 128
#define RBF 64

typedef __attribute__((ext_vector_type(8))) short bf16x8;
typedef __attribute__((ext_vector_type(4))) float f32x4;

__device__ inline short f2bf(float f) {
  union { float f; unsigned u; } v; v.f = f;
  const unsigned r = (v.u + 0x7FFFu + ((v.u >> 16) & 1u)) >> 16;
  return (short)r;
}

// ---------------------------------------------------------------- utilities
__global__ __launch_bounds__(128) void ln_rows(const float* __restrict__ X,
                                               const float* __restrict__ g,
                                               const float* __restrict__ bb,
                                               float* __restrict__ Y, int N) {
  __shared__ float sh[4];
  const int row = blockIdx.x;
  const int j = threadIdx.x;
  float x = X[(size_t)row * H + j];
  float s = x, q = x * x;
#pragma unroll
  for (int m = 32; m; m >>= 1) {
    s += __shfl_xor(s, m, 64);
    q += __shfl_xor(q, m, 64);
  }
  if ((j & 63) == 0) { sh[(j >> 6) * 2] = s; sh[(j >> 6) * 2 + 1] = q; }
  __syncthreads();
  s = sh[0] + sh[2];
  q = sh[1] + sh[3];
  const float mu = s * 0.0078125f;
  const float var = q * 0.0078125f - mu * mu;
  const float rs = rsqrtf(var + 1e-5f);
  Y[(size_t)row * H + j] = (x - mu) * rs * g[j] + bb[j];
}

// conv_k (o,i,tap) -> MFMA B-frag bf16 directly (no f32 transpose pass):
// Ktb[(((tap*4+kb)*8+cb)*64+l)*8+j] = K[( (cb*16+(l&15))*H + kb*32+(l>>4)*8+j )*27 + tap]
__global__ __launch_bounds__(256) void pack_kt(const float* __restrict__ K,
                                               short* __restrict__ Ktb) {
  const int id = blockIdx.x * 256 + threadIdx.x;
  if (id >= 27 * 4 * 8 * 64) return;
  const int l = id & 63;
  int r = id >> 6;
  const int cb = r & 7; r >>= 3;
  const int kb = r & 3;
  const int tap = r >> 2;
  const int o = cb * 16 + (l & 15);
  const int i0 = kb * 32 + (l >> 4) * 8;
  short* out = Ktb + (size_t)id * 8;
#pragma unroll
  for (int j = 0; j < 8; ++j)
    out[j] = f2bf(K[((size_t)o * H + i0 + j) * 27 + tap]);
}

// 3x We[64][128] f32 -> frag-layout bf16 in one launch
__global__ __launch_bounds__(256) void pack_we3(
    const float* __restrict__ We0, const float* __restrict__ We1,
    const float* __restrict__ We2, short* __restrict__ Wb0,
    short* __restrict__ Wb1, short* __restrict__ Wb2) {
  const int id = blockIdx.x * 256 + threadIdx.x;
  if (id >= 3072) return;
  const int which = id >> 10;
  const int i = id & 1023;
  const float* We = which == 0 ? We0 : which == 1 ? We1 : We2;
  short* Web = which == 0 ? Wb0 : which == 1 ? Wb1 : Wb2;
  const int f = i >> 6, l = i & 63;
  const int h = f >> 3, c = f & 7;
  const int col = (c << 4) + (l & 15);
  const int k0 = h * 32 + (l >> 4) * 8;
  short* o = Web + (size_t)i * 8;
#pragma unroll
  for (int j = 0; j < 8; ++j) o[j] = f2bf(We[(k0 + j) * H + col]);
}

// ----------------------------------------------- counting-sort (CSR builder)
__global__ __launch_bounds__(256) void k_hist(const int* __restrict__ dst, int E,
                                              int* __restrict__ cnt) {
  int e = blockIdx.x * 256 + threadIdx.x;
  const int stride = gridDim.x * 256;
  for (; e < E; e += stride) atomicAdd(&cnt[dst[e]], 1);
}

__global__ __launch_bounds__(256) void k_blocksum(const int* __restrict__ cnt,
                                                  int* __restrict__ bsum) {
  __shared__ int sh[256];
  const int t = threadIdx.x;
  sh[t] = cnt[blockIdx.x * 256 + t];
  __syncthreads();
#pragma unroll
  for (int o = 128; o; o >>= 1) {
    if (t < o) sh[t] += sh[t + o];
    __syncthreads();
  }
  if (!t) bsum[blockIdx.x] = sh[0];
}

__global__ __launch_bounds__(256) void k_scan_bsum(const int* __restrict__ bsum,
                                                   int* __restrict__ bpre, int NB) {
  __shared__ int sh[256];
  const int t = threadIdx.x;
  const int v = (t < NB) ? bsum[t] : 0;
  sh[t] = v;
  __syncthreads();
  for (int o = 1; o < 256; o <<= 1) {
    const int u = (t >= o) ? sh[t - o] : 0;
    __syncthreads();
    sh[t] += u;
    __syncthreads();
  }
  if (t < NB) bpre[t] = sh[t] - v;
}

__global__ __launch_bounds__(256) void k_apply(const int* __restrict__ cnt,
                                               const int* __restrict__ bpre,
                                               int* __restrict__ rowptr,
                                               int* __restrict__ cursor, int N) {
  __shared__ int sh[256];
  const int t = threadIdx.x;
  const int i = blockIdx.x * 256 + t;
  const int v = cnt[i];
  sh[t] = v;
  __syncthreads();
  for (int o = 1; o < 256; o <<= 1) {
    const int u = (t >= o) ? sh[t - o] : 0;
    __syncthreads();
    sh[t] += u;
    __syncthreads();
  }
  const int excl = sh[t] - v + bpre[blockIdx.x];
  if (i <= N) {
    rowptr[i] = excl;
    if (i < N) cursor[i] = excl;
  }
}

// permute src/dst/ew into CSR order; block 0 also writes the 16-entry pads
__global__ __launch_bounds__(256) void k_perm(const int* __restrict__ dst,
                                              const int* __restrict__ src,
                                              const float* __restrict__ ew, int E,
                                              int* __restrict__ cursor,
                                              int* __restrict__ perm,
                                              int* __restrict__ srcp,
                                              int* __restrict__ dstp,
                                              float* __restrict__ ewp) {
  if (blockIdx.x == 0 && threadIdx.x < 16) {
    perm[E + threadIdx.x] = 0;
    srcp[E + threadIdx.x] = 0;
    dstp[E + threadIdx.x] = -1;  // -> dump row
    ewp[E + threadIdx.x] = 0.f;
  }
  int e = blockIdx.x * 256 + threadIdx.x;
  const int stride = gridDim.x * 256;
  for (; e < E; e += stride) {
    const int d = dst[e];
    const int p = atomicAdd(&cursor[d], 1);
    perm[p] = e;
    srcp[p] = src[e];
    dstp[p] = d;
    ewp[p] = ew[e];
  }
}

// ------------------------------------------- node projection: Y = [LN](X) @ W
template <bool DO_LN>
__global__ __launch_bounds__(256) void proj_kernel(const float* __restrict__ X,
                                                   const float* __restrict__ W,
                                                   const float* __restrict__ g,
                                                   const float* __restrict__ bb,
                                                   float* __restrict__ Y, int N) {
  __shared__ float At[128 * 68];
  const int row0 = blockIdx.x * 64;
  const int t = threadIdx.x;
  const int lk = (t & 31) * 4;
  const int lr = t >> 5;
  float4 g4 = {0, 0, 0, 0}, b4 = {0, 0, 0, 0};
  if (DO_LN) {
    g4 = *(const float4*)(g + lk);
    b4 = *(const float4*)(bb + lk);
  }
#pragma unroll
  for (int p = 0; p < 8; ++p) {
    const int r = lr + p * 8;
    const int row = row0 + r;
    float4 xv = make_float4(0.f, 0.f, 0.f, 0.f);
    if (row < N) xv = *(const float4*)(X + (size_t)row * H + lk);
    if (DO_LN) {
      float s = xv.x + xv.y + xv.z + xv.w;
      float q = xv.x * xv.x + xv.y * xv.y + xv.z * xv.z + xv.w * xv.w;
#pragma unroll
      for (int m = 16; m; m >>= 1) {
        s += __shfl_xor(s, m, 64);
        q += __shfl_xor(q, m, 64);
      }
      const float mu = s * 0.0078125f;
      const float var = q * 0.0078125f - mu * mu;
      const float rs = rsqrtf(var + 1e-5f);
      xv.x = (xv.x - mu) * rs * g4.x + b4.x;
      xv.y = (xv.y - mu) * rs * g4.y + b4.y;
      xv.z = (xv.z - mu) * rs * g4.z + b4.z;
      xv.w = (xv.w - mu) * rs * g4.w + b4.w;
    }
    At[(lk + 0) * 68 + r] = xv.x;
    At[(lk + 1) * 68 + r] = xv.y;
    At[(lk + 2) * 68 + r] = xv.z;
    At[(lk + 3) * 68 + r] = xv.w;
  }
  __syncthreads();
  const int tc = t & 15;
  const int tr = t >> 4;
  float acc[4][8];
#pragma unroll
  for (int i = 0; i < 4; ++i)
#pragma unroll
    for (int c = 0; c < 8; ++c) acc[i][c] = 0.f;
  const float* wbase = W + tc * 8;
#pragma unroll 4
  for (int k = 0; k < 128; ++k) {
    const float4 a4 = *(const float4*)(At + k * 68 + tr * 4);
    const float4 w0 = *(const float4*)(wbase + k * H);
    const float4 w1 = *(const float4*)(wbase + k * H + 4);
    const float av[4] = {a4.x, a4.y, a4.z, a4.w};
#pragma unroll
    for (int i = 0; i < 4; ++i) {
      acc[i][0] += av[i] * w0.x; acc[i][1] += av[i] * w0.y;
      acc[i][2] += av[i] * w0.z; acc[i][3] += av[i] * w0.w;
      acc[i][4] += av[i] * w1.x; acc[i][5] += av[i] * w1.y;
      acc[i][6] += av[i] * w1.z; acc[i][7] += av[i] * w1.w;
    }
  }
#pragma unroll
  for (int i = 0; i < 4; ++i) {
    const int row = row0 + tr * 4 + i;
    if (row < N) {
      float4 o0 = {acc[i][0], acc[i][1], acc[i][2], acc[i][3]};
      float4 o1 = {acc[i][4], acc[i][5], acc[i][6], acc[i][7]};
      float* yp = Y + (size_t)row * H + tc * 8;
      *(float4*)yp = o0;
      *(float4*)(yp + 4) = o1;
    }
  }
}

// ----------------------------------------- tiled MFMA edge gather (CSR)
// No LDS atomics (lg-replicated acc + in-lane adjacent merge, R8) and no
// eapf materialization (R10): ea rows loaded inline via perm and converted
// to bf16 A-frags in-register. ew applied post-MFMA in f32.
template <int NPB, bool FUSE_LN>
__global__ __launch_bounds__(256, 3) void gather_mfma(
    const float* __restrict__ P, const short* __restrict__ Web,
    const float* __restrict__ ea, const int* __restrict__ perm,
    const int* __restrict__ srcp, const int* __restrict__ dstp,
    const float* __restrict__ ewp, const int* __restrict__ rowptr, int E,
    int N, const float* __restrict__ base, const float* __restrict__ skip,
    const float* __restrict__ g, const float* __restrict__ bb,
    float* __restrict__ out) {
  constexpr int RSTR = (NPB + 1) * 132;                       // dwords/replica
  constexpr int RPAD = RSTR + ((16 - (RSTR & 31)) & 31);      // ≡16 (mod 32)
  __shared__ float acc[4 * RPAD];
  const int t = threadIdx.x;
  const int w = t >> 6, lane = t & 63;
  const int n0 = blockIdx.x * NPB;
  for (int u = t; u < 4 * RPAD; u += 256) acc[u] = 0.f;
  const int rp0 = rowptr[n0];
  const int rp1 = rowptr[min(n0 + NPB, N)];
  __syncthreads();
  const int q0 = rp0 >> 4;
  const int q1 = (rp1 + 15) >> 4;
  const int Em1 = E - 1;

  const int c0 = 2 * w;
  const bf16x8 bw0 = *(const bf16x8*)(Web + ((size_t)((0 + c0) * 64 + lane)) * 8);
  const bf16x8 bw1 = *(const bf16x8*)(Web + ((size_t)((8 + c0) * 64 + lane)) * 8);
  const bf16x8 bw2 = *(const bf16x8*)(Web + ((size_t)((1 + c0) * 64 + lane)) * 8);
  const bf16x8 bw3 = *(const bf16x8*)(Web + ((size_t)((9 + c0) * 64 + lane)) * 8);

  const int l15 = lane & 15, lg = lane >> 4, rbase = lg * 4;
  const int col0 = c0 * 16 + l15;
  float* const arep = acc + lg * RPAD;  // this lane's private replica

  auto LOADI = [&](int q, float4& e0, float4& e1, float4& e2, float4& e3,
                   int4& sp, int4& dp, float4& wq) {
    const int pe = perm[min(q * 16 + l15, Em1)];
    const float* er = ea + (size_t)pe * RBF + lg * 8;
    e0 = *(const float4*)(er);
    e1 = *(const float4*)(er + 4);
    e2 = *(const float4*)(er + 32);
    e3 = *(const float4*)(er + 36);
    sp = *(const int4*)(srcp + q * 16 + rbase);
    dp = *(const int4*)(dstp + q * 16 + rbase);
    wq = *(const float4*)(ewp + q * 16 + rbase);
  };
  auto PLOAD = [&](const int4& sp, float* pv) {
    const float* p0 = P + (size_t)sp.x * H + col0;
    const float* p1 = P + (size_t)sp.y * H + col0;
    const float* p2 = P + (size_t)sp.z * H + col0;
    const float* p3 = P + (size_t)sp.w * H + col0;
    pv[0] = p0[0]; pv[4] = p0[16];
    pv[1] = p1[0]; pv[5] = p1[16];
    pv[2] = p2[0]; pv[6] = p2[16];
    pv[3] = p3[0]; pv[7] = p3[16];
  };
  auto COMP = [&](const float4& e0, const float4& e1, const float4& e2,
                  const float4& e3, const float* pv, const int4& dp,
                  const float4& wq) {
    bf16x8 A0, A1;
    A0[0] = f2bf(e0.x); A0[1] = f2bf(e0.y); A0[2] = f2bf(e0.z); A0[3] = f2bf(e0.w);
    A0[4] = f2bf(e1.x); A0[5] = f2bf(e1.y); A0[6] = f2bf(e1.z); A0[7] = f2bf(e1.w);
    A1[0] = f2bf(e2.x); A1[1] = f2bf(e2.y); A1[2] = f2bf(e2.z); A1[3] = f2bf(e2.w);
    A1[4] = f2bf(e3.x); A1[5] = f2bf(e3.y); A1[6] = f2bf(e3.z); A1[7] = f2bf(e3.w);
    f32x4 C0 = {0.f, 0.f, 0.f, 0.f};
    C0 = __builtin_amdgcn_mfma_f32_16x16x32_bf16(A0, bw0, C0, 0, 0, 0);
    C0 = __builtin_amdgcn_mfma_f32_16x16x32_bf16(A1, bw1, C0, 0, 0, 0);
    f32x4 C1 = {0.f, 0.f, 0.f, 0.f};
    C1 = __builtin_amdgcn_mfma_f32_16x16x32_bf16(A0, bw2, C1, 0, 0, 0);
    C1 = __builtin_amdgcn_mfma_f32_16x16x32_bf16(A1, bw3, C1, 0, 0, 0);
    const float wqa[4] = {wq.x, wq.y, wq.z, wq.w};
    const int dls[4] = {dp.x - n0, dp.y - n0, dp.z - n0, dp.w - n0};
    int dl[5];
#pragma unroll
    for (int j = 0; j < 4; ++j)
      dl[j] = ((unsigned)dls[j] < (unsigned)NPB) ? dls[j] : NPB;
    dl[4] = -1;  // sentinel: forces flush at j=3
    float c0v = 0.f, c1v = 0.f;
#pragma unroll
    for (int j = 0; j < 4; ++j) {
      c0v += C0[j] * pv[j] * wqa[j];
      c1v += C1[j] * pv[4 + j] * wqa[j];
      if (dl[j + 1] != dl[j]) {
        float* a0 = arep + dl[j] * 132 + col0;
        a0[0] += c0v;
        a0[16] += c1v;
        c0v = 0.f;
        c1v = 0.f;
      }
    }
  };

  if (q1 > q0) {
    float4 e0A, e1A, e2A, e3A, e0B, e1B, e2B, e3B;
    int4 spa, dpa, spb, dpb;
    float4 wqa, wqb;
    float pva[8], pvb[8];
    LOADI(q0, e0A, e1A, e2A, e3A, spa, dpa, wqa);
    PLOAD(spa, pva);
    for (int q = q0; q < q1; q += 2) {
      if (q + 1 < q1) {
        LOADI(q + 1, e0B, e1B, e2B, e3B, spb, dpb, wqb);
        PLOAD(spb, pvb);
      }
      COMP(e0A, e1A, e2A, e3A, pva, dpa, wqa);
      if (q + 2 < q1) {
        LOADI(q + 2, e0A, e1A, e2A, e3A, spa, dpa, wqa);
        PLOAD(spa, pva);
      }
      if (q + 1 < q1) COMP(e0B, e1B, e2B, e3B, pvb, dpb, wqb);
    }
  }
  __syncthreads();

  // ---- epilogue: sum the 4 replicas; one write per node; optional LN fuse
  for (int n = w; n < NPB; n += 4) {
    const int node = n0 + n;
    if (node >= N) break;
    const int rb = n * 132 + lane;
    const float v0 = acc[rb] + acc[RPAD + rb] + acc[2 * RPAD + rb] +
                     acc[3 * RPAD + rb];
    const float v1 = acc[rb + 64] + acc[RPAD + rb + 64] +
                     acc[2 * RPAD + rb + 64] + acc[3 * RPAD + rb + 64];
    const size_t i0 = (size_t)node * H + lane;
    if (FUSE_LN) {
      float s = v0 + v1, q = v0 * v0 + v1 * v1;
#pragma unroll
      for (int m = 32; m; m >>= 1) {
        s += __shfl_xor(s, m, 64);
        q += __shfl_xor(q, m, 64);
      }
      const float mu = s * 0.0078125f;
      const float var = q * 0.0078125f - mu * mu;
      const float rs = rsqrtf(var + 1e-5f);
      out[i0] = base[i0] + (v0 - mu) * rs * g[lane] + bb[lane] + skip[i0];
      out[i0 + 64] =
          base[i0 + 64] + (v1 - mu) * rs * g[lane + 64] + bb[lane + 64] + skip[i0 + 64];
    } else {
      out[i0] = v0;
      out[i0 + 64] = v1;
    }
  }
}

// -------------------------------------------------------- conv3d via MFMA
__global__ __launch_bounds__(256, 2) void conv3d_mfma(
    const float* __restrict__ Min, const short* __restrict__ Ktb,
    const float* __restrict__ bias, float* __restrict__ Mout) {
  __shared__ short in_s[193 * 128];  // bf16; row 192 = zeros
  const int b = blockIdx.x >> 3;
  const int x = blockIdx.x & 7;
  const int t = threadIdx.x;
  const int w = t >> 6, lane = t & 63;
  const int l15 = lane & 15, lg = lane >> 4;

  if (t < 128) in_s[192 * 128 + t] = 0;
#pragma unroll
  for (int it = 0; it < 12; ++it) {
    const int gidx = it * 256 + t;
    const int r = gidx >> 4;
    const int ch = (gidx & 15) * 8;
    const int gx = x + (r >> 6) - 1;
    const int yz = r & 63;
    float4 v0 = make_float4(0.f, 0.f, 0.f, 0.f), v1 = v0;
    if (gx >= 0 && gx < 8) {
      const float* src = Min + ((size_t)((b * 8 + gx) * 64 + yz)) * H + ch;
      v0 = *(const float4*)(src);
      v1 = *(const float4*)(src + 4);
    }
    bf16x8 pk;
    pk[0] = f2bf(v0.x); pk[1] = f2bf(v0.y); pk[2] = f2bf(v0.z); pk[3] = f2bf(v0.w);
    pk[4] = f2bf(v1.x); pk[5] = f2bf(v1.y); pk[6] = f2bf(v1.z); pk[7] = f2bf(v1.w);
    const int byte0 = (r * 256 + ch * 2) ^ ((r & 7) << 4);
    *(bf16x8*)((char*)in_s + byte0) = pk;
  }
  __syncthreads();

  const int cb0 = 2 * w;
  f32x4 C[4][2];
#pragma unroll
  for (int mt = 0; mt < 4; ++mt) {
    C[mt][0] = (f32x4){0.f, 0.f, 0.f, 0.f};
    C[mt][1] = (f32x4){0.f, 0.f, 0.f, 0.f};
  }

  auto BP = [&](int u, int cbi) -> const bf16x8* {
    return (const bf16x8*)(Ktb + (((size_t)u * 8) + cb0 + cbi) * 64 * 8 +
                           (size_t)lane * 8);
  };
  bf16x8 Ba0 = *BP(0, 0), Ba1 = *BP(0, 1);
  for (int u = 0; u < 108; ++u) {
    const int un = min(u + 1, 107);
    const bf16x8 Bn0 = *BP(un, 0);
    const bf16x8 Bn1 = *BP(un, 1);
    const int tap = u >> 2, kb = u & 3;
    const int dx = tap / 9, dy = (tap / 3) % 3, dz = tap % 3;
#pragma unroll
    for (int mt = 0; mt < 4; ++mt) {
      const int v = mt * 16 + l15;
      const int y = v >> 3, z = v & 7;
      const int ny = y + dy - 1, nz = z + dz - 1;
      const bool ok = (ny >= 0 && ny < 8 && nz >= 0 && nz < 8);
      const int vrow = ok ? dx * 64 + ny * 8 + nz : 192;
      const int byte0 = ((vrow * 256 + kb * 64 + lg * 16) ^ ((vrow & 7) << 4));
      const bf16x8 A = *(const bf16x8*)((const char*)in_s + byte0);
      C[mt][0] = __builtin_amdgcn_mfma_f32_16x16x32_bf16(A, Ba0, C[mt][0], 0, 0, 0);
      C[mt][1] = __builtin_amdgcn_mfma_f32_16x16x32_bf16(A, Ba1, C[mt][1], 0, 0, 0);
    }
    Ba0 = Bn0;
    Ba1 = Bn1;
  }

  const float b0 = bias[cb0 * 16 + l15];
  const float b1 = bias[cb0 * 16 + 16 + l15];
  float* obase = Mout + ((size_t)((b * 8 + x) * 64)) * H;
#pragma unroll
  for (int mt = 0; mt < 4; ++mt)
#pragma unroll
    for (int j = 0; j < 4; ++j) {
      const int vox = mt * 16 + lg * 4 + j;
      float* op = obase + (size_t)vox * H + cb0 * 16 + l15;
      op[0] = C[mt][0][j] + b0;
      op[16] = C[mt][1][j] + b1;
    }
}

// ------------------------------------------------------------------ driver
static inline void build_csr(const int* dst, const int* src, const float* ew,
                             int E, int N, int* cnt, int* bsum, int* bpre,
                             int* rowptr, int* cursor, int* perm, int* srcp,
                             int* dstp, float* ewp, hipStream_t stream) {
  const int NB = (N + 256) / 256;
  hipMemsetAsync(cnt, 0, (size_t)NB * 256 * sizeof(int), stream);
  k_hist<<<1024, 256, 0, stream>>>(dst, E, cnt);
  k_blocksum<<<NB, 256, 0, stream>>>(cnt, bsum);
  k_scan_bsum<<<1, 256, 0, stream>>>(bsum, bpre, NB);
  k_apply<<<NB, 256, 0, stream>>>(cnt, bpre, rowptr, cursor, N);
  k_perm<<<1024, 256, 0, stream>>>(dst, src, ew, E, cursor, perm, srcp, dstp, ewp);
}

extern "C" void kernel_launch(void* const* d_in, const int* in_sizes, int n_in,
                              void* d_out, int out_size, void* d_ws, size_t ws_size,
                              hipStream_t stream) {
  const float* a_x = (const float*)d_in[0];
  const float* m_x = (const float*)d_in[1];
  const int* aa_idx = (const int*)d_in[2];
  const int* a2m_src = (const int*)d_in[3];
  const int* a2m_dst = (const int*)d_in[4];
  const int* m2a_src = (const int*)d_in[5];
  const int* m2a_dst = (const int*)d_in[6];
  const float* aa_w = (const float*)d_in[7];
  const float* a2m_w = (const float*)d_in[8];
  const float* m2a_w = (const float*)d_in[9];
  const float* aa_ea = (const float*)d_in[10];
  const float* a2m_ea = (const float*)d_in[11];
  const float* m2a_ea = (const float*)d_in[12];
  const float* W_short = (const float*)d_in[13];
  const float* We_short = (const float*)d_in[14];
  const float* W_a2m = (const float*)d_in[15];
  const float* We_a2m = (const float*)d_in[16];
  const float* W_m2a = (const float*)d_in[17];
  const float* We_m2a = (const float*)d_in[18];
  const float* conv_k = (const float*)d_in[19];
  const float* conv_b = (const float*)d_in[20];
  const float* g_short = (const float*)d_in[21];
  const float* b_short = (const float*)d_in[22];
  const float* g_long = (const float*)d_in[23];
  const float* b_long = (const float*)d_in[24];
  const float* g_a2m = (const float*)d_in[25];
  const float* b_a2m = (const float*)d_in[26];
  const float* g_m2a = (const float*)d_in[27];
  const float* b_m2a = (const float*)d_in[28];

  const int NA = in_sizes[0] / H;
  const int NM = in_sizes[1] / H;
  const int E_AA = in_sizes[2] / 2;
  const int E_AM = in_sizes[3];
  const int E_MA = in_sizes[5];
  const int* aa_src = aa_idx;
  const int* aa_dst = aa_idx + E_AA;

  float* ws = (float*)d_ws;
  float* p_buf = ws;                         // NA*H
  float* m1_buf = p_buf + (size_t)NA * H;    // NM*H
  float* m2_buf = m1_buf + (size_t)NM * H;   // NM*H
  float* a2_buf = m2_buf + (size_t)NM * H;   // NA*H
  float* ewp_sh = a2_buf + (size_t)NA * H;   // max E + 16 (shared)
  short* web_aa = (short*)(ewp_sh + E_AA + 16);
  short* web_a2m = web_aa + 8192;
  short* web_m2a = web_a2m + 8192;
  short* ktb = web_m2a + 8192;               // 27*4*8*64*8 = 442368 shorts
  int* iws = (int*)(ktb + 442368);
  int* perm_sh = iws;   iws += E_AA + 16;    // shared across sets
  int* srcp_aa = iws;   iws += E_AA + 16;
  int* srcp_a2m = iws;  iws += E_AM + 16;
  int* srcp_m2a = iws;  iws += E_MA + 16;
  int* dstp_aa = iws;   iws += E_AA + 16;
  int* dstp_a2m = iws;  iws += E_AM + 16;
  int* dstp_m2a = iws;  iws += E_MA + 16;
  int* rp_aa = iws;     iws += NA + 1;
  int* rp_a2m = iws;    iws += NM + 1;
  int* rp_m2a = iws;    iws += NA + 1;
  const int PADN = ((NA + 256) / 256) * 256;
  int* cnt = iws;       iws += PADN;
  int* cursor = iws;    iws += PADN;
  int* bsum = iws;      iws += 256;
  int* bpre = iws;      iws += 256;

  float* out_a = (float*)d_out;
  float* out_m = out_a + (size_t)NA * H;

  // ---- independent prep
  pack_we3<<<12, 256, 0, stream>>>(We_short, We_a2m, We_m2a, web_aa, web_a2m,
                                   web_m2a);
  pack_kt<<<(27 * 4 * 8 * 64 + 255) / 256, 256, 0, stream>>>(conv_k, ktb);
  ln_rows<<<NM, 128, 0, stream>>>(m_x, g_long, b_long, m1_buf, NM);
  conv3d_mfma<<<(NM / 64), 256, 0, stream>>>(m1_buf, ktb, conv_b, m2_buf);
  proj_kernel<true><<<(NA + 63) / 64, 256, 0, stream>>>(a_x, W_short, g_short,
                                                        b_short, p_buf, NA);

  // ---- AA: csr -> gather (ea inlined)
  build_csr(aa_dst, aa_src, aa_w, E_AA, NA, cnt, bsum, bpre, rp_aa, cursor,
            perm_sh, srcp_aa, dstp_aa, ewp_sh, stream);
  gather_mfma<16, false><<<(NA + 15) / 16, 256, 0, stream>>>(
      p_buf, web_aa, aa_ea, perm_sh, srcp_aa, dstp_aa, ewp_sh, rp_aa, E_AA,
      NA, nullptr, nullptr, nullptr, nullptr, a2_buf);

  // ---- a2m
  build_csr(a2m_dst, a2m_src, a2m_w, E_AM, NM, cnt, bsum, bpre, rp_a2m, cursor,
            perm_sh, srcp_a2m, dstp_a2m, ewp_sh, stream);
  proj_kernel<false><<<(NA + 63) / 64, 256, 0, stream>>>(a2_buf, W_a2m, nullptr,
                                                         nullptr, p_buf, NA);
  gather_mfma<16, true><<<(NM + 15) / 16, 256, 0, stream>>>(
      p_buf, web_a2m, a2m_ea, perm_sh, srcp_a2m, dstp_a2m, ewp_sh, rp_a2m,
      E_AM, NM, m2_buf, m_x, g_a2m, b_a2m, out_m);

  // ---- m2a
  build_csr(m2a_dst, m2a_src, m2a_w, E_MA, NA, cnt, bsum, bpre, rp_m2a, cursor,
            perm_sh, srcp_m2a, dstp_m2a, ewp_sh, stream);
  proj_kernel<false><<<(NM + 63) / 64, 256, 0, stream>>>(m2_buf, W_m2a, nullptr,
                                                         nullptr, m1_buf, NM);
  gather_mfma<16, true><<<(NA + 15) / 16, 256, 0, stream>>>(
      m1_buf, web_m2a, m2a_ea, perm_sh, srcp_m2a, dstp_m2a, ewp_sh, rp_m2a,
      E_MA, NA, a2_buf, a_x, g_m2a, b_m2a, out_a);
}

// Round 11
// 690.163 us; speedup vs baseline: 3.1132x; 1.0946x over previous
//
#include <hip/hip_runtime.h>
#include <hip/hip_bf16.h>

#define H 128
#define RBF 64

typedef __attribute__((ext_vector_type(8))) short bf16x8;
typedef __attribute__((ext_vector_type(4))) float f32x4;

__device__ inline short f2bf(float f) {
  union { float f; unsigned u; } v; v.f = f;
  const unsigned r = (v.u + 0x7FFFu + ((v.u >> 16) & 1u)) >> 16;
  return (short)r;
}

// ---------------------------------------------------------------- utilities
__global__ __launch_bounds__(128) void ln_rows(const float* __restrict__ X,
                                               const float* __restrict__ g,
                                               const float* __restrict__ bb,
                                               float* __restrict__ Y, int N) {
  __shared__ float sh[4];
  const int row = blockIdx.x;
  const int j = threadIdx.x;
  float x = X[(size_t)row * H + j];
  float s = x, q = x * x;
#pragma unroll
  for (int m = 32; m; m >>= 1) {
    s += __shfl_xor(s, m, 64);
    q += __shfl_xor(q, m, 64);
  }
  if ((j & 63) == 0) { sh[(j >> 6) * 2] = s; sh[(j >> 6) * 2 + 1] = q; }
  __syncthreads();
  s = sh[0] + sh[2];
  q = sh[1] + sh[3];
  const float mu = s * 0.0078125f;
  const float var = q * 0.0078125f - mu * mu;
  const float rs = rsqrtf(var + 1e-5f);
  Y[(size_t)row * H + j] = (x - mu) * rs * g[j] + bb[j];
}

// conv_k (o,i,tap) -> MFMA B-frag bf16 directly
__global__ __launch_bounds__(256) void pack_kt(const float* __restrict__ K,
                                               short* __restrict__ Ktb) {
  const int id = blockIdx.x * 256 + threadIdx.x;
  if (id >= 27 * 4 * 8 * 64) return;
  const int l = id & 63;
  int r = id >> 6;
  const int cb = r & 7; r >>= 3;
  const int kb = r & 3;
  const int tap = r >> 2;
  const int o = cb * 16 + (l & 15);
  const int i0 = kb * 32 + (l >> 4) * 8;
  short* out = Ktb + (size_t)id * 8;
#pragma unroll
  for (int j = 0; j < 8; ++j)
    out[j] = f2bf(K[((size_t)o * H + i0 + j) * 27 + tap]);
}

// 3x We[64][128] f32 -> frag-layout bf16 in one launch
__global__ __launch_bounds__(256) void pack_we3(
    const float* __restrict__ We0, const float* __restrict__ We1,
    const float* __restrict__ We2, short* __restrict__ Wb0,
    short* __restrict__ Wb1, short* __restrict__ Wb2) {
  const int id = blockIdx.x * 256 + threadIdx.x;
  if (id >= 3072) return;
  const int which = id >> 10;
  const int i = id & 1023;
  const float* We = which == 0 ? We0 : which == 1 ? We1 : We2;
  short* Web = which == 0 ? Wb0 : which == 1 ? Wb1 : Wb2;
  const int f = i >> 6, l = i & 63;
  const int h = f >> 3, c = f & 7;
  const int col = (c << 4) + (l & 15);
  const int k0 = h * 32 + (l >> 4) * 8;
  short* o = Web + (size_t)i * 8;
#pragma unroll
  for (int j = 0; j < 8; ++j) o[j] = f2bf(We[(k0 + j) * H + col]);
}

// -------------------------------------- fused 3-set counting-sort (CSR)
__global__ __launch_bounds__(256) void k_hist3(
    const int* __restrict__ d0, const int* __restrict__ d1,
    const int* __restrict__ d2, int E0, int E1, int E2,
    int* __restrict__ cnt, int off1, int off2) {
  int i = blockIdx.x * 256 + threadIdx.x;
  const int stride = gridDim.x * 256;
  const int ET = E0 + E1 + E2;
  for (; i < ET; i += stride) {
    int d, off;
    if (i < E0) { d = d0[i]; off = 0; }
    else if (i < E0 + E1) { d = d1[i - E0]; off = off1; }
    else { d = d2[i - E0 - E1]; off = off2; }
    atomicAdd(&cnt[off + d], 1);
  }
}

__global__ __launch_bounds__(256) void k_blocksum(const int* __restrict__ cnt,
                                                  int* __restrict__ bsum) {
  __shared__ int sh[256];
  const int t = threadIdx.x;
  sh[t] = cnt[blockIdx.x * 256 + t];
  __syncthreads();
#pragma unroll
  for (int o = 128; o; o >>= 1) {
    if (t < o) sh[t] += sh[t + o];
    __syncthreads();
  }
  if (!t) bsum[blockIdx.x] = sh[0];
}

// exclusive scan of <=512 block sums, single block
__global__ __launch_bounds__(512) void k_scan512(const int* __restrict__ bsum,
                                                 int* __restrict__ bpre, int NB) {
  __shared__ int sh[512];
  const int t = threadIdx.x;
  const int v = (t < NB) ? bsum[t] : 0;
  sh[t] = v;
  __syncthreads();
  for (int o = 1; o < 512; o <<= 1) {
    const int u = (t >= o) ? sh[t - o] : 0;
    __syncthreads();
    sh[t] += u;
    __syncthreads();
  }
  if (t < NB) bpre[t] = sh[t] - v;
}

// per-set rowptr/cursor from concatenated counts (base subtraction)
__global__ __launch_bounds__(256) void k_apply3(
    const int* __restrict__ cnt, const int* __restrict__ bpre,
    int* __restrict__ rp0, int* __restrict__ rp1, int* __restrict__ rp2,
    int* __restrict__ cursor, int N0, int N1, int N2, int S1, int S2) {
  __shared__ int sh[256];
  const int b = blockIdx.x;
  const int t = threadIdx.x;
  const int gi = b * 256 + t;
  const int v = cnt[gi];
  sh[t] = v;
  __syncthreads();
  for (int o = 1; o < 256; o <<= 1) {
    const int u = (t >= o) ? sh[t - o] : 0;
    __syncthreads();
    sh[t] += u;
    __syncthreads();
  }
  int sb, N;
  int* rp;
  if (b < S1) { sb = 0; N = N0; rp = rp0; }
  else if (b < S2) { sb = S1; N = N1; rp = rp1; }
  else { sb = S2; N = N2; rp = rp2; }
  const int excl = sh[t] - v + bpre[b] - bpre[sb];
  const int il = (b - sb) * 256 + t;
  if (il <= N) {
    rp[il] = excl;
    if (il < N) cursor[gi] = excl;
  }
}

// ---- fused permute + bf16 convert + ew premultiply (ea moved exactly once)
// thread = edge (sequential ea read, coalesced); writes 128B bf16 row at CSR
// slot p plus srcp/dstp. No perm array survives.
__global__ __launch_bounds__(256) void k_perm2(
    const int* __restrict__ dst, const int* __restrict__ src,
    const float* __restrict__ ew, const float* __restrict__ ea, int E,
    int* __restrict__ cursor, int* __restrict__ srcp, int* __restrict__ dstp,
    short* __restrict__ eapfp) {
  int e = blockIdx.x * 256 + threadIdx.x;
  const int stride = gridDim.x * 256;
  for (; e < E; e += stride) {
    const int d = dst[e];
    const float w = ew[e];
    const int p = atomicAdd(&cursor[d], 1);
    srcp[p] = src[e];
    dstp[p] = d;
    const float* er = ea + (size_t)e * RBF;
    short* ob = eapfp + (size_t)p * RBF;
#pragma unroll
    for (int k = 0; k < RBF; k += 8) {
      const float4 x0 = *(const float4*)(er + k);
      const float4 x1 = *(const float4*)(er + k + 4);
      bf16x8 pk;
      pk[0] = f2bf(x0.x * w); pk[1] = f2bf(x0.y * w);
      pk[2] = f2bf(x0.z * w); pk[3] = f2bf(x0.w * w);
      pk[4] = f2bf(x1.x * w); pk[5] = f2bf(x1.y * w);
      pk[6] = f2bf(x1.z * w); pk[7] = f2bf(x1.w * w);
      *(bf16x8*)(ob + k) = pk;
    }
  }
}

// ------------------------------------------- node projection: Y = [LN](X) @ W
template <bool DO_LN>
__global__ __launch_bounds__(256) void proj_kernel(const float* __restrict__ X,
                                                   const float* __restrict__ W,
                                                   const float* __restrict__ g,
                                                   const float* __restrict__ bb,
                                                   float* __restrict__ Y, int N) {
  __shared__ float At[128 * 68];
  const int row0 = blockIdx.x * 64;
  const int t = threadIdx.x;
  const int lk = (t & 31) * 4;
  const int lr = t >> 5;
  float4 g4 = {0, 0, 0, 0}, b4 = {0, 0, 0, 0};
  if (DO_LN) {
    g4 = *(const float4*)(g + lk);
    b4 = *(const float4*)(bb + lk);
  }
#pragma unroll
  for (int p = 0; p < 8; ++p) {
    const int r = lr + p * 8;
    const int row = row0 + r;
    float4 xv = make_float4(0.f, 0.f, 0.f, 0.f);
    if (row < N) xv = *(const float4*)(X + (size_t)row * H + lk);
    if (DO_LN) {
      float s = xv.x + xv.y + xv.z + xv.w;
      float q = xv.x * xv.x + xv.y * xv.y + xv.z * xv.z + xv.w * xv.w;
#pragma unroll
      for (int m = 16; m; m >>= 1) {
        s += __shfl_xor(s, m, 64);
        q += __shfl_xor(q, m, 64);
      }
      const float mu = s * 0.0078125f;
      const float var = q * 0.0078125f - mu * mu;
      const float rs = rsqrtf(var + 1e-5f);
      xv.x = (xv.x - mu) * rs * g4.x + b4.x;
      xv.y = (xv.y - mu) * rs * g4.y + b4.y;
      xv.z = (xv.z - mu) * rs * g4.z + b4.z;
      xv.w = (xv.w - mu) * rs * g4.w + b4.w;
    }
    At[(lk + 0) * 68 + r] = xv.x;
    At[(lk + 1) * 68 + r] = xv.y;
    At[(lk + 2) * 68 + r] = xv.z;
    At[(lk + 3) * 68 + r] = xv.w;
  }
  __syncthreads();
  const int tc = t & 15;
  const int tr = t >> 4;
  float acc[4][8];
#pragma unroll
  for (int i = 0; i < 4; ++i)
#pragma unroll
    for (int c = 0; c < 8; ++c) acc[i][c] = 0.f;
  const float* wbase = W + tc * 8;
#pragma unroll 4
  for (int k = 0; k < 128; ++k) {
    const float4 a4 = *(const float4*)(At + k * 68 + tr * 4);
    const float4 w0 = *(const float4*)(wbase + k * H);
    const float4 w1 = *(const float4*)(wbase + k * H + 4);
    const float av[4] = {a4.x, a4.y, a4.z, a4.w};
#pragma unroll
    for (int i = 0; i < 4; ++i) {
      acc[i][0] += av[i] * w0.x; acc[i][1] += av[i] * w0.y;
      acc[i][2] += av[i] * w0.z; acc[i][3] += av[i] * w0.w;
      acc[i][4] += av[i] * w1.x; acc[i][5] += av[i] * w1.y;
      acc[i][6] += av[i] * w1.z; acc[i][7] += av[i] * w1.w;
    }
  }
#pragma unroll
  for (int i = 0; i < 4; ++i) {
    const int row = row0 + tr * 4 + i;
    if (row < N) {
      float4 o0 = {acc[i][0], acc[i][1], acc[i][2], acc[i][3]};
      float4 o1 = {acc[i][4], acc[i][5], acc[i][6], acc[i][7]};
      float* yp = Y + (size_t)row * H + tc * 8;
      *(float4*)yp = o0;
      *(float4*)(yp + 4) = o1;
    }
  }
}

// ----------------------------------------- tiled MFMA edge gather (CSR)
// A-frags = direct bf16 loads from eapfp (ew premultiplied in k_perm2).
// No LDS atomics (lg-replicated acc + in-lane adjacent merge).
template <int NPB, bool FUSE_LN>
__global__ __launch_bounds__(256, 3) void gather_mfma(
    const float* __restrict__ P, const short* __restrict__ Web,
    const short* __restrict__ eapfp, const int* __restrict__ srcp,
    const int* __restrict__ dstp, const int* __restrict__ rowptr, int N,
    const float* __restrict__ base, const float* __restrict__ skip,
    const float* __restrict__ g, const float* __restrict__ bb,
    float* __restrict__ out) {
  constexpr int RSTR = (NPB + 1) * 132;
  constexpr int RPAD = RSTR + ((16 - (RSTR & 31)) & 31);  // ≡16 (mod 32)
  __shared__ float acc[4 * RPAD];
  const int t = threadIdx.x;
  const int w = t >> 6, lane = t & 63;
  const int n0 = blockIdx.x * NPB;
  for (int u = t; u < 4 * RPAD; u += 256) acc[u] = 0.f;
  const int rp0 = rowptr[n0];
  const int rp1 = rowptr[min(n0 + NPB, N)];
  __syncthreads();
  const int q0 = rp0 >> 4;
  const int q1 = (rp1 + 15) >> 4;   // E is a multiple of 16 -> never OOB

  const int c0 = 2 * w;
  const bf16x8 bw0 = *(const bf16x8*)(Web + ((size_t)((0 + c0) * 64 + lane)) * 8);
  const bf16x8 bw1 = *(const bf16x8*)(Web + ((size_t)((8 + c0) * 64 + lane)) * 8);
  const bf16x8 bw2 = *(const bf16x8*)(Web + ((size_t)((1 + c0) * 64 + lane)) * 8);
  const bf16x8 bw3 = *(const bf16x8*)(Web + ((size_t)((9 + c0) * 64 + lane)) * 8);

  const int l15 = lane & 15, lg = lane >> 4, rbase = lg * 4;
  const int col0 = c0 * 16 + l15;
  float* const arep = acc + lg * RPAD;

  auto LOADI = [&](int q, bf16x8& A0, bf16x8& A1, int4& sp, int4& dp) {
    const short* fb = eapfp + ((size_t)(q * 16 + l15)) * RBF + lg * 8;
    A0 = *(const bf16x8*)(fb);
    A1 = *(const bf16x8*)(fb + 32);
    sp = *(const int4*)(srcp + q * 16 + rbase);
    dp = *(const int4*)(dstp + q * 16 + rbase);
  };
  auto PLOAD = [&](const int4& sp, float* pv) {
    const float* p0 = P + (size_t)sp.x * H + col0;
    const float* p1 = P + (size_t)sp.y * H + col0;
    const float* p2 = P + (size_t)sp.z * H + col0;
    const float* p3 = P + (size_t)sp.w * H + col0;
    pv[0] = p0[0]; pv[4] = p0[16];
    pv[1] = p1[0]; pv[5] = p1[16];
    pv[2] = p2[0]; pv[6] = p2[16];
    pv[3] = p3[0]; pv[7] = p3[16];
  };
  auto COMP = [&](const bf16x8& A0, const bf16x8& A1, const float* pv,
                  const int4& dp) {
    f32x4 C0 = {0.f, 0.f, 0.f, 0.f};
    C0 = __builtin_amdgcn_mfma_f32_16x16x32_bf16(A0, bw0, C0, 0, 0, 0);
    C0 = __builtin_amdgcn_mfma_f32_16x16x32_bf16(A1, bw1, C0, 0, 0, 0);
    f32x4 C1 = {0.f, 0.f, 0.f, 0.f};
    C1 = __builtin_amdgcn_mfma_f32_16x16x32_bf16(A0, bw2, C1, 0, 0, 0);
    C1 = __builtin_amdgcn_mfma_f32_16x16x32_bf16(A1, bw3, C1, 0, 0, 0);
    const int dls[4] = {dp.x - n0, dp.y - n0, dp.z - n0, dp.w - n0};
    int dl[5];
#pragma unroll
    for (int j = 0; j < 4; ++j)
      dl[j] = ((unsigned)dls[j] < (unsigned)NPB) ? dls[j] : NPB;
    dl[4] = -1;
    float c0v = 0.f, c1v = 0.f;
#pragma unroll
    for (int j = 0; j < 4; ++j) {
      c0v += C0[j] * pv[j];
      c1v += C1[j] * pv[4 + j];
      if (dl[j + 1] != dl[j]) {
        float* a0 = arep + dl[j] * 132 + col0;
        a0[0] += c0v;
        a0[16] += c1v;
        c0v = 0.f;
        c1v = 0.f;
      }
    }
  };

  if (q1 > q0) {
    bf16x8 A0a, A1a, A0b, A1b;
    int4 spa, dpa, spb, dpb;
    float pva[8], pvb[8];
    LOADI(q0, A0a, A1a, spa, dpa);
    PLOAD(spa, pva);
    for (int q = q0; q < q1; q += 2) {
      if (q + 1 < q1) { LOADI(q + 1, A0b, A1b, spb, dpb); PLOAD(spb, pvb); }
      COMP(A0a, A1a, pva, dpa);
      if (q + 2 < q1) { LOADI(q + 2, A0a, A1a, spa, dpa); PLOAD(spa, pva); }
      if (q + 1 < q1) COMP(A0b, A1b, pvb, dpb);
    }
  }
  __syncthreads();

  for (int n = w; n < NPB; n += 4) {
    const int node = n0 + n;
    if (node >= N) break;
    const int rb = n * 132 + lane;
    const float v0 = acc[rb] + acc[RPAD + rb] + acc[2 * RPAD + rb] +
                     acc[3 * RPAD + rb];
    const float v1 = acc[rb + 64] + acc[RPAD + rb + 64] +
                     acc[2 * RPAD + rb + 64] + acc[3 * RPAD + rb + 64];
    const size_t i0 = (size_t)node * H + lane;
    if (FUSE_LN) {
      float s = v0 + v1, q = v0 * v0 + v1 * v1;
#pragma unroll
      for (int m = 32; m; m >>= 1) {
        s += __shfl_xor(s, m, 64);
        q += __shfl_xor(q, m, 64);
      }
      const float mu = s * 0.0078125f;
      const float var = q * 0.0078125f - mu * mu;
      const float rs = rsqrtf(var + 1e-5f);
      out[i0] = base[i0] + (v0 - mu) * rs * g[lane] + bb[lane] + skip[i0];
      out[i0 + 64] =
          base[i0 + 64] + (v1 - mu) * rs * g[lane + 64] + bb[lane + 64] + skip[i0 + 64];
    } else {
      out[i0] = v0;
      out[i0 + 64] = v1;
    }
  }
}

// -------------------------------------------------------- conv3d via MFMA
__global__ __launch_bounds__(256, 2) void conv3d_mfma(
    const float* __restrict__ Min, const short* __restrict__ Ktb,
    const float* __restrict__ bias, float* __restrict__ Mout) {
  __shared__ short in_s[193 * 128];
  const int b = blockIdx.x >> 3;
  const int x = blockIdx.x & 7;
  const int t = threadIdx.x;
  const int w = t >> 6, lane = t & 63;
  const int l15 = lane & 15, lg = lane >> 4;

  if (t < 128) in_s[192 * 128 + t] = 0;
#pragma unroll
  for (int it = 0; it < 12; ++it) {
    const int gidx = it * 256 + t;
    const int r = gidx >> 4;
    const int ch = (gidx & 15) * 8;
    const int gx = x + (r >> 6) - 1;
    const int yz = r & 63;
    float4 v0 = make_float4(0.f, 0.f, 0.f, 0.f), v1 = v0;
    if (gx >= 0 && gx < 8) {
      const float* src = Min + ((size_t)((b * 8 + gx) * 64 + yz)) * H + ch;
      v0 = *(const float4*)(src);
      v1 = *(const float4*)(src + 4);
    }
    bf16x8 pk;
    pk[0] = f2bf(v0.x); pk[1] = f2bf(v0.y); pk[2] = f2bf(v0.z); pk[3] = f2bf(v0.w);
    pk[4] = f2bf(v1.x); pk[5] = f2bf(v1.y); pk[6] = f2bf(v1.z); pk[7] = f2bf(v1.w);
    const int byte0 = (r * 256 + ch * 2) ^ ((r & 7) << 4);
    *(bf16x8*)((char*)in_s + byte0) = pk;
  }
  __syncthreads();

  const int cb0 = 2 * w;
  f32x4 C[4][2];
#pragma unroll
  for (int mt = 0; mt < 4; ++mt) {
    C[mt][0] = (f32x4){0.f, 0.f, 0.f, 0.f};
    C[mt][1] = (f32x4){0.f, 0.f, 0.f, 0.f};
  }

  auto BP = [&](int u, int cbi) -> const bf16x8* {
    return (const bf16x8*)(Ktb + (((size_t)u * 8) + cb0 + cbi) * 64 * 8 +
                           (size_t)lane * 8);
  };
  bf16x8 Ba0 = *BP(0, 0), Ba1 = *BP(0, 1);
  for (int u = 0; u < 108; ++u) {
    const int un = min(u + 1, 107);
    const bf16x8 Bn0 = *BP(un, 0);
    const bf16x8 Bn1 = *BP(un, 1);
    const int tap = u >> 2, kb = u & 3;
    const int dx = tap / 9, dy = (tap / 3) % 3, dz = tap % 3;
#pragma unroll
    for (int mt = 0; mt < 4; ++mt) {
      const int v = mt * 16 + l15;
      const int y = v >> 3, z = v & 7;
      const int ny = y + dy - 1, nz = z + dz - 1;
      const bool ok = (ny >= 0 && ny < 8 && nz >= 0 && nz < 8);
      const int vrow = ok ? dx * 64 + ny * 8 + nz : 192;
      const int byte0 = ((vrow * 256 + kb * 64 + lg * 16) ^ ((vrow & 7) << 4));
      const bf16x8 A = *(const bf16x8*)((const char*)in_s + byte0);
      C[mt][0] = __builtin_amdgcn_mfma_f32_16x16x32_bf16(A, Ba0, C[mt][0], 0, 0, 0);
      C[mt][1] = __builtin_amdgcn_mfma_f32_16x16x32_bf16(A, Ba1, C[mt][1], 0, 0, 0);
    }
    Ba0 = Bn0;
    Ba1 = Bn1;
  }

  const float b0 = bias[cb0 * 16 + l15];
  const float b1 = bias[cb0 * 16 + 16 + l15];
  float* obase = Mout + ((size_t)((b * 8 + x) * 64)) * H;
#pragma unroll
  for (int mt = 0; mt < 4; ++mt)
#pragma unroll
    for (int j = 0; j < 4; ++j) {
      const int vox = mt * 16 + lg * 4 + j;
      float* op = obase + (size_t)vox * H + cb0 * 16 + l15;
      op[0] = C[mt][0][j] + b0;
      op[16] = C[mt][1][j] + b1;
    }
}

// ------------------------------------------------------------------ driver
extern "C" void kernel_launch(void* const* d_in, const int* in_sizes, int n_in,
                              void* d_out, int out_size, void* d_ws, size_t ws_size,
                              hipStream_t stream) {
  const float* a_x = (const float*)d_in[0];
  const float* m_x = (const float*)d_in[1];
  const int* aa_idx = (const int*)d_in[2];
  const int* a2m_src = (const int*)d_in[3];
  const int* a2m_dst = (const int*)d_in[4];
  const int* m2a_src = (const int*)d_in[5];
  const int* m2a_dst = (const int*)d_in[6];
  const float* aa_w = (const float*)d_in[7];
  const float* a2m_w = (const float*)d_in[8];
  const float* m2a_w = (const float*)d_in[9];
  const float* aa_ea = (const float*)d_in[10];
  const float* a2m_ea = (const float*)d_in[11];
  const float* m2a_ea = (const float*)d_in[12];
  const float* W_short = (const float*)d_in[13];
  const float* We_short = (const float*)d_in[14];
  const float* W_a2m = (const float*)d_in[15];
  const float* We_a2m = (const float*)d_in[16];
  const float* W_m2a = (const float*)d_in[17];
  const float* We_m2a = (const float*)d_in[18];
  const float* conv_k = (const float*)d_in[19];
  const float* conv_b = (const float*)d_in[20];
  const float* g_short = (const float*)d_in[21];
  const float* b_short = (const float*)d_in[22];
  const float* g_long = (const float*)d_in[23];
  const float* b_long = (const float*)d_in[24];
  const float* g_a2m = (const float*)d_in[25];
  const float* b_a2m = (const float*)d_in[26];
  const float* g_m2a = (const float*)d_in[27];
  const float* b_m2a = (const float*)d_in[28];

  const int NA = in_sizes[0] / H;
  const int NM = in_sizes[1] / H;
  const int E_AA = in_sizes[2] / 2;
  const int E_AM = in_sizes[3];
  const int E_MA = in_sizes[5];
  const int* aa_src = aa_idx;
  const int* aa_dst = aa_idx + E_AA;

  // CSR geometry (concatenated count region)
  const int NB_A = (NA + 256) / 256;       // 196
  const int NB_M = (NM + 256) / 256;       // 65
  const int S1 = NB_A, S2 = NB_A + NB_M;   // set start blocks
  const int NB_T = NB_A + NB_M + NB_A;     // 457
  const int OFF1 = S1 * 256, OFF2 = S2 * 256;

  float* ws = (float*)d_ws;
  float* p_buf = ws;                         // NA*H
  float* m1_buf = p_buf + (size_t)NA * H;    // NM*H
  float* m2_buf = m1_buf + (size_t)NM * H;   // NM*H
  float* a2_buf = m2_buf + (size_t)NM * H;   // NA*H
  short* web_aa = (short*)(a2_buf + (size_t)NA * H);
  short* web_a2m = web_aa + 8192;
  short* web_m2a = web_a2m + 8192;
  short* ktb = web_m2a + 8192;               // 442368 shorts
  short* eapfp = ktb + 442368;               // E_AA*64 shorts (shared, serial)
  int* iws = (int*)(eapfp + (size_t)E_AA * RBF);
  int* srcp_aa = iws;   iws += E_AA;
  int* srcp_a2m = iws;  iws += E_AM;
  int* srcp_m2a = iws;  iws += E_MA;
  int* dstp_aa = iws;   iws += E_AA;
  int* dstp_a2m = iws;  iws += E_AM;
  int* dstp_m2a = iws;  iws += E_MA;
  int* cnt = iws;       iws += NB_T * 256;
  int* cursor = iws;    iws += NB_T * 256;
  int* bsum = iws;      iws += 512;
  int* bpre = iws;      iws += 512;
  int* rp_aa = iws;     iws += NA + 1;
  int* rp_a2m = iws;    iws += NM + 1;
  int* rp_m2a = iws;    iws += NA + 1;

  float* out_a = (float*)d_out;
  float* out_m = out_a + (size_t)NA * H;

  // ---- independent prep
  pack_we3<<<12, 256, 0, stream>>>(We_short, We_a2m, We_m2a, web_aa, web_a2m,
                                   web_m2a);
  pack_kt<<<(27 * 4 * 8 * 64 + 255) / 256, 256, 0, stream>>>(conv_k, ktb);
  ln_rows<<<NM, 128, 0, stream>>>(m_x, g_long, b_long, m1_buf, NM);
  conv3d_mfma<<<(NM / 64), 256, 0, stream>>>(m1_buf, ktb, conv_b, m2_buf);
  proj_kernel<true><<<(NA + 63) / 64, 256, 0, stream>>>(a_x, W_short, g_short,
                                                        b_short, p_buf, NA);

  // ---- fused 3-set CSR build
  hipMemsetAsync(cnt, 0, (size_t)NB_T * 256 * sizeof(int), stream);
  k_hist3<<<2048, 256, 0, stream>>>(aa_dst, a2m_dst, m2a_dst, E_AA, E_AM, E_MA,
                                    cnt, OFF1, OFF2);
  k_blocksum<<<NB_T, 256, 0, stream>>>(cnt, bsum);
  k_scan512<<<1, 512, 0, stream>>>(bsum, bpre, NB_T);
  k_apply3<<<NB_T, 256, 0, stream>>>(cnt, bpre, rp_aa, rp_a2m, rp_m2a, cursor,
                                     NA, NM, NA, S1, S2);

  // ---- AA
  k_perm2<<<2048, 256, 0, stream>>>(aa_dst, aa_src, aa_w, aa_ea, E_AA, cursor,
                                    srcp_aa, dstp_aa, eapfp);
  gather_mfma<16, false><<<(NA + 15) / 16, 256, 0, stream>>>(
      p_buf, web_aa, eapfp, srcp_aa, dstp_aa, rp_aa, NA, nullptr, nullptr,
      nullptr, nullptr, a2_buf);

  // ---- a2m (reuses eapfp; stream-serial)
  proj_kernel<false><<<(NA + 63) / 64, 256, 0, stream>>>(a2_buf, W_a2m, nullptr,
                                                         nullptr, p_buf, NA);
  k_perm2<<<2048, 256, 0, stream>>>(a2m_dst, a2m_src, a2m_w, a2m_ea, E_AM,
                                    cursor + OFF1, srcp_a2m, dstp_a2m, eapfp);
  gather_mfma<16, true><<<(NM + 15) / 16, 256, 0, stream>>>(
      p_buf, web_a2m, eapfp, srcp_a2m, dstp_a2m, rp_a2m, NM, m2_buf, m_x,
      g_a2m, b_a2m, out_m);

  // ---- m2a
  proj_kernel<false><<<(NM + 63) / 64, 256, 0, stream>>>(m2_buf, W_m2a, nullptr,
                                                         nullptr, m1_buf, NM);
  k_perm2<<<2048, 256, 0, stream>>>(m2a_dst, m2a_src, m2a_w, m2a_ea, E_MA,
                                    cursor + OFF2, srcp_m2a, dstp_m2a, eapfp);
  gather_mfma<16, true><<<(NA + 15) / 16, 256, 0, stream>>>(
      m1_buf, web_m2a, eapfp, srcp_m2a, dstp_m2a, rp_m2a, NA, a2_buf, a_x,
      g_m2a, b_m2a, out_a);
}

// Round 12
// 623.298 us; speedup vs baseline: 3.4471x; 1.1073x over previous
//
#include <hip/hip_runtime.h>
#include <hip/hip_bf16.h>

#define H 128
#define RBF 64

typedef __attribute__((ext_vector_type(8))) short bf16x8;
typedef __attribute__((ext_vector_type(4))) float f32x4;

__device__ inline short f2bf(float f) {
  union { float f; unsigned u; } v; v.f = f;
  const unsigned r = (v.u + 0x7FFFu + ((v.u >> 16) & 1u)) >> 16;
  return (short)r;
}

// ---------------------------------------------------------------- utilities
__global__ __launch_bounds__(128) void ln_rows(const float* __restrict__ X,
                                               const float* __restrict__ g,
                                               const float* __restrict__ bb,
                                               float* __restrict__ Y, int N) {
  __shared__ float sh[4];
  const int row = blockIdx.x;
  const int j = threadIdx.x;
  float x = X[(size_t)row * H + j];
  float s = x, q = x * x;
#pragma unroll
  for (int m = 32; m; m >>= 1) {
    s += __shfl_xor(s, m, 64);
    q += __shfl_xor(q, m, 64);
  }
  if ((j & 63) == 0) { sh[(j >> 6) * 2] = s; sh[(j >> 6) * 2 + 1] = q; }
  __syncthreads();
  s = sh[0] + sh[2];
  q = sh[1] + sh[3];
  const float mu = s * 0.0078125f;
  const float var = q * 0.0078125f - mu * mu;
  const float rs = rsqrtf(var + 1e-5f);
  Y[(size_t)row * H + j] = (x - mu) * rs * g[j] + bb[j];
}

// conv_k (o,i,tap) -> MFMA B-frag bf16 directly
__global__ __launch_bounds__(256) void pack_kt(const float* __restrict__ K,
                                               short* __restrict__ Ktb) {
  const int id = blockIdx.x * 256 + threadIdx.x;
  if (id >= 27 * 4 * 8 * 64) return;
  const int l = id & 63;
  int r = id >> 6;
  const int cb = r & 7; r >>= 3;
  const int kb = r & 3;
  const int tap = r >> 2;
  const int o = cb * 16 + (l & 15);
  const int i0 = kb * 32 + (l >> 4) * 8;
  short* out = Ktb + (size_t)id * 8;
#pragma unroll
  for (int j = 0; j < 8; ++j)
    out[j] = f2bf(K[((size_t)o * H + i0 + j) * 27 + tap]);
}

// 3x We[64][128] f32 -> frag-layout bf16 in one launch
__global__ __launch_bounds__(256) void pack_we3(
    const float* __restrict__ We0, const float* __restrict__ We1,
    const float* __restrict__ We2, short* __restrict__ Wb0,
    short* __restrict__ Wb1, short* __restrict__ Wb2) {
  const int id = blockIdx.x * 256 + threadIdx.x;
  if (id >= 3072) return;
  const int which = id >> 10;
  const int i = id & 1023;
  const float* We = which == 0 ? We0 : which == 1 ? We1 : We2;
  short* Web = which == 0 ? Wb0 : which == 1 ? Wb1 : Wb2;
  const int f = i >> 6, l = i & 63;
  const int h = f >> 3, c = f & 7;
  const int col = (c << 4) + (l & 15);
  const int k0 = h * 32 + (l >> 4) * 8;
  short* o = Web + (size_t)i * 8;
#pragma unroll
  for (int j = 0; j < 8; ++j) o[j] = f2bf(We[(k0 + j) * H + col]);
}

// -------------------------------------- fused 3-set counting-sort (CSR)
__global__ __launch_bounds__(256) void k_hist3(
    const int* __restrict__ d0, const int* __restrict__ d1,
    const int* __restrict__ d2, int E0, int E1, int E2,
    int* __restrict__ cnt, int off1, int off2) {
  int i = blockIdx.x * 256 + threadIdx.x;
  const int stride = gridDim.x * 256;
  const int ET = E0 + E1 + E2;
  for (; i < ET; i += stride) {
    int d, off;
    if (i < E0) { d = d0[i]; off = 0; }
    else if (i < E0 + E1) { d = d1[i - E0]; off = off1; }
    else { d = d2[i - E0 - E1]; off = off2; }
    atomicAdd(&cnt[off + d], 1);
  }
}

__global__ __launch_bounds__(256) void k_blocksum(const int* __restrict__ cnt,
                                                  int* __restrict__ bsum) {
  __shared__ int sh[256];
  const int t = threadIdx.x;
  sh[t] = cnt[blockIdx.x * 256 + t];
  __syncthreads();
#pragma unroll
  for (int o = 128; o; o >>= 1) {
    if (t < o) sh[t] += sh[t + o];
    __syncthreads();
  }
  if (!t) bsum[blockIdx.x] = sh[0];
}

// exclusive scan of <=512 block sums, single block
__global__ __launch_bounds__(512) void k_scan512(const int* __restrict__ bsum,
                                                 int* __restrict__ bpre, int NB) {
  __shared__ int sh[512];
  const int t = threadIdx.x;
  const int v = (t < NB) ? bsum[t] : 0;
  sh[t] = v;
  __syncthreads();
  for (int o = 1; o < 512; o <<= 1) {
    const int u = (t >= o) ? sh[t - o] : 0;
    __syncthreads();
    sh[t] += u;
    __syncthreads();
  }
  if (t < NB) bpre[t] = sh[t] - v;
}

// per-set rowptr/cursor from concatenated counts (base subtraction)
__global__ __launch_bounds__(256) void k_apply3(
    const int* __restrict__ cnt, const int* __restrict__ bpre,
    int* __restrict__ rp0, int* __restrict__ rp1, int* __restrict__ rp2,
    int* __restrict__ cursor, int N0, int N1, int N2, int S1, int S2) {
  __shared__ int sh[256];
  const int b = blockIdx.x;
  const int t = threadIdx.x;
  const int gi = b * 256 + t;
  const int v = cnt[gi];
  sh[t] = v;
  __syncthreads();
  for (int o = 1; o < 256; o <<= 1) {
    const int u = (t >= o) ? sh[t - o] : 0;
    __syncthreads();
    sh[t] += u;
    __syncthreads();
  }
  int sb, N;
  int* rp;
  if (b < S1) { sb = 0; N = N0; rp = rp0; }
  else if (b < S2) { sb = S1; N = N1; rp = rp1; }
  else { sb = S2; N = N2; rp = rp2; }
  const int excl = sh[t] - v + bpre[b] - bpre[sb];
  const int il = (b - sb) * 256 + t;
  if (il <= N) {
    rp[il] = excl;
    if (il < N) cursor[gi] = excl;
  }
}

// ---- wave-cooperative permute + bf16 convert + ew premultiply.
// Wave owns 16 edges: lanes 0..15 do metadata (atomic slot + packed int2
// (src,dst) store); whole wave then moves the 16 ea rows with fully
// coalesced reads (lane = (row, 64B chunk)) and 32B/lane row writes.
__global__ __launch_bounds__(256) void k_perm2w(
    const int* __restrict__ dst, const int* __restrict__ src,
    const float* __restrict__ ew, const float* __restrict__ ea, int E,
    int* __restrict__ cursor, int2* __restrict__ sd,
    short* __restrict__ eapfp) {
  const int lane = threadIdx.x & 63;
  const int wid = blockIdx.x * 4 + (threadIdx.x >> 6);
  const int nw = gridDim.x * 4;
  if (blockIdx.x == 0 && threadIdx.x < 16)
    sd[E + threadIdx.x] = make_int2(0, -1);  // tail-tile pad -> dump row
  const int r = lane >> 2;  // row 0..15
  const int c = lane & 3;   // 64B chunk 0..3
  for (int ebase = wid * 16; ebase < E; ebase += nw * 16) {
    const int ecnt = min(16, E - ebase);
    int p = 0;
    float w = 0.f;
    if (lane < ecnt) {
      const int e = ebase + lane;
      const int d = dst[e];
      w = ew[e];
      p = atomicAdd(&cursor[d], 1);
      sd[p] = make_int2(src[e], d);
    }
    const int pr = __shfl(p, r, 64);
    const float wr = __shfl(w, r, 64);
    if (r < ecnt) {
      const float* er = ea + ((size_t)(ebase + r)) * RBF + c * 16;
      const float4 x0 = *(const float4*)(er);
      const float4 x1 = *(const float4*)(er + 4);
      const float4 x2 = *(const float4*)(er + 8);
      const float4 x3 = *(const float4*)(er + 12);
      bf16x8 o0, o1;
      o0[0] = f2bf(x0.x * wr); o0[1] = f2bf(x0.y * wr);
      o0[2] = f2bf(x0.z * wr); o0[3] = f2bf(x0.w * wr);
      o0[4] = f2bf(x1.x * wr); o0[5] = f2bf(x1.y * wr);
      o0[6] = f2bf(x1.z * wr); o0[7] = f2bf(x1.w * wr);
      o1[0] = f2bf(x2.x * wr); o1[1] = f2bf(x2.y * wr);
      o1[2] = f2bf(x2.z * wr); o1[3] = f2bf(x2.w * wr);
      o1[4] = f2bf(x3.x * wr); o1[5] = f2bf(x3.y * wr);
      o1[6] = f2bf(x3.z * wr); o1[7] = f2bf(x3.w * wr);
      short* ob = eapfp + (size_t)pr * RBF + c * 16;
      *(bf16x8*)(ob) = o0;
      *(bf16x8*)(ob + 8) = o1;
    }
  }
}

// ------------------------------------------- node projection: Y = [LN](X) @ W
template <bool DO_LN>
__global__ __launch_bounds__(256) void proj_kernel(const float* __restrict__ X,
                                                   const float* __restrict__ W,
                                                   const float* __restrict__ g,
                                                   const float* __restrict__ bb,
                                                   float* __restrict__ Y, int N) {
  __shared__ float At[128 * 68];
  const int row0 = blockIdx.x * 64;
  const int t = threadIdx.x;
  const int lk = (t & 31) * 4;
  const int lr = t >> 5;
  float4 g4 = {0, 0, 0, 0}, b4 = {0, 0, 0, 0};
  if (DO_LN) {
    g4 = *(const float4*)(g + lk);
    b4 = *(const float4*)(bb + lk);
  }
#pragma unroll
  for (int p = 0; p < 8; ++p) {
    const int r = lr + p * 8;
    const int row = row0 + r;
    float4 xv = make_float4(0.f, 0.f, 0.f, 0.f);
    if (row < N) xv = *(const float4*)(X + (size_t)row * H + lk);
    if (DO_LN) {
      float s = xv.x + xv.y + xv.z + xv.w;
      float q = xv.x * xv.x + xv.y * xv.y + xv.z * xv.z + xv.w * xv.w;
#pragma unroll
      for (int m = 16; m; m >>= 1) {
        s += __shfl_xor(s, m, 64);
        q += __shfl_xor(q, m, 64);
      }
      const float mu = s * 0.0078125f;
      const float var = q * 0.0078125f - mu * mu;
      const float rs = rsqrtf(var + 1e-5f);
      xv.x = (xv.x - mu) * rs * g4.x + b4.x;
      xv.y = (xv.y - mu) * rs * g4.y + b4.y;
      xv.z = (xv.z - mu) * rs * g4.z + b4.z;
      xv.w = (xv.w - mu) * rs * g4.w + b4.w;
    }
    At[(lk + 0) * 68 + r] = xv.x;
    At[(lk + 1) * 68 + r] = xv.y;
    At[(lk + 2) * 68 + r] = xv.z;
    At[(lk + 3) * 68 + r] = xv.w;
  }
  __syncthreads();
  const int tc = t & 15;
  const int tr = t >> 4;
  float acc[4][8];
#pragma unroll
  for (int i = 0; i < 4; ++i)
#pragma unroll
    for (int c = 0; c < 8; ++c) acc[i][c] = 0.f;
  const float* wbase = W + tc * 8;
#pragma unroll 4
  for (int k = 0; k < 128; ++k) {
    const float4 a4 = *(const float4*)(At + k * 68 + tr * 4);
    const float4 w0 = *(const float4*)(wbase + k * H);
    const float4 w1 = *(const float4*)(wbase + k * H + 4);
    const float av[4] = {a4.x, a4.y, a4.z, a4.w};
#pragma unroll
    for (int i = 0; i < 4; ++i) {
      acc[i][0] += av[i] * w0.x; acc[i][1] += av[i] * w0.y;
      acc[i][2] += av[i] * w0.z; acc[i][3] += av[i] * w0.w;
      acc[i][4] += av[i] * w1.x; acc[i][5] += av[i] * w1.y;
      acc[i][6] += av[i] * w1.z; acc[i][7] += av[i] * w1.w;
    }
  }
#pragma unroll
  for (int i = 0; i < 4; ++i) {
    const int row = row0 + tr * 4 + i;
    if (row < N) {
      float4 o0 = {acc[i][0], acc[i][1], acc[i][2], acc[i][3]};
      float4 o1 = {acc[i][4], acc[i][5], acc[i][6], acc[i][7]};
      float* yp = Y + (size_t)row * H + tc * 8;
      *(float4*)yp = o0;
      *(float4*)(yp + 4) = o1;
    }
  }
}

// ----------------------------------------- tiled MFMA edge gather (CSR)
// A-frags = direct bf16 loads from eapfp (ew premultiplied in k_perm2w).
// No LDS atomics (lg-replicated acc + in-lane adjacent merge).
template <int NPB, bool FUSE_LN>
__global__ __launch_bounds__(256, 3) void gather_mfma(
    const float* __restrict__ P, const short* __restrict__ Web,
    const short* __restrict__ eapfp, const int2* __restrict__ sd,
    const int* __restrict__ rowptr, int N, const float* __restrict__ base,
    const float* __restrict__ skip, const float* __restrict__ g,
    const float* __restrict__ bb, float* __restrict__ out) {
  constexpr int RSTR = (NPB + 1) * 132;
  constexpr int RPAD = RSTR + ((16 - (RSTR & 31)) & 31);  // ≡16 (mod 32)
  __shared__ float acc[4 * RPAD];
  const int t = threadIdx.x;
  const int w = t >> 6, lane = t & 63;
  const int n0 = blockIdx.x * NPB;
  for (int u = t; u < 4 * RPAD; u += 256) acc[u] = 0.f;
  const int rp0 = rowptr[n0];
  const int rp1 = rowptr[min(n0 + NPB, N)];
  __syncthreads();
  const int q0 = rp0 >> 4;
  const int q1 = (rp1 + 15) >> 4;

  const int c0 = 2 * w;
  const bf16x8 bw0 = *(const bf16x8*)(Web + ((size_t)((0 + c0) * 64 + lane)) * 8);
  const bf16x8 bw1 = *(const bf16x8*)(Web + ((size_t)((8 + c0) * 64 + lane)) * 8);
  const bf16x8 bw2 = *(const bf16x8*)(Web + ((size_t)((1 + c0) * 64 + lane)) * 8);
  const bf16x8 bw3 = *(const bf16x8*)(Web + ((size_t)((9 + c0) * 64 + lane)) * 8);

  const int l15 = lane & 15, lg = lane >> 4, rbase = lg * 4;
  const int col0 = c0 * 16 + l15;
  float* const arep = acc + lg * RPAD;

  auto LOADI = [&](int q, bf16x8& A0, bf16x8& A1, int4& sp, int4& dp) {
    const short* fb = eapfp + ((size_t)(q * 16 + l15)) * RBF + lg * 8;
    A0 = *(const bf16x8*)(fb);
    A1 = *(const bf16x8*)(fb + 32);
    const int4 sd01 = *(const int4*)(sd + (size_t)(q * 16 + rbase));
    const int4 sd23 = *(const int4*)(sd + (size_t)(q * 16 + rbase + 2));
    sp = make_int4(sd01.x, sd01.z, sd23.x, sd23.z);
    dp = make_int4(sd01.y, sd01.w, sd23.y, sd23.w);
  };
  auto PLOAD = [&](const int4& sp, float* pv) {
    const float* p0 = P + (size_t)sp.x * H + col0;
    const float* p1 = P + (size_t)sp.y * H + col0;
    const float* p2 = P + (size_t)sp.z * H + col0;
    const float* p3 = P + (size_t)sp.w * H + col0;
    pv[0] = p0[0]; pv[4] = p0[16];
    pv[1] = p1[0]; pv[5] = p1[16];
    pv[2] = p2[0]; pv[6] = p2[16];
    pv[3] = p3[0]; pv[7] = p3[16];
  };
  auto COMP = [&](const bf16x8& A0, const bf16x8& A1, const float* pv,
                  const int4& dp) {
    f32x4 C0 = {0.f, 0.f, 0.f, 0.f};
    C0 = __builtin_amdgcn_mfma_f32_16x16x32_bf16(A0, bw0, C0, 0, 0, 0);
    C0 = __builtin_amdgcn_mfma_f32_16x16x32_bf16(A1, bw1, C0, 0, 0, 0);
    f32x4 C1 = {0.f, 0.f, 0.f, 0.f};
    C1 = __builtin_amdgcn_mfma_f32_16x16x32_bf16(A0, bw2, C1, 0, 0, 0);
    C1 = __builtin_amdgcn_mfma_f32_16x16x32_bf16(A1, bw3, C1, 0, 0, 0);
    const int dls[4] = {dp.x - n0, dp.y - n0, dp.z - n0, dp.w - n0};
    int dl[5];
#pragma unroll
    for (int j = 0; j < 4; ++j)
      dl[j] = ((unsigned)dls[j] < (unsigned)NPB) ? dls[j] : NPB;
    dl[4] = -1;
    float c0v = 0.f, c1v = 0.f;
#pragma unroll
    for (int j = 0; j < 4; ++j) {
      c0v += C0[j] * pv[j];
      c1v += C1[j] * pv[4 + j];
      if (dl[j + 1] != dl[j]) {
        float* a0 = arep + dl[j] * 132 + col0;
        a0[0] += c0v;
        a0[16] += c1v;
        c0v = 0.f;
        c1v = 0.f;
      }
    }
  };

  if (q1 > q0) {
    bf16x8 A0a, A1a, A0b, A1b;
    int4 spa, dpa, spb, dpb;
    float pva[8], pvb[8];
    LOADI(q0, A0a, A1a, spa, dpa);
    PLOAD(spa, pva);
    for (int q = q0; q < q1; q += 2) {
      if (q + 1 < q1) { LOADI(q + 1, A0b, A1b, spb, dpb); PLOAD(spb, pvb); }
      COMP(A0a, A1a, pva, dpa);
      if (q + 2 < q1) { LOADI(q + 2, A0a, A1a, spa, dpa); PLOAD(spa, pva); }
      if (q + 1 < q1) COMP(A0b, A1b, pvb, dpb);
    }
  }
  __syncthreads();

  for (int n = w; n < NPB; n += 4) {
    const int node = n0 + n;
    if (node >= N) break;
    const int rb = n * 132 + lane;
    const float v0 = acc[rb] + acc[RPAD + rb] + acc[2 * RPAD + rb] +
                     acc[3 * RPAD + rb];
    const float v1 = acc[rb + 64] + acc[RPAD + rb + 64] +
                     acc[2 * RPAD + rb + 64] + acc[3 * RPAD + rb + 64];
    const size_t i0 = (size_t)node * H + lane;
    if (FUSE_LN) {
      float s = v0 + v1, q = v0 * v0 + v1 * v1;
#pragma unroll
      for (int m = 32; m; m >>= 1) {
        s += __shfl_xor(s, m, 64);
        q += __shfl_xor(q, m, 64);
      }
      const float mu = s * 0.0078125f;
      const float var = q * 0.0078125f - mu * mu;
      const float rs = rsqrtf(var + 1e-5f);
      out[i0] = base[i0] + (v0 - mu) * rs * g[lane] + bb[lane] + skip[i0];
      out[i0 + 64] =
          base[i0 + 64] + (v1 - mu) * rs * g[lane + 64] + bb[lane + 64] + skip[i0 + 64];
    } else {
      out[i0] = v0;
      out[i0 + 64] = v1;
    }
  }
}

// -------------------------------------------------------- conv3d via MFMA
__global__ __launch_bounds__(256, 2) void conv3d_mfma(
    const float* __restrict__ Min, const short* __restrict__ Ktb,
    const float* __restrict__ bias, float* __restrict__ Mout) {
  __shared__ short in_s[193 * 128];
  const int b = blockIdx.x >> 3;
  const int x = blockIdx.x & 7;
  const int t = threadIdx.x;
  const int w = t >> 6, lane = t & 63;
  const int l15 = lane & 15, lg = lane >> 4;

  if (t < 128) in_s[192 * 128 + t] = 0;
#pragma unroll
  for (int it = 0; it < 12; ++it) {
    const int gidx = it * 256 + t;
    const int r = gidx >> 4;
    const int ch = (gidx & 15) * 8;
    const int gx = x + (r >> 6) - 1;
    const int yz = r & 63;
    float4 v0 = make_float4(0.f, 0.f, 0.f, 0.f), v1 = v0;
    if (gx >= 0 && gx < 8) {
      const float* src = Min + ((size_t)((b * 8 + gx) * 64 + yz)) * H + ch;
      v0 = *(const float4*)(src);
      v1 = *(const float4*)(src + 4);
    }
    bf16x8 pk;
    pk[0] = f2bf(v0.x); pk[1] = f2bf(v0.y); pk[2] = f2bf(v0.z); pk[3] = f2bf(v0.w);
    pk[4] = f2bf(v1.x); pk[5] = f2bf(v1.y); pk[6] = f2bf(v1.z); pk[7] = f2bf(v1.w);
    const int byte0 = (r * 256 + ch * 2) ^ ((r & 7) << 4);
    *(bf16x8*)((char*)in_s + byte0) = pk;
  }
  __syncthreads();

  const int cb0 = 2 * w;
  f32x4 C[4][2];
#pragma unroll
  for (int mt = 0; mt < 4; ++mt) {
    C[mt][0] = (f32x4){0.f, 0.f, 0.f, 0.f};
    C[mt][1] = (f32x4){0.f, 0.f, 0.f, 0.f};
  }

  auto BP = [&](int u, int cbi) -> const bf16x8* {
    return (const bf16x8*)(Ktb + (((size_t)u * 8) + cb0 + cbi) * 64 * 8 +
                           (size_t)lane * 8);
  };
  bf16x8 Ba0 = *BP(0, 0), Ba1 = *BP(0, 1);
  for (int u = 0; u < 108; ++u) {
    const int un = min(u + 1, 107);
    const bf16x8 Bn0 = *BP(un, 0);
    const bf16x8 Bn1 = *BP(un, 1);
    const int tap = u >> 2, kb = u & 3;
    const int dx = tap / 9, dy = (tap / 3) % 3, dz = tap % 3;
#pragma unroll
    for (int mt = 0; mt < 4; ++mt) {
      const int v = mt * 16 + l15;
      const int y = v >> 3, z = v & 7;
      const int ny = y + dy - 1, nz = z + dz - 1;
      const bool ok = (ny >= 0 && ny < 8 && nz >= 0 && nz < 8);
      const int vrow = ok ? dx * 64 + ny * 8 + nz : 192;
      const int byte0 = ((vrow * 256 + kb * 64 + lg * 16) ^ ((vrow & 7) << 4));
      const bf16x8 A = *(const bf16x8*)((const char*)in_s + byte0);
      C[mt][0] = __builtin_amdgcn_mfma_f32_16x16x32_bf16(A, Ba0, C[mt][0], 0, 0, 0);
      C[mt][1] = __builtin_amdgcn_mfma_f32_16x16x32_bf16(A, Ba1, C[mt][1], 0, 0, 0);
    }
    Ba0 = Bn0;
    Ba1 = Bn1;
  }

  const float b0 = bias[cb0 * 16 + l15];
  const float b1 = bias[cb0 * 16 + 16 + l15];
  float* obase = Mout + ((size_t)((b * 8 + x) * 64)) * H;
#pragma unroll
  for (int mt = 0; mt < 4; ++mt)
#pragma unroll
    for (int j = 0; j < 4; ++j) {
      const int vox = mt * 16 + lg * 4 + j;
      float* op = obase + (size_t)vox * H + cb0 * 16 + l15;
      op[0] = C[mt][0][j] + b0;
      op[16] = C[mt][1][j] + b1;
    }
}

// ------------------------------------------------------------------ driver
extern "C" void kernel_launch(void* const* d_in, const int* in_sizes, int n_in,
                              void* d_out, int out_size, void* d_ws, size_t ws_size,
                              hipStream_t stream) {
  const float* a_x = (const float*)d_in[0];
  const float* m_x = (const float*)d_in[1];
  const int* aa_idx = (const int*)d_in[2];
  const int* a2m_src = (const int*)d_in[3];
  const int* a2m_dst = (const int*)d_in[4];
  const int* m2a_src = (const int*)d_in[5];
  const int* m2a_dst = (const int*)d_in[6];
  const float* aa_w = (const float*)d_in[7];
  const float* a2m_w = (const float*)d_in[8];
  const float* m2a_w = (const float*)d_in[9];
  const float* aa_ea = (const float*)d_in[10];
  const float* a2m_ea = (const float*)d_in[11];
  const float* m2a_ea = (const float*)d_in[12];
  const float* W_short = (const float*)d_in[13];
  const float* We_short = (const float*)d_in[14];
  const float* W_a2m = (const float*)d_in[15];
  const float* We_a2m = (const float*)d_in[16];
  const float* W_m2a = (const float*)d_in[17];
  const float* We_m2a = (const float*)d_in[18];
  const float* conv_k = (const float*)d_in[19];
  const float* conv_b = (const float*)d_in[20];
  const float* g_short = (const float*)d_in[21];
  const float* b_short = (const float*)d_in[22];
  const float* g_long = (const float*)d_in[23];
  const float* b_long = (const float*)d_in[24];
  const float* g_a2m = (const float*)d_in[25];
  const float* b_a2m = (const float*)d_in[26];
  const float* g_m2a = (const float*)d_in[27];
  const float* b_m2a = (const float*)d_in[28];

  const int NA = in_sizes[0] / H;
  const int NM = in_sizes[1] / H;
  const int E_AA = in_sizes[2] / 2;
  const int E_AM = in_sizes[3];
  const int E_MA = in_sizes[5];
  const int* aa_src = aa_idx;
  const int* aa_dst = aa_idx + E_AA;

  // CSR geometry (concatenated count region)
  const int NB_A = (NA + 256) / 256;
  const int NB_M = (NM + 256) / 256;
  const int S1 = NB_A, S2 = NB_A + NB_M;
  const int NB_T = NB_A + NB_M + NB_A;
  const int OFF1 = S1 * 256, OFF2 = S2 * 256;

  float* ws = (float*)d_ws;
  float* p_buf = ws;                         // NA*H
  float* m1_buf = p_buf + (size_t)NA * H;    // NM*H
  float* m2_buf = m1_buf + (size_t)NM * H;   // NM*H
  float* a2_buf = m2_buf + (size_t)NM * H;   // NA*H
  short* web_aa = (short*)(a2_buf + (size_t)NA * H);
  short* web_a2m = web_aa + 8192;
  short* web_m2a = web_a2m + 8192;
  short* ktb = web_m2a + 8192;               // 442368 shorts
  short* eapfp = ktb + 442368;               // E_AA*64 shorts (shared, serial)
  int2* sd_aa = (int2*)(eapfp + (size_t)E_AA * RBF);
  int2* sd_a2m = sd_aa + E_AA + 16;
  int2* sd_m2a = sd_a2m + E_AM + 16;
  int* iws = (int*)(sd_m2a + E_MA + 16);
  int* cnt = iws;       iws += NB_T * 256;
  int* cursor = iws;    iws += NB_T * 256;
  int* bsum = iws;      iws += 512;
  int* bpre = iws;      iws += 512;
  int* rp_aa = iws;     iws += NA + 1;
  int* rp_a2m = iws;    iws += NM + 1;
  int* rp_m2a = iws;    iws += NA + 1;

  float* out_a = (float*)d_out;
  float* out_m = out_a + (size_t)NA * H;

  // ---- independent prep
  pack_we3<<<12, 256, 0, stream>>>(We_short, We_a2m, We_m2a, web_aa, web_a2m,
                                   web_m2a);
  pack_kt<<<(27 * 4 * 8 * 64 + 255) / 256, 256, 0, stream>>>(conv_k, ktb);
  ln_rows<<<NM, 128, 0, stream>>>(m_x, g_long, b_long, m1_buf, NM);
  conv3d_mfma<<<(NM / 64), 256, 0, stream>>>(m1_buf, ktb, conv_b, m2_buf);
  proj_kernel<true><<<(NA + 63) / 64, 256, 0, stream>>>(a_x, W_short, g_short,
                                                        b_short, p_buf, NA);

  // ---- fused 3-set CSR build
  hipMemsetAsync(cnt, 0, (size_t)NB_T * 256 * sizeof(int), stream);
  k_hist3<<<2048, 256, 0, stream>>>(aa_dst, a2m_dst, m2a_dst, E_AA, E_AM, E_MA,
                                    cnt, OFF1, OFF2);
  k_blocksum<<<NB_T, 256, 0, stream>>>(cnt, bsum);
  k_scan512<<<1, 512, 0, stream>>>(bsum, bpre, NB_T);
  k_apply3<<<NB_T, 256, 0, stream>>>(cnt, bpre, rp_aa, rp_a2m, rp_m2a, cursor,
                                     NA, NM, NA, S1, S2);

  // ---- AA
  k_perm2w<<<2048, 256, 0, stream>>>(aa_dst, aa_src, aa_w, aa_ea, E_AA, cursor,
                                     sd_aa, eapfp);
  gather_mfma<16, false><<<(NA + 15) / 16, 256, 0, stream>>>(
      p_buf, web_aa, eapfp, sd_aa, rp_aa, NA, nullptr, nullptr, nullptr,
      nullptr, a2_buf);

  // ---- a2m (reuses eapfp; stream-serial)
  proj_kernel<false><<<(NA + 63) / 64, 256, 0, stream>>>(a2_buf, W_a2m, nullptr,
                                                         nullptr, p_buf, NA);
  k_perm2w<<<2048, 256, 0, stream>>>(a2m_dst, a2m_src, a2m_w, a2m_ea, E_AM,
                                     cursor + OFF1, sd_a2m, eapfp);
  gather_mfma<16, true><<<(NM + 15) / 16, 256, 0, stream>>>(
      p_buf, web_a2m, eapfp, sd_a2m, rp_a2m, NM, m2_buf, m_x, g_a2m, b_a2m,
      out_m);

  // ---- m2a
  proj_kernel<false><<<(NM + 63) / 64, 256, 0, stream>>>(m2_buf, W_m2a, nullptr,
                                                         nullptr, m1_buf, NM);
  k_perm2w<<<2048, 256, 0, stream>>>(m2a_dst, m2a_src, m2a_w, m2a_ea, E_MA,
                                     cursor + OFF2, sd_m2a, eapfp);
  gather_mfma<16, true><<<(NA + 15) / 16, 256, 0, stream>>>(
      m1_buf, web_m2a, eapfp, sd_m2a, rp_m2a, NA, a2_buf, a_x, g_m2a, b_m2a,
      out_a);
}

// Round 13
// 557.665 us; speedup vs baseline: 3.8529x; 1.1177x over previous
//
#include <hip/hip_runtime.h>
#include <hip/hip_bf16.h>

#define H 128
#define RBF 64

typedef __attribute__((ext_vector_type(8))) short bf16x8;
typedef __attribute__((ext_vector_type(4))) float f32x4;

__device__ inline short f2bf(float f) {
  union { float f; unsigned u; } v; v.f = f;
  const unsigned r = (v.u + 0x7FFFu + ((v.u >> 16) & 1u)) >> 16;
  return (short)r;
}

// ---------------------------------------------------------------- utilities
__global__ __launch_bounds__(128) void ln_rows(const float* __restrict__ X,
                                               const float* __restrict__ g,
                                               const float* __restrict__ bb,
                                               float* __restrict__ Y, int N) {
  __shared__ float sh[4];
  const int row = blockIdx.x;
  const int j = threadIdx.x;
  float x = X[(size_t)row * H + j];
  float s = x, q = x * x;
#pragma unroll
  for (int m = 32; m; m >>= 1) {
    s += __shfl_xor(s, m, 64);
    q += __shfl_xor(q, m, 64);
  }
  if ((j & 63) == 0) { sh[(j >> 6) * 2] = s; sh[(j >> 6) * 2 + 1] = q; }
  __syncthreads();
  s = sh[0] + sh[2];
  q = sh[1] + sh[3];
  const float mu = s * 0.0078125f;
  const float var = q * 0.0078125f - mu * mu;
  const float rs = rsqrtf(var + 1e-5f);
  Y[(size_t)row * H + j] = (x - mu) * rs * g[j] + bb[j];
}

// conv_k (o,i,tap) -> MFMA B-frag bf16 directly
__global__ __launch_bounds__(256) void pack_kt(const float* __restrict__ K,
                                               short* __restrict__ Ktb) {
  const int id = blockIdx.x * 256 + threadIdx.x;
  if (id >= 27 * 4 * 8 * 64) return;
  const int l = id & 63;
  int r = id >> 6;
  const int cb = r & 7; r >>= 3;
  const int kb = r & 3;
  const int tap = r >> 2;
  const int o = cb * 16 + (l & 15);
  const int i0 = kb * 32 + (l >> 4) * 8;
  short* out = Ktb + (size_t)id * 8;
#pragma unroll
  for (int j = 0; j < 8; ++j)
    out[j] = f2bf(K[((size_t)o * H + i0 + j) * 27 + tap]);
}

// 3x We[64][128] f32 -> frag-layout bf16 in one launch
__global__ __launch_bounds__(256) void pack_we3(
    const float* __restrict__ We0, const float* __restrict__ We1,
    const float* __restrict__ We2, short* __restrict__ Wb0,
    short* __restrict__ Wb1, short* __restrict__ Wb2) {
  const int id = blockIdx.x * 256 + threadIdx.x;
  if (id >= 3072) return;
  const int which = id >> 10;
  const int i = id & 1023;
  const float* We = which == 0 ? We0 : which == 1 ? We1 : We2;
  short* Web = which == 0 ? Wb0 : which == 1 ? Wb1 : Wb2;
  const int f = i >> 6, l = i & 63;
  const int h = f >> 3, c = f & 7;
  const int col = (c << 4) + (l & 15);
  const int k0 = h * 32 + (l >> 4) * 8;
  short* o = Web + (size_t)i * 8;
#pragma unroll
  for (int j = 0; j < 8; ++j) o[j] = f2bf(We[(k0 + j) * H + col]);
}

// 3x W[128][128] f32 -> B-frag bf16 (frag f = kb*8+cb, kb=0..3)
__global__ __launch_bounds__(256) void pack_w3(
    const float* __restrict__ W0, const float* __restrict__ W1,
    const float* __restrict__ W2, short* __restrict__ Wb0,
    short* __restrict__ Wb1, short* __restrict__ Wb2) {
  const int id = blockIdx.x * 256 + threadIdx.x;
  if (id >= 3 * 2048) return;
  const int which = id >> 11;
  const int i = id & 2047;
  const float* W = which == 0 ? W0 : which == 1 ? W1 : W2;
  short* Wb = which == 0 ? Wb0 : which == 1 ? Wb1 : Wb2;
  const int f = i >> 6, l = i & 63;
  const int kb = f >> 3, cb = f & 7;
  const int col = cb * 16 + (l & 15);
  const int k0 = kb * 32 + (l >> 4) * 8;
  short* o = Wb + (size_t)i * 8;
#pragma unroll
  for (int j = 0; j < 8; ++j) o[j] = f2bf(W[(size_t)(k0 + j) * H + col]);
}

// -------------------------------------- fused 3-set counting-sort (CSR)
__global__ __launch_bounds__(256) void k_hist3(
    const int* __restrict__ d0, const int* __restrict__ d1,
    const int* __restrict__ d2, int E0, int E1, int E2,
    int* __restrict__ cnt, int off1, int off2) {
  int i = blockIdx.x * 256 + threadIdx.x;
  const int stride = gridDim.x * 256;
  const int ET = E0 + E1 + E2;
  for (; i < ET; i += stride) {
    int d, off;
    if (i < E0) { d = d0[i]; off = 0; }
    else if (i < E0 + E1) { d = d1[i - E0]; off = off1; }
    else { d = d2[i - E0 - E1]; off = off2; }
    atomicAdd(&cnt[off + d], 1);
  }
}

__global__ __launch_bounds__(256) void k_blocksum(const int* __restrict__ cnt,
                                                  int* __restrict__ bsum) {
  __shared__ int sh[256];
  const int t = threadIdx.x;
  sh[t] = cnt[blockIdx.x * 256 + t];
  __syncthreads();
#pragma unroll
  for (int o = 128; o; o >>= 1) {
    if (t < o) sh[t] += sh[t + o];
    __syncthreads();
  }
  if (!t) bsum[blockIdx.x] = sh[0];
}

__global__ __launch_bounds__(512) void k_scan512(const int* __restrict__ bsum,
                                                 int* __restrict__ bpre, int NB) {
  __shared__ int sh[512];
  const int t = threadIdx.x;
  const int v = (t < NB) ? bsum[t] : 0;
  sh[t] = v;
  __syncthreads();
  for (int o = 1; o < 512; o <<= 1) {
    const int u = (t >= o) ? sh[t - o] : 0;
    __syncthreads();
    sh[t] += u;
    __syncthreads();
  }
  if (t < NB) bpre[t] = sh[t] - v;
}

__global__ __launch_bounds__(256) void k_apply3(
    const int* __restrict__ cnt, const int* __restrict__ bpre,
    int* __restrict__ rp0, int* __restrict__ rp1, int* __restrict__ rp2,
    int* __restrict__ cursor, int N0, int N1, int N2, int S1, int S2) {
  __shared__ int sh[256];
  const int b = blockIdx.x;
  const int t = threadIdx.x;
  const int gi = b * 256 + t;
  const int v = cnt[gi];
  sh[t] = v;
  __syncthreads();
  for (int o = 1; o < 256; o <<= 1) {
    const int u = (t >= o) ? sh[t - o] : 0;
    __syncthreads();
    sh[t] += u;
    __syncthreads();
  }
  int sb, N;
  int* rp;
  if (b < S1) { sb = 0; N = N0; rp = rp0; }
  else if (b < S2) { sb = S1; N = N1; rp = rp1; }
  else { sb = S2; N = N2; rp = rp2; }
  const int excl = sh[t] - v + bpre[b] - bpre[sb];
  const int il = (b - sb) * 256 + t;
  if (il <= N) {
    rp[il] = excl;
    if (il < N) cursor[gi] = excl;
  }
}

// ---- wave-cooperative permute + bf16 convert + ew premultiply
__global__ __launch_bounds__(256) void k_perm2w(
    const int* __restrict__ dst, const int* __restrict__ src,
    const float* __restrict__ ew, const float* __restrict__ ea, int E,
    int* __restrict__ cursor, int2* __restrict__ sd,
    short* __restrict__ eapfp) {
  const int lane = threadIdx.x & 63;
  const int wid = blockIdx.x * 4 + (threadIdx.x >> 6);
  const int nw = gridDim.x * 4;
  if (blockIdx.x == 0 && threadIdx.x < 16)
    sd[E + threadIdx.x] = make_int2(0, -1);  // tail-tile pad -> dump row
  const int r = lane >> 2;
  const int c = lane & 3;
  for (int ebase = wid * 16; ebase < E; ebase += nw * 16) {
    const int ecnt = min(16, E - ebase);
    int p = 0;
    float w = 0.f;
    if (lane < ecnt) {
      const int e = ebase + lane;
      const int d = dst[e];
      w = ew[e];
      p = atomicAdd(&cursor[d], 1);
      sd[p] = make_int2(src[e], d);
    }
    const int pr = __shfl(p, r, 64);
    const float wr = __shfl(w, r, 64);
    if (r < ecnt) {
      const float* er = ea + ((size_t)(ebase + r)) * RBF + c * 16;
      const float4 x0 = *(const float4*)(er);
      const float4 x1 = *(const float4*)(er + 4);
      const float4 x2 = *(const float4*)(er + 8);
      const float4 x3 = *(const float4*)(er + 12);
      bf16x8 o0, o1;
      o0[0] = f2bf(x0.x * wr); o0[1] = f2bf(x0.y * wr);
      o0[2] = f2bf(x0.z * wr); o0[3] = f2bf(x0.w * wr);
      o0[4] = f2bf(x1.x * wr); o0[5] = f2bf(x1.y * wr);
      o0[6] = f2bf(x1.z * wr); o0[7] = f2bf(x1.w * wr);
      o1[0] = f2bf(x2.x * wr); o1[1] = f2bf(x2.y * wr);
      o1[2] = f2bf(x2.z * wr); o1[3] = f2bf(x2.w * wr);
      o1[4] = f2bf(x3.x * wr); o1[5] = f2bf(x3.y * wr);
      o1[6] = f2bf(x3.z * wr); o1[7] = f2bf(x3.w * wr);
      short* ob = eapfp + (size_t)pr * RBF + c * 16;
      *(bf16x8*)(ob) = o0;
      *(bf16x8*)(ob + 8) = o1;
    }
  }
}

// ------------------------------ projection via MFMA: Y = X @ W (bf16/f32acc)
// Block = 64 rows x 128 cols, K=128. X staged f32->bf16 in swizzled LDS.
__global__ __launch_bounds__(256, 2) void proj_mfma(
    const float* __restrict__ X, const short* __restrict__ Wb,
    float* __restrict__ Y, int N) {
  __shared__ short xs[64 * 128];  // bf16, XOR-swizzled rows
  const int row0 = blockIdx.x * 64;
  const int t = threadIdx.x;
  const int w = t >> 6, lane = t & 63;
  const int l15 = lane & 15, lg = lane >> 4;

#pragma unroll
  for (int it = 0; it < 4; ++it) {
    const int gidx = it * 256 + t;  // 1024 chunks of 8 ch
    const int r = gidx >> 4;        // 0..63
    const int ch = (gidx & 15) * 8;
    const int row = row0 + r;
    float4 v0 = make_float4(0.f, 0.f, 0.f, 0.f), v1 = v0;
    if (row < N) {
      const float* src = X + (size_t)row * H + ch;
      v0 = *(const float4*)(src);
      v1 = *(const float4*)(src + 4);
    }
    bf16x8 pk;
    pk[0] = f2bf(v0.x); pk[1] = f2bf(v0.y); pk[2] = f2bf(v0.z); pk[3] = f2bf(v0.w);
    pk[4] = f2bf(v1.x); pk[5] = f2bf(v1.y); pk[6] = f2bf(v1.z); pk[7] = f2bf(v1.w);
    const int byte0 = (r * 256 + ch * 2) ^ ((r & 7) << 4);
    *(bf16x8*)((char*)xs + byte0) = pk;
  }
  __syncthreads();

  const int cb0 = 2 * w;
  // B fragments: 4 kb x 2 ci = 8 frags (32 VGPR)
  bf16x8 bw[4][2];
#pragma unroll
  for (int kb = 0; kb < 4; ++kb)
#pragma unroll
    for (int ci = 0; ci < 2; ++ci)
      bw[kb][ci] = *(const bf16x8*)(Wb + (((size_t)kb * 8 + cb0 + ci) * 64 +
                                          lane) * 8);

  f32x4 C[4][2];
#pragma unroll
  for (int mt = 0; mt < 4; ++mt) {
    C[mt][0] = (f32x4){0.f, 0.f, 0.f, 0.f};
    C[mt][1] = (f32x4){0.f, 0.f, 0.f, 0.f};
  }
#pragma unroll
  for (int kb = 0; kb < 4; ++kb) {
#pragma unroll
    for (int mt = 0; mt < 4; ++mt) {
      const int r = mt * 16 + l15;
      const int byte0 = (r * 256 + kb * 64 + lg * 16) ^ ((r & 7) << 4);
      const bf16x8 A = *(const bf16x8*)((const char*)xs + byte0);
      C[mt][0] = __builtin_amdgcn_mfma_f32_16x16x32_bf16(A, bw[kb][0], C[mt][0], 0, 0, 0);
      C[mt][1] = __builtin_amdgcn_mfma_f32_16x16x32_bf16(A, bw[kb][1], C[mt][1], 0, 0, 0);
    }
  }
#pragma unroll
  for (int mt = 0; mt < 4; ++mt)
#pragma unroll
    for (int j = 0; j < 4; ++j) {
      const int row = row0 + mt * 16 + lg * 4 + j;
      if (row < N) {
        float* yp = Y + (size_t)row * H + cb0 * 16 + l15;
        yp[0] = C[mt][0][j];
        yp[16] = C[mt][1][j];
      }
    }
}

// ----------------------------------------- tiled MFMA edge gather (CSR)
// bf16 A-frags from eapfp; lg-replicated LDS acc (no atomics); 3-deep
// register pipeline (depth-2 barely covers the ~200cyc L2 P-load latency).
template <int NPB, bool FUSE_LN>
__global__ __launch_bounds__(256, 3) void gather_mfma(
    const float* __restrict__ P, const short* __restrict__ Web,
    const short* __restrict__ eapfp, const int2* __restrict__ sd,
    const int* __restrict__ rowptr, int N, const float* __restrict__ base,
    const float* __restrict__ skip, const float* __restrict__ g,
    const float* __restrict__ bb, float* __restrict__ out) {
  constexpr int RSTR = (NPB + 1) * 132;
  constexpr int RPAD = RSTR + ((16 - (RSTR & 31)) & 31);  // ≡16 (mod 32)
  __shared__ float acc[4 * RPAD];
  const int t = threadIdx.x;
  const int w = t >> 6, lane = t & 63;
  const int n0 = blockIdx.x * NPB;
  for (int u = t; u < 4 * RPAD; u += 256) acc[u] = 0.f;
  const int rp0 = rowptr[n0];
  const int rp1 = rowptr[min(n0 + NPB, N)];
  __syncthreads();
  const int q0 = rp0 >> 4;
  const int q1 = (rp1 + 15) >> 4;

  const int c0 = 2 * w;
  const bf16x8 bw0 = *(const bf16x8*)(Web + ((size_t)((0 + c0) * 64 + lane)) * 8);
  const bf16x8 bw1 = *(const bf16x8*)(Web + ((size_t)((8 + c0) * 64 + lane)) * 8);
  const bf16x8 bw2 = *(const bf16x8*)(Web + ((size_t)((1 + c0) * 64 + lane)) * 8);
  const bf16x8 bw3 = *(const bf16x8*)(Web + ((size_t)((9 + c0) * 64 + lane)) * 8);

  const int l15 = lane & 15, lg = lane >> 4, rbase = lg * 4;
  const int col0 = c0 * 16 + l15;
  float* const arep = acc + lg * RPAD;

  auto LOAD = [&](int q, bf16x8& A0, bf16x8& A1, int4& sp, int4& dp,
                  float* pv) {
    const short* fb = eapfp + ((size_t)(q * 16 + l15)) * RBF + lg * 8;
    A0 = *(const bf16x8*)(fb);
    A1 = *(const bf16x8*)(fb + 32);
    const int4 sd01 = *(const int4*)(sd + (size_t)(q * 16 + rbase));
    const int4 sd23 = *(const int4*)(sd + (size_t)(q * 16 + rbase + 2));
    sp = make_int4(sd01.x, sd01.z, sd23.x, sd23.z);
    dp = make_int4(sd01.y, sd01.w, sd23.y, sd23.w);
    const float* p0 = P + (size_t)sp.x * H + col0;
    const float* p1 = P + (size_t)sp.y * H + col0;
    const float* p2 = P + (size_t)sp.z * H + col0;
    const float* p3 = P + (size_t)sp.w * H + col0;
    pv[0] = p0[0]; pv[4] = p0[16];
    pv[1] = p1[0]; pv[5] = p1[16];
    pv[2] = p2[0]; pv[6] = p2[16];
    pv[3] = p3[0]; pv[7] = p3[16];
  };
  auto COMP = [&](const bf16x8& A0, const bf16x8& A1, const float* pv,
                  const int4& dp) {
    f32x4 C0 = {0.f, 0.f, 0.f, 0.f};
    C0 = __builtin_amdgcn_mfma_f32_16x16x32_bf16(A0, bw0, C0, 0, 0, 0);
    C0 = __builtin_amdgcn_mfma_f32_16x16x32_bf16(A1, bw1, C0, 0, 0, 0);
    f32x4 C1 = {0.f, 0.f, 0.f, 0.f};
    C1 = __builtin_amdgcn_mfma_f32_16x16x32_bf16(A0, bw2, C1, 0, 0, 0);
    C1 = __builtin_amdgcn_mfma_f32_16x16x32_bf16(A1, bw3, C1, 0, 0, 0);
    const int dls[4] = {dp.x - n0, dp.y - n0, dp.z - n0, dp.w - n0};
    int dl[5];
#pragma unroll
    for (int j = 0; j < 4; ++j)
      dl[j] = ((unsigned)dls[j] < (unsigned)NPB) ? dls[j] : NPB;
    dl[4] = -1;
    float c0v = 0.f, c1v = 0.f;
#pragma unroll
    for (int j = 0; j < 4; ++j) {
      c0v += C0[j] * pv[j];
      c1v += C1[j] * pv[4 + j];
      if (dl[j + 1] != dl[j]) {
        float* a0 = arep + dl[j] * 132 + col0;
        a0[0] += c0v;
        a0[16] += c1v;
        c0v = 0.f;
        c1v = 0.f;
      }
    }
  };

  if (q1 > q0) {
    bf16x8 A0a, A1a, A0b, A1b, A0c, A1c;
    int4 spa, dpa, spb, dpb, spc, dpc;
    float pva[8], pvb[8], pvc[8];
    LOAD(q0, A0a, A1a, spa, dpa, pva);
    if (q0 + 1 < q1) LOAD(q0 + 1, A0b, A1b, spb, dpb, pvb);
    int q = q0;
    while (true) {
      if (q + 2 < q1) LOAD(q + 2, A0c, A1c, spc, dpc, pvc);
      COMP(A0a, A1a, pva, dpa);
      if (++q >= q1) break;
      if (q + 2 < q1) LOAD(q + 2, A0a, A1a, spa, dpa, pva);
      COMP(A0b, A1b, pvb, dpb);
      if (++q >= q1) break;
      if (q + 2 < q1) LOAD(q + 2, A0b, A1b, spb, dpb, pvb);
      COMP(A0c, A1c, pvc, dpc);
      if (++q >= q1) break;
    }
  }
  __syncthreads();

  for (int n = w; n < NPB; n += 4) {
    const int node = n0 + n;
    if (node >= N) break;
    const int rb = n * 132 + lane;
    const float v0 = acc[rb] + acc[RPAD + rb] + acc[2 * RPAD + rb] +
                     acc[3 * RPAD + rb];
    const float v1 = acc[rb + 64] + acc[RPAD + rb + 64] +
                     acc[2 * RPAD + rb + 64] + acc[3 * RPAD + rb + 64];
    const size_t i0 = (size_t)node * H + lane;
    if (FUSE_LN) {
      float s = v0 + v1, q = v0 * v0 + v1 * v1;
#pragma unroll
      for (int m = 32; m; m >>= 1) {
        s += __shfl_xor(s, m, 64);
        q += __shfl_xor(q, m, 64);
      }
      const float mu = s * 0.0078125f;
      const float var = q * 0.0078125f - mu * mu;
      const float rs = rsqrtf(var + 1e-5f);
      out[i0] = base[i0] + (v0 - mu) * rs * g[lane] + bb[lane] + skip[i0];
      out[i0 + 64] =
          base[i0 + 64] + (v1 - mu) * rs * g[lane + 64] + bb[lane + 64] + skip[i0 + 64];
    } else {
      out[i0] = v0;
      out[i0 + 64] = v1;
    }
  }
}

// -------------------------------------------------------- conv3d via MFMA
__global__ __launch_bounds__(256, 2) void conv3d_mfma(
    const float* __restrict__ Min, const short* __restrict__ Ktb,
    const float* __restrict__ bias, float* __restrict__ Mout) {
  __shared__ short in_s[193 * 128];
  const int b = blockIdx.x >> 3;
  const int x = blockIdx.x & 7;
  const int t = threadIdx.x;
  const int w = t >> 6, lane = t & 63;
  const int l15 = lane & 15, lg = lane >> 4;

  if (t < 128) in_s[192 * 128 + t] = 0;
#pragma unroll
  for (int it = 0; it < 12; ++it) {
    const int gidx = it * 256 + t;
    const int r = gidx >> 4;
    const int ch = (gidx & 15) * 8;
    const int gx = x + (r >> 6) - 1;
    const int yz = r & 63;
    float4 v0 = make_float4(0.f, 0.f, 0.f, 0.f), v1 = v0;
    if (gx >= 0 && gx < 8) {
      const float* src = Min + ((size_t)((b * 8 + gx) * 64 + yz)) * H + ch;
      v0 = *(const float4*)(src);
      v1 = *(const float4*)(src + 4);
    }
    bf16x8 pk;
    pk[0] = f2bf(v0.x); pk[1] = f2bf(v0.y); pk[2] = f2bf(v0.z); pk[3] = f2bf(v0.w);
    pk[4] = f2bf(v1.x); pk[5] = f2bf(v1.y); pk[6] = f2bf(v1.z); pk[7] = f2bf(v1.w);
    const int byte0 = (r * 256 + ch * 2) ^ ((r & 7) << 4);
    *(bf16x8*)((char*)in_s + byte0) = pk;
  }
  __syncthreads();

  const int cb0 = 2 * w;
  f32x4 C[4][2];
#pragma unroll
  for (int mt = 0; mt < 4; ++mt) {
    C[mt][0] = (f32x4){0.f, 0.f, 0.f, 0.f};
    C[mt][1] = (f32x4){0.f, 0.f, 0.f, 0.f};
  }

  auto BP = [&](int u, int cbi) -> const bf16x8* {
    return (const bf16x8*)(Ktb + (((size_t)u * 8) + cb0 + cbi) * 64 * 8 +
                           (size_t)lane * 8);
  };
  bf16x8 Ba0 = *BP(0, 0), Ba1 = *BP(0, 1);
  for (int u = 0; u < 108; ++u) {
    const int un = min(u + 1, 107);
    const bf16x8 Bn0 = *BP(un, 0);
    const bf16x8 Bn1 = *BP(un, 1);
    const int tap = u >> 2, kb = u & 3;
    const int dx = tap / 9, dy = (tap / 3) % 3, dz = tap % 3;
#pragma unroll
    for (int mt = 0; mt < 4; ++mt) {
      const int v = mt * 16 + l15;
      const int y = v >> 3, z = v & 7;
      const int ny = y + dy - 1, nz = z + dz - 1;
      const bool ok = (ny >= 0 && ny < 8 && nz >= 0 && nz < 8);
      const int vrow = ok ? dx * 64 + ny * 8 + nz : 192;
      const int byte0 = ((vrow * 256 + kb * 64 + lg * 16) ^ ((vrow & 7) << 4));
      const bf16x8 A = *(const bf16x8*)((const char*)in_s + byte0);
      C[mt][0] = __builtin_amdgcn_mfma_f32_16x16x32_bf16(A, Ba0, C[mt][0], 0, 0, 0);
      C[mt][1] = __builtin_amdgcn_mfma_f32_16x16x32_bf16(A, Ba1, C[mt][1], 0, 0, 0);
    }
    Ba0 = Bn0;
    Ba1 = Bn1;
  }

  const float b0 = bias[cb0 * 16 + l15];
  const float b1 = bias[cb0 * 16 + 16 + l15];
  float* obase = Mout + ((size_t)((b * 8 + x) * 64)) * H;
#pragma unroll
  for (int mt = 0; mt < 4; ++mt)
#pragma unroll
    for (int j = 0; j < 4; ++j) {
      const int vox = mt * 16 + lg * 4 + j;
      float* op = obase + (size_t)vox * H + cb0 * 16 + l15;
      op[0] = C[mt][0][j] + b0;
      op[16] = C[mt][1][j] + b1;
    }
}

// ------------------------------------------------------------------ driver
extern "C" void kernel_launch(void* const* d_in, const int* in_sizes, int n_in,
                              void* d_out, int out_size, void* d_ws, size_t ws_size,
                              hipStream_t stream) {
  const float* a_x = (const float*)d_in[0];
  const float* m_x = (const float*)d_in[1];
  const int* aa_idx = (const int*)d_in[2];
  const int* a2m_src = (const int*)d_in[3];
  const int* a2m_dst = (const int*)d_in[4];
  const int* m2a_src = (const int*)d_in[5];
  const int* m2a_dst = (const int*)d_in[6];
  const float* aa_w = (const float*)d_in[7];
  const float* a2m_w = (const float*)d_in[8];
  const float* m2a_w = (const float*)d_in[9];
  const float* aa_ea = (const float*)d_in[10];
  const float* a2m_ea = (const float*)d_in[11];
  const float* m2a_ea = (const float*)d_in[12];
  const float* W_short = (const float*)d_in[13];
  const float* We_short = (const float*)d_in[14];
  const float* W_a2m = (const float*)d_in[15];
  const float* We_a2m = (const float*)d_in[16];
  const float* W_m2a = (const float*)d_in[17];
  const float* We_m2a = (const float*)d_in[18];
  const float* conv_k = (const float*)d_in[19];
  const float* conv_b = (const float*)d_in[20];
  const float* g_short = (const float*)d_in[21];
  const float* b_short = (const float*)d_in[22];
  const float* g_long = (const float*)d_in[23];
  const float* b_long = (const float*)d_in[24];
  const float* g_a2m = (const float*)d_in[25];
  const float* b_a2m = (const float*)d_in[26];
  const float* g_m2a = (const float*)d_in[27];
  const float* b_m2a = (const float*)d_in[28];

  const int NA = in_sizes[0] / H;
  const int NM = in_sizes[1] / H;
  const int E_AA = in_sizes[2] / 2;
  const int E_AM = in_sizes[3];
  const int E_MA = in_sizes[5];
  const int* aa_src = aa_idx;
  const int* aa_dst = aa_idx + E_AA;

  const int NB_A = (NA + 256) / 256;
  const int NB_M = (NM + 256) / 256;
  const int S1 = NB_A, S2 = NB_A + NB_M;
  const int NB_T = NB_A + NB_M + NB_A;
  const int OFF1 = S1 * 256, OFF2 = S2 * 256;

  float* ws = (float*)d_ws;
  float* p_buf = ws;                         // NA*H
  float* m1_buf = p_buf + (size_t)NA * H;    // NM*H
  float* m2_buf = m1_buf + (size_t)NM * H;   // NM*H
  float* a2_buf = m2_buf + (size_t)NM * H;   // NA*H
  float* a1_buf = a2_buf + (size_t)NA * H;   // NA*H : LN(a_x)
  short* web_aa = (short*)(a1_buf + (size_t)NA * H);
  short* web_a2m = web_aa + 8192;
  short* web_m2a = web_a2m + 8192;
  short* wb_s = web_m2a + 8192;              // 16384 shorts each
  short* wb_a2m = wb_s + 16384;
  short* wb_m2a = wb_a2m + 16384;
  short* ktb = wb_m2a + 16384;               // 442368 shorts
  short* eapfp = ktb + 442368;               // E_AA*64 shorts (shared, serial)
  int2* sd_aa = (int2*)(eapfp + (size_t)E_AA * RBF);
  int2* sd_a2m = sd_aa + E_AA + 16;
  int2* sd_m2a = sd_a2m + E_AM + 16;
  int* iws = (int*)(sd_m2a + E_MA + 16);
  int* cnt = iws;       iws += NB_T * 256;
  int* cursor = iws;    iws += NB_T * 256;
  int* bsum = iws;      iws += 512;
  int* bpre = iws;      iws += 512;
  int* rp_aa = iws;     iws += NA + 1;
  int* rp_a2m = iws;    iws += NM + 1;
  int* rp_m2a = iws;    iws += NA + 1;

  float* out_a = (float*)d_out;
  float* out_m = out_a + (size_t)NA * H;

  // ---- independent prep
  pack_we3<<<12, 256, 0, stream>>>(We_short, We_a2m, We_m2a, web_aa, web_a2m,
                                   web_m2a);
  pack_w3<<<24, 256, 0, stream>>>(W_short, W_a2m, W_m2a, wb_s, wb_a2m, wb_m2a);
  pack_kt<<<(27 * 4 * 8 * 64 + 255) / 256, 256, 0, stream>>>(conv_k, ktb);
  ln_rows<<<NM, 128, 0, stream>>>(m_x, g_long, b_long, m1_buf, NM);
  conv3d_mfma<<<(NM / 64), 256, 0, stream>>>(m1_buf, ktb, conv_b, m2_buf);
  ln_rows<<<NA, 128, 0, stream>>>(a_x, g_short, b_short, a1_buf, NA);
  proj_mfma<<<(NA + 63) / 64, 256, 0, stream>>>(a1_buf, wb_s, p_buf, NA);

  // ---- fused 3-set CSR build
  hipMemsetAsync(cnt, 0, (size_t)NB_T * 256 * sizeof(int), stream);
  k_hist3<<<2048, 256, 0, stream>>>(aa_dst, a2m_dst, m2a_dst, E_AA, E_AM, E_MA,
                                    cnt, OFF1, OFF2);
  k_blocksum<<<NB_T, 256, 0, stream>>>(cnt, bsum);
  k_scan512<<<1, 512, 0, stream>>>(bsum, bpre, NB_T);
  k_apply3<<<NB_T, 256, 0, stream>>>(cnt, bpre, rp_aa, rp_a2m, rp_m2a, cursor,
                                     NA, NM, NA, S1, S2);

  // ---- AA
  k_perm2w<<<2048, 256, 0, stream>>>(aa_dst, aa_src, aa_w, aa_ea, E_AA, cursor,
                                     sd_aa, eapfp);
  gather_mfma<16, false><<<(NA + 15) / 16, 256, 0, stream>>>(
      p_buf, web_aa, eapfp, sd_aa, rp_aa, NA, nullptr, nullptr, nullptr,
      nullptr, a2_buf);

  // ---- a2m (reuses eapfp; stream-serial)
  proj_mfma<<<(NA + 63) / 64, 256, 0, stream>>>(a2_buf, wb_a2m, p_buf, NA);
  k_perm2w<<<2048, 256, 0, stream>>>(a2m_dst, a2m_src, a2m_w, a2m_ea, E_AM,
                                     cursor + OFF1, sd_a2m, eapfp);
  gather_mfma<16, true><<<(NM + 15) / 16, 256, 0, stream>>>(
      p_buf, web_a2m, eapfp, sd_a2m, rp_a2m, NM, m2_buf, m_x, g_a2m, b_a2m,
      out_m);

  // ---- m2a
  proj_mfma<<<(NM + 63) / 64, 256, 0, stream>>>(m2_buf, wb_m2a, m1_buf, NM);
  k_perm2w<<<2048, 256, 0, stream>>>(m2a_dst, m2a_src, m2a_w, m2a_ea, E_MA,
                                     cursor + OFF2, sd_m2a, eapfp);
  gather_mfma<16, true><<<(NA + 15) / 16, 256, 0, stream>>>(
      m1_buf, web_m2a, eapfp, sd_m2a, rp_m2a, NA, a2_buf, a_x, g_m2a, b_m2a,
      out_a);
}